// Round 6
// baseline (1796.684 us; speedup 1.0000x reference)
//
#include <hip/hip_runtime.h>
#include <cstddef>
#include <cstdint>

#define HW96 9216
#define FRAME (64 * 9216)

typedef unsigned short ushort_t;
typedef __attribute__((ext_vector_type(8))) short bf16x8;
typedef __attribute__((ext_vector_type(4))) float f32x4;
typedef __attribute__((ext_vector_type(4))) unsigned u32x4;

// packed u32 = (bf16 hi bits << 16) | bf16 lo bits; value = hi + lo exactly
__device__ __forceinline__ float unpk(unsigned p) {
    return __uint_as_float(p & 0xFFFF0000u) + __uint_as_float(p << 16);
}
__device__ __forceinline__ unsigned pk(float v) {
    unsigned u = __float_as_uint(v);
    unsigned hi = u & 0xFFFF0000u;
    float rem = v - __uint_as_float(hi);
    unsigned r = __float_as_uint(rem);
    unsigned lo = (r + 0x7FFFu + ((r >> 16) & 1u)) >> 16;
    return hi | (lo & 0xFFFFu);
}
__device__ __forceinline__ void split16(float v, ushort_t& h, ushort_t& l) {
    unsigned u = __float_as_uint(v);
    h = (ushort_t)(u >> 16);
    float rem = v - __uint_as_float(u & 0xFFFF0000u);
    unsigned r = __float_as_uint(rem);
    l = (ushort_t)((r + 0x7FFFu + ((r >> 16) & 1u)) >> 16);
}

// ---------------------------------------------------------------------------
// Plain repack: OIHW -> [i][o] fp32 (fusion 1x1 only).
// ---------------------------------------------------------------------------
__global__ __launch_bounds__(256) void repack_fus_k(const float* __restrict__ w,
                                                    float* __restrict__ wp) {
    int idx = blockIdx.x * 256 + threadIdx.x;  // 128*64
    if (idx >= 128 * 64) return;
    int o = idx % 64;
    int i = idx / 64;
    wp[idx] = w[o * 128 + i];
}

// ---------------------------------------------------------------------------
// MFMA A-fragment prepack (16x16x32) with bf16 hi/lo split.
// mode 0 (3x3 conv): layout [hl][t][cc][ot][lane][j]; K = cin chunks of 32.
// mode 1 (dconv):    layout [hl][cc][ot][lane][j]; K = g*72 + tap*8 + c.
// A[m=lane&15][k=(lane>>4)*8+j].
// ---------------------------------------------------------------------------
struct FragJob { const float* src; ushort_t* dst; int O, I, OT, KC, mode; };
struct FragJobs { FragJob j[14]; };

__global__ __launch_bounds__(256) void frag_all_k(FragJobs jobs) {
    const FragJob& J = jobs.j[blockIdx.y];
    int idx = blockIdx.x * 256 + threadIdx.x;
    int total = (J.mode ? 1 : 9) * J.KC * J.OT * 512;
    if (idx >= total) return;
    int jj = idx & 7;
    int lane = (idx >> 3) & 63;
    int rem = idx >> 9;
    int ot = rem % J.OT;
    rem /= J.OT;
    int cc = rem % J.KC;
    int t = rem / J.KC;
    int o = ot * 16 + (lane & 15);
    float wv = 0.f;
    if (J.mode == 0) {
        int ci = cc * 32 + (lane >> 4) * 8 + jj;
        if (o < J.O && ci < J.I) wv = J.src[(o * J.I + ci) * 9 + t];
    } else {
        int K = cc * 32 + (lane >> 4) * 8 + jj;
        int g = K / 72, r2 = K % 72;
        int tap = r2 >> 3, c = r2 & 7;
        int ci = g * 8 + c;
        if (o < J.O && ci < J.I) wv = J.src[(o * J.I + ci) * 9 + tap];
    }
    ushort_t h, l;
    split16(wv, h, l);
    J.dst[idx] = h;
    J.dst[total + idx] = l;
}

// ---------------------------------------------------------------------------
// Transposing pack: planar fp32 frames -> interleaved [px][64ch] packed u32.
// Block handles one 64-px x 64-ch tile via padded LDS. grid (144, T).
// ---------------------------------------------------------------------------
__global__ __launch_bounds__(256) void pack_tr_k(const float* __restrict__ src,
                                                 unsigned* __restrict__ dst) {
    const int t = blockIdx.y;
    const int px0 = blockIdx.x * 64;
    __shared__ unsigned tile[64 * 65];
    const float* s = src + (size_t)t * FRAME;
    unsigned* d = dst + (size_t)t * FRAME;
#pragma unroll
    for (int it = 0; it < 16; ++it) {
        int e = it * 256 + threadIdx.x;
        int p = e & 63, ch = e >> 6;
        tile[ch * 65 + p] = pk(s[(size_t)ch * HW96 + px0 + p]);
    }
    __syncthreads();
#pragma unroll
    for (int it = 0; it < 16; ++it) {
        int e = it * 256 + threadIdx.x;
        int ch = e & 63, p = e >> 6;
        d[(size_t)(px0 + p) * 64 + ch] = tile[ch * 65 + p];
    }
}

// ---------------------------------------------------------------------------
// MFMA implicit-GEMM 3x3 conv, 16x16x32 bf16.
// TERMS=3: AhBh + AlBh + AhBl (fp32-grade, feature path).
// TERMS=2: AhBh + AhBl (weight-lo dropped; offset/mask path).
// OTN: out-tiles in the frag layout (4 for 64-cout convs, 28 for ow4).
// RAW=1: write planar packed-u32 raw output (ow4; no act/addsrc).
// Block: 128 thr = 2 waves; each wave one 16-cout tile; OTG=OTN/2 blocks/seg.
// ---------------------------------------------------------------------------
template <int TERMS, int OTN, int RAW>
__global__ __launch_bounds__(128, 3) void convm_k(
    const unsigned* __restrict__ s0, const unsigned* __restrict__ s1,
    const unsigned* __restrict__ s2, int b0, int b1, int b2, int nsrc,
    const ushort_t* __restrict__ wfrag, int KCfull,
    const float* __restrict__ bias, const float* __restrict__ addsrc,
    unsigned* __restrict__ outpk, int act) {
    const int OTG = OTN / 2;
    const int tid = threadIdx.x;
    const int lane = tid & 63;
    const int w = tid >> 6;              // 0..1
    const int h = blockIdx.x % OTG;      // out-tile group
    const int bseg = blockIdx.x / OTG;   // px segment
    const int ot = h * 2 + w;            // out-tile 0..OTN-1
    const int xb = (bseg % 6) * 16;
    const int y = bseg / 6;
    const int n = lane & 15;
    const int quad = lane >> 4;

    __shared__ __align__(16) ushort_t ldsH[3 * 18 * 72];
    __shared__ __align__(16) ushort_t ldsL[3 * 18 * 72];

    // staging job decode (loop-invariant): 432 jobs = 54 (r,c) x 8 octets
    int jst[4], jok[4], joff[4], jbase[4];
#pragma unroll
    for (int i = 0; i < 4; ++i) {
        int e = tid + i * 128;
        int rc = e >> 3, cg = e & 7;
        int r = rc / 18, col = rc - r * 18;
        int gy = y - 1 + r, gx = xb - 1 + col;
        jst[i] = (e < 432);
        jok[i] = jst[i] && ((unsigned)gy < 96u) && ((unsigned)gx < 96u);
        joff[i] = (gy * 96 + gx) * 64 + cg * 8;
        jbase[i] = rc * 72 + cg * 8;
    }

    f32x4 acc0, acc1;
#pragma unroll
    for (int r = 0; r < 4; ++r) { acc0[r] = 0.f; acc1[r] = 0.f; }

    const size_t hlOff = (size_t)9 * KCfull * OTN * 512;

    for (int j = 0; j < nsrc; ++j) {
        const unsigned* sv = (j == 0) ? s0 : (j == 1 ? s1 : s2);
        const int base = (j == 0) ? b0 : (j == 1 ? b1 : b2);
        __syncthreads();
#pragma unroll
        for (int i = 0; i < 4; ++i) {
            if (jst[i]) {
                u32x4 a, b;
                if (jok[i]) {
                    a = *(const u32x4*)(sv + joff[i]);
                    b = *(const u32x4*)(sv + joff[i] + 4);
                } else {
#pragma unroll
                    for (int q = 0; q < 4; ++q) { a[q] = 0; b[q] = 0; }
                }
                u32x4 H, L;
#pragma unroll
                for (int q = 0; q < 2; ++q) {
                    H[q] = (a[2 * q] >> 16) | (a[2 * q + 1] & 0xFFFF0000u);
                    L[q] = (a[2 * q] & 0xFFFFu) | (a[2 * q + 1] << 16);
                    H[2 + q] = (b[2 * q] >> 16) | (b[2 * q + 1] & 0xFFFF0000u);
                    L[2 + q] = (b[2 * q] & 0xFFFFu) | (b[2 * q + 1] << 16);
                }
                *(u32x4*)(ldsH + jbase[i]) = H;
                *(u32x4*)(ldsL + jbase[i]) = L;
            }
        }
        __syncthreads();
        // depth-5 rolling pipeline over 18 steps (t = s>>1, cc2 = s&1)
        bf16x8 pAh[5], pAl[5], pBh[5], pBl[5];
#pragma unroll
        for (int s = 0; s < 23; ++s) {
            if (s >= 5) {  // consume BEFORE refilling the slot
                const int u = s - 5;
                const bf16x8 Ah = pAh[u % 5];
                const bf16x8 Bh = pBh[u % 5], Bl = pBl[u % 5];
                if (u & 1) {
                    acc1 = __builtin_amdgcn_mfma_f32_16x16x32_bf16(Ah, Bh, acc1, 0, 0, 0);
                    if (TERMS == 3)
                        acc1 = __builtin_amdgcn_mfma_f32_16x16x32_bf16(pAl[u % 5], Bh, acc1, 0, 0, 0);
                    acc1 = __builtin_amdgcn_mfma_f32_16x16x32_bf16(Ah, Bl, acc1, 0, 0, 0);
                } else {
                    acc0 = __builtin_amdgcn_mfma_f32_16x16x32_bf16(Ah, Bh, acc0, 0, 0, 0);
                    if (TERMS == 3)
                        acc0 = __builtin_amdgcn_mfma_f32_16x16x32_bf16(pAl[u % 5], Bh, acc0, 0, 0, 0);
                    acc0 = __builtin_amdgcn_mfma_f32_16x16x32_bf16(Ah, Bl, acc0, 0, 0, 0);
                }
            }
            if (s < 18) {
                const int t = s >> 1, cc2 = s & 1;
                const int ky = t / 3, kx = t % 3;
                const int ccor = base + cc2;
                const ushort_t* ab =
                    wfrag + (((size_t)(t * KCfull + ccor) * OTN + ot) * 64 + lane) * 8;
                pAh[s % 5] = *(const bf16x8*)ab;
                if (TERMS == 3) pAl[s % 5] = *(const bf16x8*)(ab + hlOff);
                const int lb = (ky * 18 + n + kx) * 72 + cc2 * 32 + quad * 8;
                pBh[s % 5] = *(const bf16x8*)(ldsH + lb);
                pBl[s % 5] = *(const bf16x8*)(ldsL + lb);
            }
        }
    }

    const int px = y * 96 + xb + n;
    if (RAW) {
        // planar packed-u32 raw output (448 rows; bias only for cout<432)
#pragma unroll
        for (int r = 0; r < 4; ++r) {
            int cout = ot * 16 + quad * 4 + r;
            float v = acc0[r] + acc1[r] + (cout < 432 ? bias[cout] : 0.f);
            outpk[(size_t)cout * HW96 + px] = pk(v);
        }
    } else {
#pragma unroll
        for (int r = 0; r < 4; ++r) {
            int cout = ot * 16 + quad * 4 + r;
            float v = acc0[r] + acc1[r] + bias[cout];
            if (act) v = (v >= 0.f) ? v : 0.1f * v;
            if (addsrc) v += addsrc[(size_t)cout * HW96 + px];
            outpk[(size_t)px * 64 + cout] = pk(v);
        }
    }
}

// ---------------------------------------------------------------------------
// De-fused modulated deformable conv: gather + dconv MFMA only.
// raw (ow4 output) is read from global (planar packed u32, [448][9216]).
// K-split: grid 1152 = 576 seg x 2; half h handles gc rounds
// [h*ngr4/2, (h+1)*ngr4/2); partial sums to pacc[h]. LDS = cols only
// (18.9 KB) -> 4.5 blocks/CU, 18 waves/CU (2x the fused kernel).
// ---------------------------------------------------------------------------
__global__ __launch_bounds__(256) void dconv_lite_k(
    const unsigned* __restrict__ sA, const unsigned* __restrict__ sB,
    const unsigned* __restrict__ rawpk, const ushort_t* __restrict__ dwf,
    int ngr4, float* __restrict__ pacc) {
    const int tid = threadIdx.x;
    const int lane = tid & 63;
    const int w = tid >> 6;
    const int h = blockIdx.x & 1;
    const int seg = blockIdx.x >> 1;
    const int xb = (seg % 6) * 16;
    const int y = seg / 6;
    const int n = lane & 15;
    const int quad = lane >> 4;

    __shared__ __align__(16) ushort_t colsH[16 * 296];
    __shared__ __align__(16) ushort_t colsL[16 * 296];

    f32x4 acc0, acc1;
#pragma unroll
    for (int r = 0; r < 4; ++r) { acc0[r] = 0.f; acc1[r] = 0.f; }
    const size_t hlD = (size_t)36 * 4 * 512;
    const int nrounds = ngr4 >> 1;  // 1 or 2 per half

    for (int gci = 0; gci < nrounds; ++gci) {
        const int gc = h * nrounds + gci;
        __syncthreads();  // cols reuse safe
#pragma unroll
        for (int i = 0; i < 3; ++i) {
            int e = tid + i * 256;
            if (e < 576) {
                int p = e & 15;
                int r = e >> 4;  // 0..35
                int gl = r / 9, k = r - gl * 9;
                int g = gc * 4 + gl;
                int gpx = y * 96 + xb + p;
                float ry = unpk(rawpk[(size_t)(g * 18 + k * 2 + 0) * HW96 + gpx]);
                float rx = unpk(rawpk[(size_t)(g * 18 + k * 2 + 1) * HW96 + gpx]);
                float rm = unpk(rawpk[(size_t)(288 + g * 9 + k) * HW96 + gpx]);
                float oy = 5.f * (1.f - 2.f / (1.f + __expf(2.f * ry)));
                float ox = 5.f * (1.f - 2.f / (1.f + __expf(2.f * rx)));
                float m = 1.f / (1.f + __expf(-rm));
                float sy = oy + (float)(y - 1 + k / 3);
                float sx = ox + (float)(xb + p - 1 + k % 3);
                float fy0 = floorf(sy), fx0 = floorf(sx);
                float fy = sy - fy0, fx = sx - fx0;
                int y0 = (int)fy0, x0 = (int)fx0;
                int y1 = y0 + 1, x1 = x0 + 1;
                bool vy0 = (unsigned)y0 < 96u, vy1 = (unsigned)y1 < 96u;
                bool vx0 = (unsigned)x0 < 96u, vx1 = (unsigned)x1 < 96u;
                int cy0 = min(max(y0, 0), 95), cy1 = min(max(y1, 0), 95);
                int cx0 = min(max(x0, 0), 95), cx1 = min(max(x1, 0), 95);
                float w00 = (1.f - fy) * (1.f - fx) * ((vy0 && vx0) ? 1.f : 0.f);
                float w01 = (1.f - fy) * fx * ((vy0 && vx1) ? 1.f : 0.f);
                float w10 = fy * (1.f - fx) * ((vy1 && vx0) ? 1.f : 0.f);
                float w11 = fy * fx * ((vy1 && vx1) ? 1.f : 0.f);
                const unsigned* src = (g < 8) ? sA : sB;
                int cb = (g & 7) * 8;
                int kbase = p * 296 + gl * 72 + k * 8;
                ushort_t hh[8], ll[8];
                if (src) {
                    int b00 = (cy0 * 96 + cx0) * 64 + cb;
                    int b01 = (cy0 * 96 + cx1) * 64 + cb;
                    int b10 = (cy1 * 96 + cx0) * 64 + cb;
                    int b11 = (cy1 * 96 + cx1) * 64 + cb;
                    u32x4 c00a = *(const u32x4*)(src + b00);
                    u32x4 c00b = *(const u32x4*)(src + b00 + 4);
                    u32x4 c01a = *(const u32x4*)(src + b01);
                    u32x4 c01b = *(const u32x4*)(src + b01 + 4);
                    u32x4 c10a = *(const u32x4*)(src + b10);
                    u32x4 c10b = *(const u32x4*)(src + b10 + 4);
                    u32x4 c11a = *(const u32x4*)(src + b11);
                    u32x4 c11b = *(const u32x4*)(src + b11 + 4);
#pragma unroll
                    for (int c = 0; c < 4; ++c) {
                        float v = w00 * unpk(c00a[c]) + w01 * unpk(c01a[c]) +
                                  w10 * unpk(c10a[c]) + w11 * unpk(c11a[c]);
                        split16(v * m, hh[c], ll[c]);
                        float v2 = w00 * unpk(c00b[c]) + w01 * unpk(c01b[c]) +
                                   w10 * unpk(c10b[c]) + w11 * unpk(c11b[c]);
                        split16(v2 * m, hh[4 + c], ll[4 + c]);
                    }
                } else {
#pragma unroll
                    for (int c = 0; c < 8; ++c) { hh[c] = 0; ll[c] = 0; }
                }
                u32x4 H, L;
#pragma unroll
                for (int q = 0; q < 4; ++q) {
                    H[q] = (unsigned)hh[2 * q] | ((unsigned)hh[2 * q + 1] << 16);
                    L[q] = (unsigned)ll[2 * q] | ((unsigned)ll[2 * q + 1] << 16);
                }
                *(u32x4*)(colsH + kbase) = H;
                *(u32x4*)(colsL + kbase) = L;
            }
        }
        __syncthreads();
        bf16x8 qAh[4], qAl[4], qBh[4], qBl[4];
#pragma unroll
        for (int s = 0; s < 13; ++s) {
            if (s >= 4) {  // consume BEFORE refilling the slot
                const int u = s - 4;
                const bf16x8 Ah = qAh[u % 4], Al = qAl[u % 4];
                const bf16x8 Bh = qBh[u % 4], Bl = qBl[u % 4];
                if (u & 1) {
                    acc1 = __builtin_amdgcn_mfma_f32_16x16x32_bf16(Ah, Bh, acc1, 0, 0, 0);
                    acc1 = __builtin_amdgcn_mfma_f32_16x16x32_bf16(Al, Bh, acc1, 0, 0, 0);
                    acc1 = __builtin_amdgcn_mfma_f32_16x16x32_bf16(Ah, Bl, acc1, 0, 0, 0);
                } else {
                    acc0 = __builtin_amdgcn_mfma_f32_16x16x32_bf16(Ah, Bh, acc0, 0, 0, 0);
                    acc0 = __builtin_amdgcn_mfma_f32_16x16x32_bf16(Al, Bh, acc0, 0, 0, 0);
                    acc0 = __builtin_amdgcn_mfma_f32_16x16x32_bf16(Ah, Bl, acc0, 0, 0, 0);
                }
            }
            if (s < 9) {
                const int cc = gc * 9 + s;
                const ushort_t* ab = dwf + (((size_t)cc * 4 + w) * 64 + lane) * 8;
                qAh[s % 4] = *(const bf16x8*)ab;
                qAl[s % 4] = *(const bf16x8*)(ab + hlD);
                const int lb = n * 296 + s * 32 + quad * 8;
                qBh[s % 4] = *(const bf16x8*)(colsH + lb);
                qBl[s % 4] = *(const bf16x8*)(colsL + lb);
            }
        }
    }

    const int pidx = y * 96 + xb + n;
#pragma unroll
    for (int r = 0; r < 4; ++r) {
        int cout = w * 16 + quad * 4 + r;
        pacc[(size_t)h * FRAME + (size_t)cout * HW96 + pidx] =
            acc0[r] + acc1[r];
    }
}

// ---------------------------------------------------------------------------
// Combine dconv partials: Dbuf = pacc0+pacc1+bias (planar fp32) and
// Dpk (interleaved packed) via padded-LDS transpose. grid 144.
// ---------------------------------------------------------------------------
__global__ __launch_bounds__(256) void dcomb_k(const float* __restrict__ pacc,
                                               const float* __restrict__ dbias,
                                               float* __restrict__ outf,
                                               unsigned* __restrict__ outpk) {
    const int px0 = blockIdx.x * 64;
    __shared__ unsigned tile[64 * 65];
#pragma unroll
    for (int it = 0; it < 16; ++it) {
        int e = it * 256 + threadIdx.x;
        int p = e & 63, ch = e >> 6;
        size_t off = (size_t)ch * HW96 + px0 + p;
        float v = pacc[off] + pacc[(size_t)FRAME + off] + dbias[ch];
        outf[off] = v;
        tile[ch * 65 + p] = pk(v);
    }
    __syncthreads();
#pragma unroll
    for (int it = 0; it < 16; ++it) {
        int e = it * 256 + threadIdx.x;
        int ch = e & 63, p = e >> 6;
        outpk[(size_t)(px0 + p) * 64 + ch] = tile[ch * 65 + p];
    }
}

// ---------------------------------------------------------------------------
// Fusion: 1x1 conv over [featB[t], featF[t]] (interleaved) + bias + x.
// ---------------------------------------------------------------------------
__global__ __launch_bounds__(256) void fuse_k(
    const unsigned* __restrict__ featB, const unsigned* __restrict__ featF,
    const float* __restrict__ x, const float* __restrict__ wp,
    const float* __restrict__ bias, float* __restrict__ out) {
    const int tx = threadIdx.x & 31;
    const int ty = threadIdx.x >> 5;
    const int px = blockIdx.x * 32 + tx;
    const int py = blockIdx.y * 8 + ty;
    const int t = blockIdx.z >> 3;
    const int obase = (blockIdx.z & 7) * 8;
    const int pidx = py * 96 + px;
    const unsigned* fB = featB + (size_t)t * FRAME + (size_t)pidx * 64;
    const unsigned* fF = featF + (size_t)t * FRAME + (size_t)pidx * 64;

    float acc[8];
#pragma unroll
    for (int o = 0; o < 8; ++o) acc[o] = 0.f;

#pragma unroll 4
    for (int i0 = 0; i0 < 64; i0 += 4) {
        u32x4 pv = *(const u32x4*)(fB + i0);
#pragma unroll
        for (int q = 0; q < 4; ++q) {
            float v = unpk(pv[q]);
            const float* wr = wp + (i0 + q) * 64 + obase;
#pragma unroll
            for (int o = 0; o < 8; ++o) acc[o] = fmaf(wr[o], v, acc[o]);
        }
    }
#pragma unroll 4
    for (int i0 = 0; i0 < 64; i0 += 4) {
        u32x4 pv = *(const u32x4*)(fF + i0);
#pragma unroll
        for (int q = 0; q < 4; ++q) {
            float v = unpk(pv[q]);
            const float* wr = wp + (64 + i0 + q) * 64 + obase;
#pragma unroll
            for (int o = 0; o < 8; ++o) acc[o] = fmaf(wr[o], v, acc[o]);
        }
    }
    const float* xt = x + (size_t)t * FRAME;
#pragma unroll
    for (int o = 0; o < 8; ++o)
        out[(size_t)t * FRAME + (size_t)(obase + o) * HW96 + pidx] =
            acc[o] + bias[obase + o] + xt[(size_t)(obase + o) * HW96 + pidx];
}

// ---------------------------------------------------------------------------
extern "C" void kernel_launch(void* const* d_in, const int* in_sizes, int n_in,
                              void* d_out, int out_size, void* d_ws,
                              size_t ws_size, hipStream_t stream) {
    const float* x = (const float*)d_in[0];
    auto gp = [&](int i) { return (const float*)d_in[i]; };

    struct DirP {
        const float *dw, *db, *ow1, *ob1, *ow2, *ob2, *ow3, *ob3, *ow4, *ob4,
            *bw1, *bb1, *bw2, *bb2;
    };
    DirP Pb{gp(1), gp(2), gp(3), gp(4), gp(5), gp(6), gp(7),
            gp(8), gp(9), gp(10), gp(11), gp(12), gp(13), gp(14)};
    DirP Pf{gp(15), gp(16), gp(17), gp(18), gp(19), gp(20), gp(21),
            gp(22), gp(23), gp(24), gp(25), gp(26), gp(27), gp(28)};
    const float* fus_w = gp(29);
    const float* fus_b = gp(30);

    // ---- workspace carve-up (4-byte units); all feature bufs interleaved ----
    unsigned* featBpk = (unsigned*)d_ws;
    unsigned* featFpk = featBpk + (size_t)8 * FRAME;
    unsigned* xpk = featFpk + (size_t)8 * FRAME;
    float* Dbuf = (float*)(xpk + (size_t)8 * FRAME);  // planar fp32
    unsigned* Dpk = (unsigned*)(Dbuf + FRAME);        // interleaved packed
    unsigned* hApk = Dpk + FRAME;
    unsigned* hBpk = hApk + FRAME;
    float* wfus = (float*)(hBpk + FRAME);
    ushort_t* fragp = (ushort_t*)(wfus + 128 * 64);

    auto falloc = [&](size_t nelem) {
        ushort_t* p = fragp;
        fragp += nelem;
        return p;
    };

    // ---- weight prep ----
    repack_fus_k<<<32, 256, 0, stream>>>(fus_w, wfus);

    struct DirW { ushort_t *ow1, *ow2, *ow3, *ow4, *bw1, *bw2, *dw; int bw1KC; };
    FragJobs fj;
    int nf = 0;
    auto fjob = [&](const float* src, int O, int I, int OT, int KC) {
        ushort_t* dst = falloc((size_t)2 * 9 * KC * OT * 512);
        fj.j[nf++] = FragJob{src, dst, O, I, OT, KC, 0};
        return dst;
    };
    auto fjobd = [&](const float* src) {
        ushort_t* dst = falloc((size_t)2 * 36 * 4 * 512);
        fj.j[nf++] = FragJob{src, dst, 64, 128, 4, 36, 1};
        return dst;
    };
    DirW Wb, Wf;
    Wb.ow1 = fjob(Pb.ow1, 64, 192, 4, 6);
    Wb.ow2 = fjob(Pb.ow2, 64, 64, 4, 2);
    Wb.ow3 = fjob(Pb.ow3, 64, 64, 4, 2);
    Wb.ow4 = fjob(Pb.ow4, 432, 64, 28, 2);
    Wb.bw1 = fjob(Pb.bw1, 64, 128, 4, 4);
    Wb.bw1KC = 4;
    Wb.bw2 = fjob(Pb.bw2, 64, 64, 4, 2);
    Wb.dw = fjobd(Pb.dw);
    Wf.ow1 = fjob(Pf.ow1, 64, 192, 4, 6);
    Wf.ow2 = fjob(Pf.ow2, 64, 64, 4, 2);
    Wf.ow3 = fjob(Pf.ow3, 64, 64, 4, 2);
    Wf.ow4 = fjob(Pf.ow4, 432, 64, 28, 2);
    Wf.bw1 = fjob(Pf.bw1, 64, 192, 4, 6);
    Wf.bw1KC = 6;
    Wf.bw2 = fjob(Pf.bw2, 64, 64, 4, 2);
    Wf.dw = fjobd(Pf.dw);
    frag_all_k<<<dim3(1008, 14), 256, 0, stream>>>(fj);

    // de-fused dconv scratch: raw (448 x 9216 packed u32) + pacc (2 x FRAME f32)
    unsigned* rawpk = (unsigned*)((((uintptr_t)fragp) + 15) & ~(uintptr_t)15);
    float* pacc = (float*)(rawpk + (size_t)448 * HW96);

    pack_tr_k<<<dim3(144, 8), 256, 0, stream>>>(x, xpk);

    auto convm = [&](const unsigned* a, const unsigned* b, const unsigned* c2,
                     const ushort_t* frag, int KCfull, const float* bias,
                     const float* addsrc, unsigned* out, int act, int terms) {
        const unsigned* srcs[3] = {a, b, c2};
        const unsigned* S[3] = {nullptr, nullptr, nullptr};
        int B[3] = {0, 0, 0};
        int ns = 0;
        for (int j = 0; j < 3; ++j)
            if (srcs[j]) {
                S[ns] = srcs[j];
                B[ns] = j * 2;
                ++ns;
            }
        if (terms == 2)
            convm_k<2, 4, 0><<<1152, 128, 0, stream>>>(
                S[0], S[1], S[2], B[0], B[1], B[2], ns, frag, KCfull, bias,
                addsrc, out, act);
        else
            convm_k<3, 4, 0><<<1152, 128, 0, stream>>>(
                S[0], S[1], S[2], B[0], B[1], B[2], ns, frag, KCfull, bias,
                addsrc, out, act);
    };

    for (int dir = 0; dir < 2; ++dir) {  // 0 = backward, 1 = forward
        const DirP& P = dir ? Pf : Pb;
        const DirW& W = dir ? Wf : Wb;
        unsigned* feat = dir ? featFpk : featBpk;
        const unsigned* prev1 = nullptr;
        const unsigned* prev2 = nullptr;
        for (int i = 0; i < 8; ++i) {
            int idx = dir ? i : 7 - i;
            const unsigned* cur = xpk + (size_t)idx * FRAME;
            const float* propf = nullptr;
            if (i > 0) {
                // offset/mask path: 2-term (weight-lo dropped)
                convm(prev1, cur, prev2, W.ow1, 6, P.ob1, nullptr, hApk, 1, 2);
                convm(hApk, nullptr, nullptr, W.ow2, 2, P.ob2, nullptr, hBpk, 1, 2);
                convm(hBpk, nullptr, nullptr, W.ow3, 2, P.ob3, nullptr, hApk, 1, 2);
                // ow4 (64->432), 2-term, planar packed raw out, 14 ot-groups
                convm_k<2, 28, 1><<<576 * 14, 128, 0, stream>>>(
                    hApk, nullptr, nullptr, 0, 0, 0, 1, W.ow4, 2, P.ob4,
                    nullptr, rawpk, 0);
                int ngr4 = (prev2 != nullptr) ? 4 : 2;
                dconv_lite_k<<<1152, 256, 0, stream>>>(prev1, prev2, rawpk,
                                                       W.dw, ngr4, pacc);
                dcomb_k<<<144, 256, 0, stream>>>(pacc, P.db, Dbuf, Dpk);
                propf = Dbuf;
            }
            unsigned* dst = feat + (size_t)idx * FRAME;
            // feature path: keep 3-term
            if (dir == 0) {
                convm(cur, (i > 0) ? Dpk : nullptr, nullptr, W.bw1, W.bw1KC,
                      P.bb1, nullptr, hBpk, 1, 3);
            } else {
                convm(cur, featBpk + (size_t)idx * FRAME,
                      (i > 0) ? Dpk : nullptr, W.bw1, W.bw1KC, P.bb1, nullptr,
                      hBpk, 1, 3);
            }
            convm(hBpk, nullptr, nullptr, W.bw2, 2, P.bb2, propf, dst, 0, 3);
            prev2 = prev1;
            prev1 = dst;
        }
    }

    fuse_k<<<dim3(3, 12, 64), 256, 0, stream>>>(featBpk, featFpk, x, wfus,
                                                fus_b, (float*)d_out);
}

// Round 8
// 1644.595 us; speedup vs baseline: 1.0925x; 1.0925x over previous
//
#include <hip/hip_runtime.h>
#include <cstddef>
#include <cstdint>

#define HW96 9216
#define FRAME (64 * 9216)

typedef unsigned short ushort_t;
typedef __attribute__((ext_vector_type(8))) short bf16x8;
typedef __attribute__((ext_vector_type(4))) float f32x4;
typedef __attribute__((ext_vector_type(4))) unsigned u32x4;

// packed u32 = (bf16 hi bits << 16) | bf16 lo bits; value = hi + lo exactly
__device__ __forceinline__ float unpk(unsigned p) {
    return __uint_as_float(p & 0xFFFF0000u) + __uint_as_float(p << 16);
}
__device__ __forceinline__ unsigned pk(float v) {
    unsigned u = __float_as_uint(v);
    unsigned hi = u & 0xFFFF0000u;
    float rem = v - __uint_as_float(hi);
    unsigned r = __float_as_uint(rem);
    unsigned lo = (r + 0x7FFFu + ((r >> 16) & 1u)) >> 16;
    return hi | (lo & 0xFFFFu);
}
__device__ __forceinline__ void split16(float v, ushort_t& h, ushort_t& l) {
    unsigned u = __float_as_uint(v);
    h = (ushort_t)(u >> 16);
    float rem = v - __uint_as_float(u & 0xFFFF0000u);
    unsigned r = __float_as_uint(rem);
    l = (ushort_t)((r + 0x7FFFu + ((r >> 16) & 1u)) >> 16);
}

// ---------------------------------------------------------------------------
// Plain repack: OIHW -> [i][o] fp32 (fusion 1x1 only).
// ---------------------------------------------------------------------------
__global__ __launch_bounds__(256) void repack_fus_k(const float* __restrict__ w,
                                                    float* __restrict__ wp) {
    int idx = blockIdx.x * 256 + threadIdx.x;  // 128*64
    if (idx >= 128 * 64) return;
    int o = idx % 64;
    int i = idx / 64;
    wp[idx] = w[o * 128 + i];
}

// ---------------------------------------------------------------------------
// MFMA A-fragment prepack (16x16x32) with bf16 hi/lo split.
// mode 0 (3x3 conv): layout [hl][t][cc][ot][lane][j]; K = cin chunks of 32.
// mode 1 (dconv):    layout [hl][cc][ot][lane][j]; K = g*72 + tap*8 + c.
// A[m=lane&15][k=(lane>>4)*8+j].
// ---------------------------------------------------------------------------
struct FragJob { const float* src; ushort_t* dst; int O, I, OT, KC, mode; };
struct FragJobs { FragJob j[14]; };

__global__ __launch_bounds__(256) void frag_all_k(FragJobs jobs) {
    const FragJob& J = jobs.j[blockIdx.y];
    int idx = blockIdx.x * 256 + threadIdx.x;
    int total = (J.mode ? 1 : 9) * J.KC * J.OT * 512;
    if (idx >= total) return;
    int jj = idx & 7;
    int lane = (idx >> 3) & 63;
    int rem = idx >> 9;
    int ot = rem % J.OT;
    rem /= J.OT;
    int cc = rem % J.KC;
    int t = rem / J.KC;
    int o = ot * 16 + (lane & 15);
    float wv = 0.f;
    if (J.mode == 0) {
        int ci = cc * 32 + (lane >> 4) * 8 + jj;
        if (o < J.O && ci < J.I) wv = J.src[(o * J.I + ci) * 9 + t];
    } else {
        int K = cc * 32 + (lane >> 4) * 8 + jj;
        int g = K / 72, r2 = K % 72;
        int tap = r2 >> 3, c = r2 & 7;
        int ci = g * 8 + c;
        if (o < J.O && ci < J.I) wv = J.src[(o * J.I + ci) * 9 + tap];
    }
    ushort_t h, l;
    split16(wv, h, l);
    J.dst[idx] = h;
    J.dst[total + idx] = l;
}

// ---------------------------------------------------------------------------
// Transposing pack: planar fp32 frames -> interleaved [px][64ch] packed u32.
// Block handles one 64-px x 64-ch tile via padded LDS. grid (144, T).
// ---------------------------------------------------------------------------
__global__ __launch_bounds__(256) void pack_tr_k(const float* __restrict__ src,
                                                 unsigned* __restrict__ dst) {
    const int t = blockIdx.y;
    const int px0 = blockIdx.x * 64;
    __shared__ unsigned tile[64 * 65];
    const float* s = src + (size_t)t * FRAME;
    unsigned* d = dst + (size_t)t * FRAME;
#pragma unroll
    for (int it = 0; it < 16; ++it) {
        int e = it * 256 + threadIdx.x;
        int p = e & 63, ch = e >> 6;
        tile[ch * 65 + p] = pk(s[(size_t)ch * HW96 + px0 + p]);
    }
    __syncthreads();
#pragma unroll
    for (int it = 0; it < 16; ++it) {
        int e = it * 256 + threadIdx.x;
        int ch = e & 63, p = e >> 6;
        d[(size_t)(px0 + p) * 64 + ch] = tile[ch * 65 + p];
    }
}

// ---------------------------------------------------------------------------
// MFMA implicit-GEMM 3x3 conv, 16x16x32 bf16.
// TERMS=3: AhBh + AlBh + AhBl (fp32-grade, feature path).
// TERMS=2: AhBh + AhBl (weight-lo dropped; offset/mask path).
// 128 thr = 2 waves; block = 32 couts (half) x 16 px; grid 1152.
// Depth-5 rolling pipeline, consume-before-fill ring discipline.
// ---------------------------------------------------------------------------
template <int TERMS>
__global__ __launch_bounds__(128, 3) void convm_k(
    const unsigned* __restrict__ s0, const unsigned* __restrict__ s1,
    const unsigned* __restrict__ s2, int b0, int b1, int b2, int nsrc,
    const ushort_t* __restrict__ wfrag, int KCfull,
    const float* __restrict__ bias, const float* __restrict__ addsrc,
    unsigned* __restrict__ outpk, int act) {
    const int tid = threadIdx.x;
    const int lane = tid & 63;
    const int w = tid >> 6;              // 0..1
    const int h = blockIdx.x & 1;       // cout half
    const int bseg = blockIdx.x >> 1;   // px segment
    const int ot = h * 2 + w;           // global out-tile 0..3
    const int xb = (bseg % 6) * 16;
    const int y = bseg / 6;
    const int n = lane & 15;
    const int quad = lane >> 4;

    __shared__ __align__(16) ushort_t ldsH[3 * 18 * 72];
    __shared__ __align__(16) ushort_t ldsL[3 * 18 * 72];

    // staging job decode (loop-invariant): 432 jobs = 54 (r,c) x 8 octets
    int jst[4], jok[4], joff[4], jbase[4];
#pragma unroll
    for (int i = 0; i < 4; ++i) {
        int e = tid + i * 128;
        int rc = e >> 3, cg = e & 7;
        int r = rc / 18, col = rc - r * 18;
        int gy = y - 1 + r, gx = xb - 1 + col;
        jst[i] = (e < 432);
        jok[i] = jst[i] && ((unsigned)gy < 96u) && ((unsigned)gx < 96u);
        joff[i] = (gy * 96 + gx) * 64 + cg * 8;
        jbase[i] = rc * 72 + cg * 8;
    }

    f32x4 acc0, acc1;
#pragma unroll
    for (int r = 0; r < 4; ++r) { acc0[r] = 0.f; acc1[r] = 0.f; }

    const size_t hlOff = (size_t)9 * KCfull * 4 * 512;

    for (int j = 0; j < nsrc; ++j) {
        const unsigned* sv = (j == 0) ? s0 : (j == 1 ? s1 : s2);
        const int base = (j == 0) ? b0 : (j == 1 ? b1 : b2);
        __syncthreads();
#pragma unroll
        for (int i = 0; i < 4; ++i) {
            if (jst[i]) {
                u32x4 a, b;
                if (jok[i]) {
                    a = *(const u32x4*)(sv + joff[i]);
                    b = *(const u32x4*)(sv + joff[i] + 4);
                } else {
#pragma unroll
                    for (int q = 0; q < 4; ++q) { a[q] = 0; b[q] = 0; }
                }
                u32x4 H, L;
#pragma unroll
                for (int q = 0; q < 2; ++q) {
                    H[q] = (a[2 * q] >> 16) | (a[2 * q + 1] & 0xFFFF0000u);
                    L[q] = (a[2 * q] & 0xFFFFu) | (a[2 * q + 1] << 16);
                    H[2 + q] = (b[2 * q] >> 16) | (b[2 * q + 1] & 0xFFFF0000u);
                    L[2 + q] = (b[2 * q] & 0xFFFFu) | (b[2 * q + 1] << 16);
                }
                *(u32x4*)(ldsH + jbase[i]) = H;
                *(u32x4*)(ldsL + jbase[i]) = L;
            }
        }
        __syncthreads();
        // depth-5 rolling pipeline over 18 steps (t = s>>1, cc2 = s&1)
        bf16x8 pAh[5], pAl[5], pBh[5], pBl[5];
#pragma unroll
        for (int s = 0; s < 23; ++s) {
            if (s >= 5) {  // consume BEFORE refilling the slot
                const int u = s - 5;
                const bf16x8 Ah = pAh[u % 5];
                const bf16x8 Bh = pBh[u % 5], Bl = pBl[u % 5];
                if (u & 1) {
                    acc1 = __builtin_amdgcn_mfma_f32_16x16x32_bf16(Ah, Bh, acc1, 0, 0, 0);
                    if (TERMS == 3)
                        acc1 = __builtin_amdgcn_mfma_f32_16x16x32_bf16(pAl[u % 5], Bh, acc1, 0, 0, 0);
                    acc1 = __builtin_amdgcn_mfma_f32_16x16x32_bf16(Ah, Bl, acc1, 0, 0, 0);
                } else {
                    acc0 = __builtin_amdgcn_mfma_f32_16x16x32_bf16(Ah, Bh, acc0, 0, 0, 0);
                    if (TERMS == 3)
                        acc0 = __builtin_amdgcn_mfma_f32_16x16x32_bf16(pAl[u % 5], Bh, acc0, 0, 0, 0);
                    acc0 = __builtin_amdgcn_mfma_f32_16x16x32_bf16(Ah, Bl, acc0, 0, 0, 0);
                }
            }
            if (s < 18) {
                const int t = s >> 1, cc2 = s & 1;
                const int ky = t / 3, kx = t % 3;
                const int ccor = base + cc2;
                const ushort_t* ab =
                    wfrag + (((size_t)(t * KCfull + ccor) * 4 + ot) * 64 + lane) * 8;
                pAh[s % 5] = *(const bf16x8*)ab;
                if (TERMS == 3) pAl[s % 5] = *(const bf16x8*)(ab + hlOff);
                const int lb = (ky * 18 + n + kx) * 72 + cc2 * 32 + quad * 8;
                pBh[s % 5] = *(const bf16x8*)(ldsH + lb);
                pBl[s % 5] = *(const bf16x8*)(ldsL + lb);
            }
        }
    }

    const int px = y * 96 + xb + n;
#pragma unroll
    for (int r = 0; r < 4; ++r) {
        int cout = ot * 16 + quad * 4 + r;
        float v = acc0[r] + acc1[r] + bias[cout];
        if (act) v = (v >= 0.f) ? v : 0.1f * v;
        if (addsrc) v += addsrc[(size_t)cout * HW96 + px];
        outpk[(size_t)px * 64 + cout] = pk(v);
    }
}

// ---------------------------------------------------------------------------
// Fused ow4 + modulated deformable conv, HALF-SPLIT: grid 1152 = 576 seg x 2.
// Half h owns groups [h*ng, (h+1)*ng), ng = 4*(ngr4/2). Phase 2 computes
// exactly the ow4 out-tiles covering that group span's offset rows
// [g0*18, g0*18+ng*18) and mask rows [288+g0*9, +ng*9) — ranges DERIVED from
// ngr4 (round-7 bug: hard-coded ngr4=4 partition broke the ngr4=2 dconvs).
// Contiguous ot ranges => local rawS row = global - rowOff (plain offsets).
// LDS 34.2 KB -> 4 blocks/CU, 16 waves/CU for the latency-bound gather.
// ---------------------------------------------------------------------------
__global__ __launch_bounds__(256) void dconv_fused_k(
    const unsigned* __restrict__ sA, const unsigned* __restrict__ sB,
    const unsigned* __restrict__ hA, const ushort_t* __restrict__ w4,
    const float* __restrict__ ob4, const ushort_t* __restrict__ dwf,
    int ngr4, float* __restrict__ pacc) {
    const int tid = threadIdx.x;
    const int lane = tid & 63;
    const int w = tid >> 6;
    const int h = blockIdx.x & 1;
    const int seg = blockIdx.x >> 1;
    const int xb = (seg % 6) * 16;
    const int y = seg / 6;
    const int n = lane & 15;
    const int quad = lane >> 4;

    __shared__ __align__(16) char smem[15232 + 18944];
    float* rawS = (float*)smem;               // up to [224][17] fp32
    ushort_t* ldsAH = (ushort_t*)(smem + 15232);  // 3888 ushorts
    ushort_t* ldsAL = ldsAH + 3888;               // (15552 B <= 18944)
    ushort_t* colsH = (ushort_t*)(smem + 15232);  // union with ldsA
    ushort_t* colsL = colsH + 4736;

    // ---- out-tile ranges for this half (derived from ngr4) ----
    const int nrounds = ngr4 >> 1;   // 1 or 2
    const int ng = nrounds * 4;      // groups per half
    const int g0 = h * ng;
    const int otO_s = (g0 * 18) >> 4;
    const int otO_e = (g0 * 18 + ng * 18 - 1) >> 4;
    const int nO = otO_e - otO_s + 1;
    const int otM_s = (288 + g0 * 9) >> 4;
    const int otM_e = (288 + g0 * 9 + ng * 9 - 1) >> 4;
    const int nM = otM_e - otM_s + 1;
    const int nt = nO + nM;          // 14 (ngr4=4) or 8 (ngr4=2)
    const int rowOffO = otO_s * 16;
    const int rowOffM = otM_s * 16 - nO * 16;

    // ---- phase 1: stage hA window (interleaved source) ----
#pragma unroll
    for (int i = 0; i < 2; ++i) {
        int e = tid + i * 256;
        if (e < 432) {
            int rc = e >> 3, cg = e & 7;
            int r = rc / 18, col = rc - r * 18;
            int gy = y - 1 + r, gx = xb - 1 + col;
            bool ok = ((unsigned)gy < 96u) && ((unsigned)gx < 96u);
            u32x4 a, b;
            if (ok) {
                int off = (gy * 96 + gx) * 64 + cg * 8;
                a = *(const u32x4*)(hA + off);
                b = *(const u32x4*)(hA + off + 4);
            } else {
#pragma unroll
                for (int q = 0; q < 4; ++q) { a[q] = 0; b[q] = 0; }
            }
            u32x4 H, L;
#pragma unroll
            for (int q = 0; q < 2; ++q) {
                H[q] = (a[2 * q] >> 16) | (a[2 * q + 1] & 0xFFFF0000u);
                L[q] = (a[2 * q] & 0xFFFFu) | (a[2 * q + 1] << 16);
                H[2 + q] = (b[2 * q] >> 16) | (b[2 * q + 1] & 0xFFFF0000u);
                L[2 + q] = (b[2 * q] & 0xFFFFu) | (b[2 * q + 1] << 16);
            }
            *(u32x4*)(ldsAH + rc * 72 + cg * 8) = H;
            *(u32x4*)(ldsAL + rc * 72 + cg * 8) = L;
        }
    }
    __syncthreads();

    // ---- phase 2: needed ow4 out-tiles, 2-term, depth-5 pipeline ----
#pragma unroll 1
    for (int j = 0; j < 4; ++j) {
        const int idx = j * 4 + w;
        if (idx >= nt) break;
        const int ot = (idx < nO) ? (otO_s + idx) : (otM_s + (idx - nO));
        f32x4 a0, a1;
#pragma unroll
        for (int r = 0; r < 4; ++r) { a0[r] = 0.f; a1[r] = 0.f; }
        bf16x8 pAh[5], pBh[5], pBl[5];
#pragma unroll
        for (int s = 0; s < 23; ++s) {
            if (s >= 5) {  // consume BEFORE refilling the slot
                const int u = s - 5;
                const bf16x8 Ah = pAh[u % 5];
                const bf16x8 Bh = pBh[u % 5], Bl = pBl[u % 5];
                if (u & 1) {
                    a1 = __builtin_amdgcn_mfma_f32_16x16x32_bf16(Ah, Bh, a1, 0, 0, 0);
                    a1 = __builtin_amdgcn_mfma_f32_16x16x32_bf16(Ah, Bl, a1, 0, 0, 0);
                } else {
                    a0 = __builtin_amdgcn_mfma_f32_16x16x32_bf16(Ah, Bh, a0, 0, 0, 0);
                    a0 = __builtin_amdgcn_mfma_f32_16x16x32_bf16(Ah, Bl, a0, 0, 0, 0);
                }
            }
            if (s < 18) {
                const int t = s >> 1, cc2 = s & 1;
                const int ky = t / 3, kx = t % 3;
                const ushort_t* ab =
                    w4 + (((size_t)s * 28 + ot) * 64 + lane) * 8;
                pAh[s % 5] = *(const bf16x8*)ab;
                const int lb = (ky * 18 + n + kx) * 72 + cc2 * 32 + quad * 8;
                pBh[s % 5] = *(const bf16x8*)(ldsAH + lb);
                pBl[s % 5] = *(const bf16x8*)(ldsAL + lb);
            }
        }
#pragma unroll
        for (int r = 0; r < 4; ++r) {
            int cout = ot * 16 + quad * 4 + r;
            float v = a0[r] + a1[r] + (cout < 432 ? ob4[cout] : 0.f);
            rawS[(idx * 16 + quad * 4 + r) * 17 + n] = v;
        }
    }

    // ---- phase 3: gather + dconv MFMA (3-term, depth-4 pipeline) ----
    f32x4 acc0, acc1;
#pragma unroll
    for (int r = 0; r < 4; ++r) { acc0[r] = 0.f; acc1[r] = 0.f; }
    const size_t hlD = (size_t)36 * 4 * 512;

    for (int gci = 0; gci < nrounds; ++gci) {
        const int gc = h * nrounds + gci;
        __syncthreads();  // rawS ready / cols (ldsA) reuse safe
#pragma unroll
        for (int i = 0; i < 3; ++i) {
            int e = tid + i * 256;
            if (e < 576) {
                int p = e & 15;
                int r = e >> 4;  // 0..35
                int gl = r / 9, k = r - gl * 9;
                int g = gc * 4 + gl;
                float ry = rawS[(g * 18 + k * 2 + 0 - rowOffO) * 17 + p];
                float rx = rawS[(g * 18 + k * 2 + 1 - rowOffO) * 17 + p];
                float rm = rawS[(288 + g * 9 + k - rowOffM) * 17 + p];
                float oy = 5.f * (1.f - 2.f / (1.f + __expf(2.f * ry)));
                float ox = 5.f * (1.f - 2.f / (1.f + __expf(2.f * rx)));
                float m = 1.f / (1.f + __expf(-rm));
                float sy = oy + (float)(y - 1 + k / 3);
                float sx = ox + (float)(xb + p - 1 + k % 3);
                float fy0 = floorf(sy), fx0 = floorf(sx);
                float fy = sy - fy0, fx = sx - fx0;
                int y0 = (int)fy0, x0 = (int)fx0;
                int y1 = y0 + 1, x1 = x0 + 1;
                bool vy0 = (unsigned)y0 < 96u, vy1 = (unsigned)y1 < 96u;
                bool vx0 = (unsigned)x0 < 96u, vx1 = (unsigned)x1 < 96u;
                int cy0 = min(max(y0, 0), 95), cy1 = min(max(y1, 0), 95);
                int cx0 = min(max(x0, 0), 95), cx1 = min(max(x1, 0), 95);
                float w00 = (1.f - fy) * (1.f - fx) * ((vy0 && vx0) ? 1.f : 0.f);
                float w01 = (1.f - fy) * fx * ((vy0 && vx1) ? 1.f : 0.f);
                float w10 = fy * (1.f - fx) * ((vy1 && vx0) ? 1.f : 0.f);
                float w11 = fy * fx * ((vy1 && vx1) ? 1.f : 0.f);
                const unsigned* src = (g < 8) ? sA : sB;
                int cb = (g & 7) * 8;
                int kbase = p * 296 + gl * 72 + k * 8;
                ushort_t hh[8], ll[8];
                if (src) {
                    int b00 = (cy0 * 96 + cx0) * 64 + cb;
                    int b01 = (cy0 * 96 + cx1) * 64 + cb;
                    int b10 = (cy1 * 96 + cx0) * 64 + cb;
                    int b11 = (cy1 * 96 + cx1) * 64 + cb;
                    u32x4 c00a = *(const u32x4*)(src + b00);
                    u32x4 c00b = *(const u32x4*)(src + b00 + 4);
                    u32x4 c01a = *(const u32x4*)(src + b01);
                    u32x4 c01b = *(const u32x4*)(src + b01 + 4);
                    u32x4 c10a = *(const u32x4*)(src + b10);
                    u32x4 c10b = *(const u32x4*)(src + b10 + 4);
                    u32x4 c11a = *(const u32x4*)(src + b11);
                    u32x4 c11b = *(const u32x4*)(src + b11 + 4);
#pragma unroll
                    for (int c = 0; c < 4; ++c) {
                        float v = w00 * unpk(c00a[c]) + w01 * unpk(c01a[c]) +
                                  w10 * unpk(c10a[c]) + w11 * unpk(c11a[c]);
                        split16(v * m, hh[c], ll[c]);
                        float v2 = w00 * unpk(c00b[c]) + w01 * unpk(c01b[c]) +
                                   w10 * unpk(c10b[c]) + w11 * unpk(c11b[c]);
                        split16(v2 * m, hh[4 + c], ll[4 + c]);
                    }
                } else {
#pragma unroll
                    for (int c = 0; c < 8; ++c) { hh[c] = 0; ll[c] = 0; }
                }
                u32x4 H, L;
#pragma unroll
                for (int q = 0; q < 4; ++q) {
                    H[q] = (unsigned)hh[2 * q] | ((unsigned)hh[2 * q + 1] << 16);
                    L[q] = (unsigned)ll[2 * q] | ((unsigned)ll[2 * q + 1] << 16);
                }
                *(u32x4*)(colsH + kbase) = H;
                *(u32x4*)(colsL + kbase) = L;
            }
        }
        __syncthreads();
        bf16x8 qAh[4], qAl[4], qBh[4], qBl[4];
#pragma unroll
        for (int s = 0; s < 13; ++s) {
            if (s >= 4) {  // consume BEFORE refilling the slot
                const int u = s - 4;
                const bf16x8 Ah = qAh[u % 4], Al = qAl[u % 4];
                const bf16x8 Bh = qBh[u % 4], Bl = qBl[u % 4];
                if (u & 1) {
                    acc1 = __builtin_amdgcn_mfma_f32_16x16x32_bf16(Ah, Bh, acc1, 0, 0, 0);
                    acc1 = __builtin_amdgcn_mfma_f32_16x16x32_bf16(Al, Bh, acc1, 0, 0, 0);
                    acc1 = __builtin_amdgcn_mfma_f32_16x16x32_bf16(Ah, Bl, acc1, 0, 0, 0);
                } else {
                    acc0 = __builtin_amdgcn_mfma_f32_16x16x32_bf16(Ah, Bh, acc0, 0, 0, 0);
                    acc0 = __builtin_amdgcn_mfma_f32_16x16x32_bf16(Al, Bh, acc0, 0, 0, 0);
                    acc0 = __builtin_amdgcn_mfma_f32_16x16x32_bf16(Ah, Bl, acc0, 0, 0, 0);
                }
            }
            if (s < 9) {
                const int cc = gc * 9 + s;
                const ushort_t* ab = dwf + (((size_t)cc * 4 + w) * 64 + lane) * 8;
                qAh[s % 4] = *(const bf16x8*)ab;
                qAl[s % 4] = *(const bf16x8*)(ab + hlD);
                const int lb = n * 296 + s * 32 + quad * 8;
                qBh[s % 4] = *(const bf16x8*)(colsH + lb);
                qBl[s % 4] = *(const bf16x8*)(colsL + lb);
            }
        }
    }

    const int pidx = y * 96 + xb + n;
#pragma unroll
    for (int r = 0; r < 4; ++r) {
        int cout = w * 16 + quad * 4 + r;
        pacc[(size_t)h * FRAME + (size_t)cout * HW96 + pidx] =
            acc0[r] + acc1[r];
    }
}

// ---------------------------------------------------------------------------
// Combine dconv partials: Dbuf = pacc0+pacc1+bias (planar fp32) and
// Dpk (interleaved packed) via padded-LDS transpose. grid 144.
// ---------------------------------------------------------------------------
__global__ __launch_bounds__(256) void dcomb_k(const float* __restrict__ pacc,
                                               const float* __restrict__ dbias,
                                               float* __restrict__ outf,
                                               unsigned* __restrict__ outpk) {
    const int px0 = blockIdx.x * 64;
    __shared__ unsigned tile[64 * 65];
#pragma unroll
    for (int it = 0; it < 16; ++it) {
        int e = it * 256 + threadIdx.x;
        int p = e & 63, ch = e >> 6;
        size_t off = (size_t)ch * HW96 + px0 + p;
        float v = pacc[off] + pacc[(size_t)FRAME + off] + dbias[ch];
        outf[off] = v;
        tile[ch * 65 + p] = pk(v);
    }
    __syncthreads();
#pragma unroll
    for (int it = 0; it < 16; ++it) {
        int e = it * 256 + threadIdx.x;
        int ch = e & 63, p = e >> 6;
        outpk[(size_t)(px0 + p) * 64 + ch] = tile[ch * 65 + p];
    }
}

// ---------------------------------------------------------------------------
// Fusion: 1x1 conv over [featB[t], featF[t]] (interleaved) + bias + x.
// ---------------------------------------------------------------------------
__global__ __launch_bounds__(256) void fuse_k(
    const unsigned* __restrict__ featB, const unsigned* __restrict__ featF,
    const float* __restrict__ x, const float* __restrict__ wp,
    const float* __restrict__ bias, float* __restrict__ out) {
    const int tx = threadIdx.x & 31;
    const int ty = threadIdx.x >> 5;
    const int px = blockIdx.x * 32 + tx;
    const int py = blockIdx.y * 8 + ty;
    const int t = blockIdx.z >> 3;
    const int obase = (blockIdx.z & 7) * 8;
    const int pidx = py * 96 + px;
    const unsigned* fB = featB + (size_t)t * FRAME + (size_t)pidx * 64;
    const unsigned* fF = featF + (size_t)t * FRAME + (size_t)pidx * 64;

    float acc[8];
#pragma unroll
    for (int o = 0; o < 8; ++o) acc[o] = 0.f;

#pragma unroll 4
    for (int i0 = 0; i0 < 64; i0 += 4) {
        u32x4 pv = *(const u32x4*)(fB + i0);
#pragma unroll
        for (int q = 0; q < 4; ++q) {
            float v = unpk(pv[q]);
            const float* wr = wp + (i0 + q) * 64 + obase;
#pragma unroll
            for (int o = 0; o < 8; ++o) acc[o] = fmaf(wr[o], v, acc[o]);
        }
    }
#pragma unroll 4
    for (int i0 = 0; i0 < 64; i0 += 4) {
        u32x4 pv = *(const u32x4*)(fF + i0);
#pragma unroll
        for (int q = 0; q < 4; ++q) {
            float v = unpk(pv[q]);
            const float* wr = wp + (64 + i0 + q) * 64 + obase;
#pragma unroll
            for (int o = 0; o < 8; ++o) acc[o] = fmaf(wr[o], v, acc[o]);
        }
    }
    const float* xt = x + (size_t)t * FRAME;
#pragma unroll
    for (int o = 0; o < 8; ++o)
        out[(size_t)t * FRAME + (size_t)(obase + o) * HW96 + pidx] =
            acc[o] + bias[obase + o] + xt[(size_t)(obase + o) * HW96 + pidx];
}

// ---------------------------------------------------------------------------
extern "C" void kernel_launch(void* const* d_in, const int* in_sizes, int n_in,
                              void* d_out, int out_size, void* d_ws,
                              size_t ws_size, hipStream_t stream) {
    const float* x = (const float*)d_in[0];
    auto gp = [&](int i) { return (const float*)d_in[i]; };

    struct DirP {
        const float *dw, *db, *ow1, *ob1, *ow2, *ob2, *ow3, *ob3, *ow4, *ob4,
            *bw1, *bb1, *bw2, *bb2;
    };
    DirP Pb{gp(1), gp(2), gp(3), gp(4), gp(5), gp(6), gp(7),
            gp(8), gp(9), gp(10), gp(11), gp(12), gp(13), gp(14)};
    DirP Pf{gp(15), gp(16), gp(17), gp(18), gp(19), gp(20), gp(21),
            gp(22), gp(23), gp(24), gp(25), gp(26), gp(27), gp(28)};
    const float* fus_w = gp(29);
    const float* fus_b = gp(30);

    // ---- workspace carve-up (4-byte units); all feature bufs interleaved ----
    unsigned* featBpk = (unsigned*)d_ws;
    unsigned* featFpk = featBpk + (size_t)8 * FRAME;
    unsigned* xpk = featFpk + (size_t)8 * FRAME;
    float* Dbuf = (float*)(xpk + (size_t)8 * FRAME);  // planar fp32
    unsigned* Dpk = (unsigned*)(Dbuf + FRAME);        // interleaved packed
    unsigned* hApk = Dpk + FRAME;
    unsigned* hBpk = hApk + FRAME;
    float* wfus = (float*)(hBpk + FRAME);
    ushort_t* fragp = (ushort_t*)(wfus + 128 * 64);

    auto falloc = [&](size_t nelem) {
        ushort_t* p = fragp;
        fragp += nelem;
        return p;
    };

    // ---- weight prep ----
    repack_fus_k<<<32, 256, 0, stream>>>(fus_w, wfus);

    struct DirW { ushort_t *ow1, *ow2, *ow3, *ow4, *bw1, *bw2, *dw; int bw1KC; };
    FragJobs fj;
    int nf = 0;
    auto fjob = [&](const float* src, int O, int I, int OT, int KC) {
        ushort_t* dst = falloc((size_t)2 * 9 * KC * OT * 512);
        fj.j[nf++] = FragJob{src, dst, O, I, OT, KC, 0};
        return dst;
    };
    auto fjobd = [&](const float* src) {
        ushort_t* dst = falloc((size_t)2 * 36 * 4 * 512);
        fj.j[nf++] = FragJob{src, dst, 64, 128, 4, 36, 1};
        return dst;
    };
    DirW Wb, Wf;
    Wb.ow1 = fjob(Pb.ow1, 64, 192, 4, 6);
    Wb.ow2 = fjob(Pb.ow2, 64, 64, 4, 2);
    Wb.ow3 = fjob(Pb.ow3, 64, 64, 4, 2);
    Wb.ow4 = fjob(Pb.ow4, 432, 64, 28, 2);
    Wb.bw1 = fjob(Pb.bw1, 64, 128, 4, 4);
    Wb.bw1KC = 4;
    Wb.bw2 = fjob(Pb.bw2, 64, 64, 4, 2);
    Wb.dw = fjobd(Pb.dw);
    Wf.ow1 = fjob(Pf.ow1, 64, 192, 4, 6);
    Wf.ow2 = fjob(Pf.ow2, 64, 64, 4, 2);
    Wf.ow3 = fjob(Pf.ow3, 64, 64, 4, 2);
    Wf.ow4 = fjob(Pf.ow4, 432, 64, 28, 2);
    Wf.bw1 = fjob(Pf.bw1, 64, 192, 4, 6);
    Wf.bw1KC = 6;
    Wf.bw2 = fjob(Pf.bw2, 64, 64, 4, 2);
    Wf.dw = fjobd(Pf.dw);
    frag_all_k<<<dim3(1008, 14), 256, 0, stream>>>(fj);

    // dconv partial buffer (2 x FRAME fp32), after the weight frags
    float* pacc = (float*)((((uintptr_t)fragp) + 15) & ~(uintptr_t)15);

    pack_tr_k<<<dim3(144, 8), 256, 0, stream>>>(x, xpk);

    auto convm = [&](const unsigned* a, const unsigned* b, const unsigned* c2,
                     const ushort_t* frag, int KCfull, const float* bias,
                     const float* addsrc, unsigned* out, int act, int terms) {
        const unsigned* srcs[3] = {a, b, c2};
        const unsigned* S[3] = {nullptr, nullptr, nullptr};
        int B[3] = {0, 0, 0};
        int ns = 0;
        for (int j = 0; j < 3; ++j)
            if (srcs[j]) {
                S[ns] = srcs[j];
                B[ns] = j * 2;
                ++ns;
            }
        if (terms == 2)
            convm_k<2><<<1152, 128, 0, stream>>>(S[0], S[1], S[2], B[0], B[1],
                                                 B[2], ns, frag, KCfull, bias,
                                                 addsrc, out, act);
        else
            convm_k<3><<<1152, 128, 0, stream>>>(S[0], S[1], S[2], B[0], B[1],
                                                 B[2], ns, frag, KCfull, bias,
                                                 addsrc, out, act);
    };

    for (int dir = 0; dir < 2; ++dir) {  // 0 = backward, 1 = forward
        const DirP& P = dir ? Pf : Pb;
        const DirW& W = dir ? Wf : Wb;
        unsigned* feat = dir ? featFpk : featBpk;
        const unsigned* prev1 = nullptr;
        const unsigned* prev2 = nullptr;
        for (int i = 0; i < 8; ++i) {
            int idx = dir ? i : 7 - i;
            const unsigned* cur = xpk + (size_t)idx * FRAME;
            const float* propf = nullptr;
            if (i > 0) {
                // offset/mask path: 2-term (weight-lo dropped)
                convm(prev1, cur, prev2, W.ow1, 6, P.ob1, nullptr, hApk, 1, 2);
                convm(hApk, nullptr, nullptr, W.ow2, 2, P.ob2, nullptr, hBpk, 1, 2);
                convm(hBpk, nullptr, nullptr, W.ow3, 2, P.ob3, nullptr, hApk, 1, 2);
                int ngr4 = (prev2 != nullptr) ? 4 : 2;
                dconv_fused_k<<<1152, 256, 0, stream>>>(
                    prev1, prev2, hApk, W.ow4, P.ob4, W.dw, ngr4, pacc);
                dcomb_k<<<144, 256, 0, stream>>>(pacc, P.db, Dbuf, Dpk);
                propf = Dbuf;
            }
            unsigned* dst = feat + (size_t)idx * FRAME;
            // feature path: keep 3-term
            if (dir == 0) {
                convm(cur, (i > 0) ? Dpk : nullptr, nullptr, W.bw1, W.bw1KC,
                      P.bb1, nullptr, hBpk, 1, 3);
            } else {
                convm(cur, featBpk + (size_t)idx * FRAME,
                      (i > 0) ? Dpk : nullptr, W.bw1, W.bw1KC, P.bb1, nullptr,
                      hBpk, 1, 3);
            }
            convm(hBpk, nullptr, nullptr, W.bw2, 2, P.bb2, propf, dst, 0, 3);
            prev2 = prev1;
            prev1 = dst;
        }
    }

    fuse_k<<<dim3(3, 12, 64), 256, 0, stream>>>(featBpk, featFpk, x, wfus,
                                                fus_b, (float*)d_out);
}

// Round 9
// 1559.815 us; speedup vs baseline: 1.1519x; 1.0544x over previous
//
#include <hip/hip_runtime.h>
#include <cstddef>
#include <cstdint>

#define HW96 9216
#define FRAME (64 * 9216)

typedef unsigned short ushort_t;
typedef __attribute__((ext_vector_type(8))) short bf16x8;
typedef __attribute__((ext_vector_type(4))) float f32x4;
typedef __attribute__((ext_vector_type(4))) unsigned u32x4;

// packed u32 = (bf16 hi bits << 16) | bf16 lo bits; value = hi + lo exactly
__device__ __forceinline__ float unpk(unsigned p) {
    return __uint_as_float(p & 0xFFFF0000u) + __uint_as_float(p << 16);
}
__device__ __forceinline__ unsigned pk(float v) {
    unsigned u = __float_as_uint(v);
    unsigned hi = u & 0xFFFF0000u;
    float rem = v - __uint_as_float(hi);
    unsigned r = __float_as_uint(rem);
    unsigned lo = (r + 0x7FFFu + ((r >> 16) & 1u)) >> 16;
    return hi | (lo & 0xFFFFu);
}
__device__ __forceinline__ void split16(float v, ushort_t& h, ushort_t& l) {
    unsigned u = __float_as_uint(v);
    h = (ushort_t)(u >> 16);
    float rem = v - __uint_as_float(u & 0xFFFF0000u);
    unsigned r = __float_as_uint(rem);
    l = (ushort_t)((r + 0x7FFFu + ((r >> 16) & 1u)) >> 16);
}

// ---------------------------------------------------------------------------
// MFMA A-fragment prepack (16x16x32) with bf16 hi/lo split.
// mode 0 (3x3 conv): layout [hl][t][cc][ot][lane][j]; K = cin chunks of 32.
// mode 1 (dconv):    layout [hl][cc][ot][lane][j]; K = g*72 + tap*8 + c.
// mode 2 (1x1 conv): layout [hl][cc][ot][lane][j]; K = cin chunks of 32.
// A[m=lane&15][k=(lane>>4)*8+j].
// ---------------------------------------------------------------------------
struct FragJob { const float* src; ushort_t* dst; int O, I, OT, KC, mode; };
struct FragJobs { FragJob j[15]; };

__global__ __launch_bounds__(256) void frag_all_k(FragJobs jobs) {
    const FragJob& J = jobs.j[blockIdx.y];
    int idx = blockIdx.x * 256 + threadIdx.x;
    int total = ((J.mode == 0) ? 9 : 1) * J.KC * J.OT * 512;
    if (idx >= total) return;
    int jj = idx & 7;
    int lane = (idx >> 3) & 63;
    int rem = idx >> 9;
    int ot = rem % J.OT;
    rem /= J.OT;
    int cc = rem % J.KC;
    int t = rem / J.KC;
    int o = ot * 16 + (lane & 15);
    float wv = 0.f;
    if (J.mode == 0) {
        int ci = cc * 32 + (lane >> 4) * 8 + jj;
        if (o < J.O && ci < J.I) wv = J.src[(o * J.I + ci) * 9 + t];
    } else if (J.mode == 1) {
        int K = cc * 32 + (lane >> 4) * 8 + jj;
        int g = K / 72, r2 = K % 72;
        int tap = r2 >> 3, c = r2 & 7;
        int ci = g * 8 + c;
        if (o < J.O && ci < J.I) wv = J.src[(o * J.I + ci) * 9 + tap];
    } else {  // mode 2: 1x1
        int ci = cc * 32 + (lane >> 4) * 8 + jj;
        if (o < J.O && ci < J.I) wv = J.src[o * J.I + ci];
    }
    ushort_t h, l;
    split16(wv, h, l);
    J.dst[idx] = h;
    J.dst[total + idx] = l;
}

// ---------------------------------------------------------------------------
// Transposing pack: planar fp32 frames -> interleaved [px][64ch] packed u32.
// Block handles one 64-px x 64-ch tile via padded LDS. grid (144, T).
// ---------------------------------------------------------------------------
__global__ __launch_bounds__(256) void pack_tr_k(const float* __restrict__ src,
                                                 unsigned* __restrict__ dst) {
    const int t = blockIdx.y;
    const int px0 = blockIdx.x * 64;
    __shared__ unsigned tile[64 * 65];
    const float* s = src + (size_t)t * FRAME;
    unsigned* d = dst + (size_t)t * FRAME;
#pragma unroll
    for (int it = 0; it < 16; ++it) {
        int e = it * 256 + threadIdx.x;
        int p = e & 63, ch = e >> 6;
        tile[ch * 65 + p] = pk(s[(size_t)ch * HW96 + px0 + p]);
    }
    __syncthreads();
#pragma unroll
    for (int it = 0; it < 16; ++it) {
        int e = it * 256 + threadIdx.x;
        int ch = e & 63, p = e >> 6;
        d[(size_t)(px0 + p) * 64 + ch] = tile[ch * 65 + p];
    }
}

// ---------------------------------------------------------------------------
// MFMA implicit-GEMM 3x3 conv, 16x16x32 bf16.
// TERMS=3: AhBh + AlBh + AhBl (fp32-grade, feature path: bw2).
// TERMS=2: AhBh + AhBl (weight-lo dropped: ow1..ow3, bw1).
// 128 thr = 2 waves; block = 32 couts (half) x 16 px; grid 1152.
// Depth-5 rolling pipeline, consume-before-fill ring discipline.
// ---------------------------------------------------------------------------
template <int TERMS>
__global__ __launch_bounds__(128, 3) void convm_k(
    const unsigned* __restrict__ s0, const unsigned* __restrict__ s1,
    const unsigned* __restrict__ s2, int b0, int b1, int b2, int nsrc,
    const ushort_t* __restrict__ wfrag, int KCfull,
    const float* __restrict__ bias, const float* __restrict__ addsrc,
    unsigned* __restrict__ outpk, int act) {
    const int tid = threadIdx.x;
    const int lane = tid & 63;
    const int w = tid >> 6;              // 0..1
    const int h = blockIdx.x & 1;       // cout half
    const int bseg = blockIdx.x >> 1;   // px segment
    const int ot = h * 2 + w;           // global out-tile 0..3
    const int xb = (bseg % 6) * 16;
    const int y = bseg / 6;
    const int n = lane & 15;
    const int quad = lane >> 4;

    __shared__ __align__(16) ushort_t ldsH[3 * 18 * 72];
    __shared__ __align__(16) ushort_t ldsL[3 * 18 * 72];

    // staging job decode (loop-invariant): 432 jobs = 54 (r,c) x 8 octets
    int jst[4], jok[4], joff[4], jbase[4];
#pragma unroll
    for (int i = 0; i < 4; ++i) {
        int e = tid + i * 128;
        int rc = e >> 3, cg = e & 7;
        int r = rc / 18, col = rc - r * 18;
        int gy = y - 1 + r, gx = xb - 1 + col;
        jst[i] = (e < 432);
        jok[i] = jst[i] && ((unsigned)gy < 96u) && ((unsigned)gx < 96u);
        joff[i] = (gy * 96 + gx) * 64 + cg * 8;
        jbase[i] = rc * 72 + cg * 8;
    }

    f32x4 acc0, acc1;
#pragma unroll
    for (int r = 0; r < 4; ++r) { acc0[r] = 0.f; acc1[r] = 0.f; }

    const size_t hlOff = (size_t)9 * KCfull * 4 * 512;

    for (int j = 0; j < nsrc; ++j) {
        const unsigned* sv = (j == 0) ? s0 : (j == 1 ? s1 : s2);
        const int base = (j == 0) ? b0 : (j == 1 ? b1 : b2);
        __syncthreads();
#pragma unroll
        for (int i = 0; i < 4; ++i) {
            if (jst[i]) {
                u32x4 a, b;
                if (jok[i]) {
                    a = *(const u32x4*)(sv + joff[i]);
                    b = *(const u32x4*)(sv + joff[i] + 4);
                } else {
#pragma unroll
                    for (int q = 0; q < 4; ++q) { a[q] = 0; b[q] = 0; }
                }
                u32x4 H, L;
#pragma unroll
                for (int q = 0; q < 2; ++q) {
                    H[q] = (a[2 * q] >> 16) | (a[2 * q + 1] & 0xFFFF0000u);
                    L[q] = (a[2 * q] & 0xFFFFu) | (a[2 * q + 1] << 16);
                    H[2 + q] = (b[2 * q] >> 16) | (b[2 * q + 1] & 0xFFFF0000u);
                    L[2 + q] = (b[2 * q] & 0xFFFFu) | (b[2 * q + 1] << 16);
                }
                *(u32x4*)(ldsH + jbase[i]) = H;
                *(u32x4*)(ldsL + jbase[i]) = L;
            }
        }
        __syncthreads();
        // depth-5 rolling pipeline over 18 steps (t = s>>1, cc2 = s&1)
        bf16x8 pAh[5], pAl[5], pBh[5], pBl[5];
#pragma unroll
        for (int s = 0; s < 23; ++s) {
            if (s >= 5) {  // consume BEFORE refilling the slot
                const int u = s - 5;
                const bf16x8 Ah = pAh[u % 5];
                const bf16x8 Bh = pBh[u % 5], Bl = pBl[u % 5];
                if (u & 1) {
                    acc1 = __builtin_amdgcn_mfma_f32_16x16x32_bf16(Ah, Bh, acc1, 0, 0, 0);
                    if (TERMS == 3)
                        acc1 = __builtin_amdgcn_mfma_f32_16x16x32_bf16(pAl[u % 5], Bh, acc1, 0, 0, 0);
                    acc1 = __builtin_amdgcn_mfma_f32_16x16x32_bf16(Ah, Bl, acc1, 0, 0, 0);
                } else {
                    acc0 = __builtin_amdgcn_mfma_f32_16x16x32_bf16(Ah, Bh, acc0, 0, 0, 0);
                    if (TERMS == 3)
                        acc0 = __builtin_amdgcn_mfma_f32_16x16x32_bf16(pAl[u % 5], Bh, acc0, 0, 0, 0);
                    acc0 = __builtin_amdgcn_mfma_f32_16x16x32_bf16(Ah, Bl, acc0, 0, 0, 0);
                }
            }
            if (s < 18) {
                const int t = s >> 1, cc2 = s & 1;
                const int ky = t / 3, kx = t % 3;
                const int ccor = base + cc2;
                const ushort_t* ab =
                    wfrag + (((size_t)(t * KCfull + ccor) * 4 + ot) * 64 + lane) * 8;
                pAh[s % 5] = *(const bf16x8*)ab;
                if (TERMS == 3) pAl[s % 5] = *(const bf16x8*)(ab + hlOff);
                const int lb = (ky * 18 + n + kx) * 72 + cc2 * 32 + quad * 8;
                pBh[s % 5] = *(const bf16x8*)(ldsH + lb);
                pBl[s % 5] = *(const bf16x8*)(ldsL + lb);
            }
        }
    }

    const int px = y * 96 + xb + n;
#pragma unroll
    for (int r = 0; r < 4; ++r) {
        int cout = ot * 16 + quad * 4 + r;
        float v = acc0[r] + acc1[r] + bias[cout];
        if (act) v = (v >= 0.f) ? v : 0.1f * v;
        if (addsrc) v += addsrc[(size_t)cout * HW96 + px];
        outpk[(size_t)px * 64 + cout] = pk(v);
    }
}

// ---------------------------------------------------------------------------
// Fused ow4 + modulated deformable conv, HALF-SPLIT: grid 1152 = 576 seg x 2.
// Half h owns groups [h*ng, (h+1)*ng), ng = 4*(ngr4/2); phase-2 out-tile
// ranges DERIVED from ngr4. Phase 3 dconv MFMA is 2-term (dwf-lo dropped).
// ---------------------------------------------------------------------------
__global__ __launch_bounds__(256) void dconv_fused_k(
    const unsigned* __restrict__ sA, const unsigned* __restrict__ sB,
    const unsigned* __restrict__ hA, const ushort_t* __restrict__ w4,
    const float* __restrict__ ob4, const ushort_t* __restrict__ dwf,
    int ngr4, float* __restrict__ pacc) {
    const int tid = threadIdx.x;
    const int lane = tid & 63;
    const int w = tid >> 6;
    const int h = blockIdx.x & 1;
    const int seg = blockIdx.x >> 1;
    const int xb = (seg % 6) * 16;
    const int y = seg / 6;
    const int n = lane & 15;
    const int quad = lane >> 4;

    __shared__ __align__(16) char smem[15232 + 18944];
    float* rawS = (float*)smem;               // up to [224][17] fp32
    ushort_t* ldsAH = (ushort_t*)(smem + 15232);  // 3888 ushorts
    ushort_t* ldsAL = ldsAH + 3888;               // (15552 B <= 18944)
    ushort_t* colsH = (ushort_t*)(smem + 15232);  // union with ldsA
    ushort_t* colsL = colsH + 4736;

    // ---- out-tile ranges for this half (derived from ngr4) ----
    const int nrounds = ngr4 >> 1;   // 1 or 2
    const int ng = nrounds * 4;      // groups per half
    const int g0 = h * ng;
    const int otO_s = (g0 * 18) >> 4;
    const int otO_e = (g0 * 18 + ng * 18 - 1) >> 4;
    const int nO = otO_e - otO_s + 1;
    const int otM_s = (288 + g0 * 9) >> 4;
    const int otM_e = (288 + g0 * 9 + ng * 9 - 1) >> 4;
    const int nM = otM_e - otM_s + 1;
    const int nt = nO + nM;          // 14 (ngr4=4) or 8 (ngr4=2)
    const int rowOffO = otO_s * 16;
    const int rowOffM = otM_s * 16 - nO * 16;

    // ---- phase 1: stage hA window (interleaved source) ----
#pragma unroll
    for (int i = 0; i < 2; ++i) {
        int e = tid + i * 256;
        if (e < 432) {
            int rc = e >> 3, cg = e & 7;
            int r = rc / 18, col = rc - r * 18;
            int gy = y - 1 + r, gx = xb - 1 + col;
            bool ok = ((unsigned)gy < 96u) && ((unsigned)gx < 96u);
            u32x4 a, b;
            if (ok) {
                int off = (gy * 96 + gx) * 64 + cg * 8;
                a = *(const u32x4*)(hA + off);
                b = *(const u32x4*)(hA + off + 4);
            } else {
#pragma unroll
                for (int q = 0; q < 4; ++q) { a[q] = 0; b[q] = 0; }
            }
            u32x4 H, L;
#pragma unroll
            for (int q = 0; q < 2; ++q) {
                H[q] = (a[2 * q] >> 16) | (a[2 * q + 1] & 0xFFFF0000u);
                L[q] = (a[2 * q] & 0xFFFFu) | (a[2 * q + 1] << 16);
                H[2 + q] = (b[2 * q] >> 16) | (b[2 * q + 1] & 0xFFFF0000u);
                L[2 + q] = (b[2 * q] & 0xFFFFu) | (b[2 * q + 1] << 16);
            }
            *(u32x4*)(ldsAH + rc * 72 + cg * 8) = H;
            *(u32x4*)(ldsAL + rc * 72 + cg * 8) = L;
        }
    }
    __syncthreads();

    // ---- phase 2: needed ow4 out-tiles, 2-term, depth-5 pipeline ----
#pragma unroll 1
    for (int j = 0; j < 4; ++j) {
        const int idx = j * 4 + w;
        if (idx >= nt) break;
        const int ot = (idx < nO) ? (otO_s + idx) : (otM_s + (idx - nO));
        f32x4 a0, a1;
#pragma unroll
        for (int r = 0; r < 4; ++r) { a0[r] = 0.f; a1[r] = 0.f; }
        bf16x8 pAh[5], pBh[5], pBl[5];
#pragma unroll
        for (int s = 0; s < 23; ++s) {
            if (s >= 5) {  // consume BEFORE refilling the slot
                const int u = s - 5;
                const bf16x8 Ah = pAh[u % 5];
                const bf16x8 Bh = pBh[u % 5], Bl = pBl[u % 5];
                if (u & 1) {
                    a1 = __builtin_amdgcn_mfma_f32_16x16x32_bf16(Ah, Bh, a1, 0, 0, 0);
                    a1 = __builtin_amdgcn_mfma_f32_16x16x32_bf16(Ah, Bl, a1, 0, 0, 0);
                } else {
                    a0 = __builtin_amdgcn_mfma_f32_16x16x32_bf16(Ah, Bh, a0, 0, 0, 0);
                    a0 = __builtin_amdgcn_mfma_f32_16x16x32_bf16(Ah, Bl, a0, 0, 0, 0);
                }
            }
            if (s < 18) {
                const int t = s >> 1, cc2 = s & 1;
                const int ky = t / 3, kx = t % 3;
                const ushort_t* ab =
                    w4 + (((size_t)s * 28 + ot) * 64 + lane) * 8;
                pAh[s % 5] = *(const bf16x8*)ab;
                const int lb = (ky * 18 + n + kx) * 72 + cc2 * 32 + quad * 8;
                pBh[s % 5] = *(const bf16x8*)(ldsAH + lb);
                pBl[s % 5] = *(const bf16x8*)(ldsAL + lb);
            }
        }
#pragma unroll
        for (int r = 0; r < 4; ++r) {
            int cout = ot * 16 + quad * 4 + r;
            float v = a0[r] + a1[r] + (cout < 432 ? ob4[cout] : 0.f);
            rawS[(idx * 16 + quad * 4 + r) * 17 + n] = v;
        }
    }

    // ---- phase 3: gather + dconv MFMA (2-term, depth-4 pipeline) ----
    f32x4 acc0, acc1;
#pragma unroll
    for (int r = 0; r < 4; ++r) { acc0[r] = 0.f; acc1[r] = 0.f; }

    for (int gci = 0; gci < nrounds; ++gci) {
        const int gc = h * nrounds + gci;
        __syncthreads();  // rawS ready / cols (ldsA) reuse safe
#pragma unroll
        for (int i = 0; i < 3; ++i) {
            int e = tid + i * 256;
            if (e < 576) {
                int p = e & 15;
                int r = e >> 4;  // 0..35
                int gl = r / 9, k = r - gl * 9;
                int g = gc * 4 + gl;
                float ry = rawS[(g * 18 + k * 2 + 0 - rowOffO) * 17 + p];
                float rx = rawS[(g * 18 + k * 2 + 1 - rowOffO) * 17 + p];
                float rm = rawS[(288 + g * 9 + k - rowOffM) * 17 + p];
                float oy = 5.f * (1.f - 2.f / (1.f + __expf(2.f * ry)));
                float ox = 5.f * (1.f - 2.f / (1.f + __expf(2.f * rx)));
                float m = 1.f / (1.f + __expf(-rm));
                float sy = oy + (float)(y - 1 + k / 3);
                float sx = ox + (float)(xb + p - 1 + k % 3);
                float fy0 = floorf(sy), fx0 = floorf(sx);
                float fy = sy - fy0, fx = sx - fx0;
                int y0 = (int)fy0, x0 = (int)fx0;
                int y1 = y0 + 1, x1 = x0 + 1;
                bool vy0 = (unsigned)y0 < 96u, vy1 = (unsigned)y1 < 96u;
                bool vx0 = (unsigned)x0 < 96u, vx1 = (unsigned)x1 < 96u;
                int cy0 = min(max(y0, 0), 95), cy1 = min(max(y1, 0), 95);
                int cx0 = min(max(x0, 0), 95), cx1 = min(max(x1, 0), 95);
                float w00 = (1.f - fy) * (1.f - fx) * ((vy0 && vx0) ? 1.f : 0.f);
                float w01 = (1.f - fy) * fx * ((vy0 && vx1) ? 1.f : 0.f);
                float w10 = fy * (1.f - fx) * ((vy1 && vx0) ? 1.f : 0.f);
                float w11 = fy * fx * ((vy1 && vx1) ? 1.f : 0.f);
                const unsigned* src = (g < 8) ? sA : sB;
                int cb = (g & 7) * 8;
                int kbase = p * 296 + gl * 72 + k * 8;
                ushort_t hh[8], ll[8];
                if (src) {
                    int b00 = (cy0 * 96 + cx0) * 64 + cb;
                    int b01 = (cy0 * 96 + cx1) * 64 + cb;
                    int b10 = (cy1 * 96 + cx0) * 64 + cb;
                    int b11 = (cy1 * 96 + cx1) * 64 + cb;
                    u32x4 c00a = *(const u32x4*)(src + b00);
                    u32x4 c00b = *(const u32x4*)(src + b00 + 4);
                    u32x4 c01a = *(const u32x4*)(src + b01);
                    u32x4 c01b = *(const u32x4*)(src + b01 + 4);
                    u32x4 c10a = *(const u32x4*)(src + b10);
                    u32x4 c10b = *(const u32x4*)(src + b10 + 4);
                    u32x4 c11a = *(const u32x4*)(src + b11);
                    u32x4 c11b = *(const u32x4*)(src + b11 + 4);
#pragma unroll
                    for (int c = 0; c < 4; ++c) {
                        float v = w00 * unpk(c00a[c]) + w01 * unpk(c01a[c]) +
                                  w10 * unpk(c10a[c]) + w11 * unpk(c11a[c]);
                        split16(v * m, hh[c], ll[c]);
                        float v2 = w00 * unpk(c00b[c]) + w01 * unpk(c01b[c]) +
                                   w10 * unpk(c10b[c]) + w11 * unpk(c11b[c]);
                        split16(v2 * m, hh[4 + c], ll[4 + c]);
                    }
                } else {
#pragma unroll
                    for (int c = 0; c < 8; ++c) { hh[c] = 0; ll[c] = 0; }
                }
                u32x4 H, L;
#pragma unroll
                for (int q = 0; q < 4; ++q) {
                    H[q] = (unsigned)hh[2 * q] | ((unsigned)hh[2 * q + 1] << 16);
                    L[q] = (unsigned)ll[2 * q] | ((unsigned)ll[2 * q + 1] << 16);
                }
                *(u32x4*)(colsH + kbase) = H;
                *(u32x4*)(colsL + kbase) = L;
            }
        }
        __syncthreads();
        bf16x8 qAh[4], qBh[4], qBl[4];
#pragma unroll
        for (int s = 0; s < 13; ++s) {
            if (s >= 4) {  // consume BEFORE refilling the slot
                const int u = s - 4;
                const bf16x8 Ah = qAh[u % 4];
                const bf16x8 Bh = qBh[u % 4], Bl = qBl[u % 4];
                if (u & 1) {
                    acc1 = __builtin_amdgcn_mfma_f32_16x16x32_bf16(Ah, Bh, acc1, 0, 0, 0);
                    acc1 = __builtin_amdgcn_mfma_f32_16x16x32_bf16(Ah, Bl, acc1, 0, 0, 0);
                } else {
                    acc0 = __builtin_amdgcn_mfma_f32_16x16x32_bf16(Ah, Bh, acc0, 0, 0, 0);
                    acc0 = __builtin_amdgcn_mfma_f32_16x16x32_bf16(Ah, Bl, acc0, 0, 0, 0);
                }
            }
            if (s < 9) {
                const int cc = gc * 9 + s;
                const ushort_t* ab = dwf + (((size_t)cc * 4 + w) * 64 + lane) * 8;
                qAh[s % 4] = *(const bf16x8*)ab;
                const int lb = n * 296 + s * 32 + quad * 8;
                qBh[s % 4] = *(const bf16x8*)(colsH + lb);
                qBl[s % 4] = *(const bf16x8*)(colsL + lb);
            }
        }
    }

    const int pidx = y * 96 + xb + n;
#pragma unroll
    for (int r = 0; r < 4; ++r) {
        int cout = w * 16 + quad * 4 + r;
        pacc[(size_t)h * FRAME + (size_t)cout * HW96 + pidx] =
            acc0[r] + acc1[r];
    }
}

// ---------------------------------------------------------------------------
// Combine dconv partials: Dbuf = pacc0+pacc1+bias (planar fp32) and
// Dpk (interleaved packed) via padded-LDS transpose. grid 144.
// ---------------------------------------------------------------------------
__global__ __launch_bounds__(256) void dcomb_k(const float* __restrict__ pacc,
                                               const float* __restrict__ dbias,
                                               float* __restrict__ outf,
                                               unsigned* __restrict__ outpk) {
    const int px0 = blockIdx.x * 64;
    __shared__ unsigned tile[64 * 65];
#pragma unroll
    for (int it = 0; it < 16; ++it) {
        int e = it * 256 + threadIdx.x;
        int p = e & 63, ch = e >> 6;
        size_t off = (size_t)ch * HW96 + px0 + p;
        float v = pacc[off] + pacc[(size_t)FRAME + off] + dbias[ch];
        outf[off] = v;
        tile[ch * 65 + p] = pk(v);
    }
    __syncthreads();
#pragma unroll
    for (int it = 0; it < 16; ++it) {
        int e = it * 256 + threadIdx.x;
        int ch = e & 63, p = e >> 6;
        outpk[(size_t)(px0 + p) * 64 + ch] = tile[ch * 65 + p];
    }
}

// ---------------------------------------------------------------------------
// MFMA fusion: 1x1 conv over [featB[t], featF[t]] (K=128) + bias + x.
// 128 thr = 2 waves; block = 32 couts x 16 px; grid (1152, 8 frames).
// No halo: staging = 2 x 128 jobs of 32 B. 3-term (final output precision).
// ---------------------------------------------------------------------------
__global__ __launch_bounds__(128) void fusem_k(
    const unsigned* __restrict__ featB, const unsigned* __restrict__ featF,
    const float* __restrict__ x, const ushort_t* __restrict__ wfrag,
    const float* __restrict__ bias, float* __restrict__ out) {
    const int tid = threadIdx.x;
    const int lane = tid & 63;
    const int w = tid >> 6;
    const int h = blockIdx.x & 1;
    const int bseg = blockIdx.x >> 1;
    const int t = blockIdx.y;
    const int ot = h * 2 + w;
    const int xb = (bseg % 6) * 16;
    const int y = bseg / 6;
    const int n = lane & 15;
    const int quad = lane >> 4;

    __shared__ __align__(16) ushort_t ldsH[16 * 144];
    __shared__ __align__(16) ushort_t ldsL[16 * 144];

    const int p = tid >> 3, cg = tid & 7;
    const int off = ((y * 96 + xb + p) * 64 + cg * 8);
#pragma unroll
    for (int i = 0; i < 2; ++i) {  // i=0: featB (ch 0-63), i=1: featF (64-127)
        const unsigned* sv =
            (i == 0 ? featB : featF) + (size_t)t * FRAME;
        u32x4 a = *(const u32x4*)(sv + off);
        u32x4 b = *(const u32x4*)(sv + off + 4);
        u32x4 H, L;
#pragma unroll
        for (int q = 0; q < 2; ++q) {
            H[q] = (a[2 * q] >> 16) | (a[2 * q + 1] & 0xFFFF0000u);
            L[q] = (a[2 * q] & 0xFFFFu) | (a[2 * q + 1] << 16);
            H[2 + q] = (b[2 * q] >> 16) | (b[2 * q + 1] & 0xFFFF0000u);
            L[2 + q] = (b[2 * q] & 0xFFFFu) | (b[2 * q + 1] << 16);
        }
        *(u32x4*)(ldsH + p * 144 + i * 64 + cg * 8) = H;
        *(u32x4*)(ldsL + p * 144 + i * 64 + cg * 8) = L;
    }
    __syncthreads();

    f32x4 acc0, acc1;
#pragma unroll
    for (int r = 0; r < 4; ++r) { acc0[r] = 0.f; acc1[r] = 0.f; }
    const size_t hlOff = (size_t)4 * 4 * 512;
#pragma unroll
    for (int cc = 0; cc < 4; ++cc) {
        const ushort_t* ab = wfrag + (((size_t)cc * 4 + ot) * 64 + lane) * 8;
        bf16x8 Ah = *(const bf16x8*)ab;
        bf16x8 Al = *(const bf16x8*)(ab + hlOff);
        int lb = n * 144 + cc * 32 + quad * 8;
        bf16x8 Bh = *(const bf16x8*)(ldsH + lb);
        bf16x8 Bl = *(const bf16x8*)(ldsL + lb);
        if (cc & 1) {
            acc1 = __builtin_amdgcn_mfma_f32_16x16x32_bf16(Ah, Bh, acc1, 0, 0, 0);
            acc1 = __builtin_amdgcn_mfma_f32_16x16x32_bf16(Al, Bh, acc1, 0, 0, 0);
            acc1 = __builtin_amdgcn_mfma_f32_16x16x32_bf16(Ah, Bl, acc1, 0, 0, 0);
        } else {
            acc0 = __builtin_amdgcn_mfma_f32_16x16x32_bf16(Ah, Bh, acc0, 0, 0, 0);
            acc0 = __builtin_amdgcn_mfma_f32_16x16x32_bf16(Al, Bh, acc0, 0, 0, 0);
            acc0 = __builtin_amdgcn_mfma_f32_16x16x32_bf16(Ah, Bl, acc0, 0, 0, 0);
        }
    }

    const int pidx = y * 96 + xb + n;
    const float* xt = x + (size_t)t * FRAME;
    float* od = out + (size_t)t * FRAME;
#pragma unroll
    for (int r = 0; r < 4; ++r) {
        int cout = ot * 16 + quad * 4 + r;
        size_t o2 = (size_t)cout * HW96 + pidx;
        od[o2] = acc0[r] + acc1[r] + bias[cout] + xt[o2];
    }
}

// ---------------------------------------------------------------------------
extern "C" void kernel_launch(void* const* d_in, const int* in_sizes, int n_in,
                              void* d_out, int out_size, void* d_ws,
                              size_t ws_size, hipStream_t stream) {
    const float* x = (const float*)d_in[0];
    auto gp = [&](int i) { return (const float*)d_in[i]; };

    struct DirP {
        const float *dw, *db, *ow1, *ob1, *ow2, *ob2, *ow3, *ob3, *ow4, *ob4,
            *bw1, *bb1, *bw2, *bb2;
    };
    DirP Pb{gp(1), gp(2), gp(3), gp(4), gp(5), gp(6), gp(7),
            gp(8), gp(9), gp(10), gp(11), gp(12), gp(13), gp(14)};
    DirP Pf{gp(15), gp(16), gp(17), gp(18), gp(19), gp(20), gp(21),
            gp(22), gp(23), gp(24), gp(25), gp(26), gp(27), gp(28)};
    const float* fus_w = gp(29);
    const float* fus_b = gp(30);

    // ---- workspace carve-up (4-byte units); all feature bufs interleaved ----
    unsigned* featBpk = (unsigned*)d_ws;
    unsigned* featFpk = featBpk + (size_t)8 * FRAME;
    unsigned* xpk = featFpk + (size_t)8 * FRAME;
    float* Dbuf = (float*)(xpk + (size_t)8 * FRAME);  // planar fp32
    unsigned* Dpk = (unsigned*)(Dbuf + FRAME);        // interleaved packed
    unsigned* hApk = Dpk + FRAME;
    unsigned* hBpk = hApk + FRAME;
    ushort_t* fragp = (ushort_t*)(hBpk + FRAME);

    auto falloc = [&](size_t nelem) {
        ushort_t* p = fragp;
        fragp += nelem;
        return p;
    };

    struct DirW { ushort_t *ow1, *ow2, *ow3, *ow4, *bw1, *bw2, *dw; int bw1KC; };
    FragJobs fj;
    int nf = 0;
    auto fjob = [&](const float* src, int O, int I, int OT, int KC) {
        ushort_t* dst = falloc((size_t)2 * 9 * KC * OT * 512);
        fj.j[nf++] = FragJob{src, dst, O, I, OT, KC, 0};
        return dst;
    };
    auto fjobd = [&](const float* src) {
        ushort_t* dst = falloc((size_t)2 * 36 * 4 * 512);
        fj.j[nf++] = FragJob{src, dst, 64, 128, 4, 36, 1};
        return dst;
    };
    DirW Wb, Wf;
    Wb.ow1 = fjob(Pb.ow1, 64, 192, 4, 6);
    Wb.ow2 = fjob(Pb.ow2, 64, 64, 4, 2);
    Wb.ow3 = fjob(Pb.ow3, 64, 64, 4, 2);
    Wb.ow4 = fjob(Pb.ow4, 432, 64, 28, 2);
    Wb.bw1 = fjob(Pb.bw1, 64, 128, 4, 4);
    Wb.bw1KC = 4;
    Wb.bw2 = fjob(Pb.bw2, 64, 64, 4, 2);
    Wb.dw = fjobd(Pb.dw);
    Wf.ow1 = fjob(Pf.ow1, 64, 192, 4, 6);
    Wf.ow2 = fjob(Pf.ow2, 64, 64, 4, 2);
    Wf.ow3 = fjob(Pf.ow3, 64, 64, 4, 2);
    Wf.ow4 = fjob(Pf.ow4, 432, 64, 28, 2);
    Wf.bw1 = fjob(Pf.bw1, 64, 192, 4, 6);
    Wf.bw1KC = 6;
    Wf.bw2 = fjob(Pf.bw2, 64, 64, 4, 2);
    Wf.dw = fjobd(Pf.dw);
    // fusion 1x1 weights (mode 2): O=64, I=128, OT=4, KC=4
    ushort_t* Wfus = falloc((size_t)2 * 4 * 4 * 512);
    fj.j[nf++] = FragJob{fus_w, Wfus, 64, 128, 4, 4, 2};
    frag_all_k<<<dim3(1008, 15), 256, 0, stream>>>(fj);

    // dconv partial buffer (2 x FRAME fp32), after the weight frags
    float* pacc = (float*)((((uintptr_t)fragp) + 15) & ~(uintptr_t)15);

    pack_tr_k<<<dim3(144, 8), 256, 0, stream>>>(x, xpk);

    auto convm = [&](const unsigned* a, const unsigned* b, const unsigned* c2,
                     const ushort_t* frag, int KCfull, const float* bias,
                     const float* addsrc, unsigned* out, int act, int terms) {
        const unsigned* srcs[3] = {a, b, c2};
        const unsigned* S[3] = {nullptr, nullptr, nullptr};
        int B[3] = {0, 0, 0};
        int ns = 0;
        for (int j = 0; j < 3; ++j)
            if (srcs[j]) {
                S[ns] = srcs[j];
                B[ns] = j * 2;
                ++ns;
            }
        if (terms == 2)
            convm_k<2><<<1152, 128, 0, stream>>>(S[0], S[1], S[2], B[0], B[1],
                                                 B[2], ns, frag, KCfull, bias,
                                                 addsrc, out, act);
        else
            convm_k<3><<<1152, 128, 0, stream>>>(S[0], S[1], S[2], B[0], B[1],
                                                 B[2], ns, frag, KCfull, bias,
                                                 addsrc, out, act);
    };

    for (int dir = 0; dir < 2; ++dir) {  // 0 = backward, 1 = forward
        const DirP& P = dir ? Pf : Pb;
        const DirW& W = dir ? Wf : Wb;
        unsigned* feat = dir ? featFpk : featBpk;
        const unsigned* prev1 = nullptr;
        const unsigned* prev2 = nullptr;
        for (int i = 0; i < 8; ++i) {
            int idx = dir ? i : 7 - i;
            const unsigned* cur = xpk + (size_t)idx * FRAME;
            const float* propf = nullptr;
            if (i > 0) {
                // offset/mask path: 2-term (weight-lo dropped)
                convm(prev1, cur, prev2, W.ow1, 6, P.ob1, nullptr, hApk, 1, 2);
                convm(hApk, nullptr, nullptr, W.ow2, 2, P.ob2, nullptr, hBpk, 1, 2);
                convm(hBpk, nullptr, nullptr, W.ow3, 2, P.ob3, nullptr, hApk, 1, 2);
                int ngr4 = (prev2 != nullptr) ? 4 : 2;
                dconv_fused_k<<<1152, 256, 0, stream>>>(
                    prev1, prev2, hApk, W.ow4, P.ob4, W.dw, ngr4, pacc);
                dcomb_k<<<144, 256, 0, stream>>>(pacc, P.db, Dbuf, Dpk);
                propf = Dbuf;
            }
            unsigned* dst = feat + (size_t)idx * FRAME;
            // bw1: 2-term (weight-lo dropped); bw2: 3-term (residual hedge)
            if (dir == 0) {
                convm(cur, (i > 0) ? Dpk : nullptr, nullptr, W.bw1, W.bw1KC,
                      P.bb1, nullptr, hBpk, 1, 2);
            } else {
                convm(cur, featBpk + (size_t)idx * FRAME,
                      (i > 0) ? Dpk : nullptr, W.bw1, W.bw1KC, P.bb1, nullptr,
                      hBpk, 1, 2);
            }
            convm(hBpk, nullptr, nullptr, W.bw2, 2, P.bb2, propf, dst, 0, 3);
            prev2 = prev1;
            prev1 = dst;
        }
    }

    fusem_k<<<dim3(1152, 8), 128, 0, stream>>>(featBpk, featFpk, x, Wfus,
                                               fus_b, (float*)d_out);
}

// Round 10
// 1422.268 us; speedup vs baseline: 1.2633x; 1.0967x over previous
//
#include <hip/hip_runtime.h>
#include <cstddef>
#include <cstdint>

#define HW96 9216
#define FRAME (64 * 9216)

typedef unsigned short ushort_t;
typedef __attribute__((ext_vector_type(8))) short bf16x8;
typedef __attribute__((ext_vector_type(4))) float f32x4;
typedef __attribute__((ext_vector_type(4))) unsigned u32x4;
typedef __attribute__((ext_vector_type(8))) ushort_t u16x8;
typedef __attribute__((ext_vector_type(4))) ushort_t u16x4;

// packed u32 = (bf16 hi bits << 16) | bf16 lo bits; value = hi + lo exactly
__device__ __forceinline__ float unpk(unsigned p) {
    return __uint_as_float(p & 0xFFFF0000u) + __uint_as_float(p << 16);
}
__device__ __forceinline__ unsigned pk(float v) {
    unsigned u = __float_as_uint(v);
    unsigned hi = u & 0xFFFF0000u;
    float rem = v - __uint_as_float(hi);
    unsigned r = __float_as_uint(rem);
    unsigned lo = (r + 0x7FFFu + ((r >> 16) & 1u)) >> 16;
    return hi | (lo & 0xFFFFu);
}
__device__ __forceinline__ void split16(float v, ushort_t& h, ushort_t& l) {
    unsigned u = __float_as_uint(v);
    h = (ushort_t)(u >> 16);
    float rem = v - __uint_as_float(u & 0xFFFF0000u);
    unsigned r = __float_as_uint(rem);
    l = (ushort_t)((r + 0x7FFFu + ((r >> 16) & 1u)) >> 16);
}
__device__ __forceinline__ ushort_t bf16rnd(float v) {
    unsigned u = __float_as_uint(v);
    return (ushort_t)((u + 0x7FFFu + ((u >> 16) & 1u)) >> 16);
}
__device__ __forceinline__ float bfh(ushort_t h) {
    return __uint_as_float(((unsigned)h) << 16);
}

// ---------------------------------------------------------------------------
// MFMA A-fragment prepack (16x16x32) with bf16 hi/lo split.
// mode 0 (3x3 conv): layout [hl][t][cc][ot][lane][j]; K = cin chunks of 32.
// mode 1 (dconv):    layout [hl][cc][ot][lane][j]; K = g*72 + tap*8 + c.
// mode 2 (1x1 conv): layout [hl][cc][ot][lane][j]; K = cin chunks of 32.
// ---------------------------------------------------------------------------
struct FragJob { const float* src; ushort_t* dst; int O, I, OT, KC, mode; };
struct FragJobs { FragJob j[15]; };

__global__ __launch_bounds__(256) void frag_all_k(FragJobs jobs) {
    const FragJob& J = jobs.j[blockIdx.y];
    int idx = blockIdx.x * 256 + threadIdx.x;
    int total = ((J.mode == 0) ? 9 : 1) * J.KC * J.OT * 512;
    if (idx >= total) return;
    int jj = idx & 7;
    int lane = (idx >> 3) & 63;
    int rem = idx >> 9;
    int ot = rem % J.OT;
    rem /= J.OT;
    int cc = rem % J.KC;
    int t = rem / J.KC;
    int o = ot * 16 + (lane & 15);
    float wv = 0.f;
    if (J.mode == 0) {
        int ci = cc * 32 + (lane >> 4) * 8 + jj;
        if (o < J.O && ci < J.I) wv = J.src[(o * J.I + ci) * 9 + t];
    } else if (J.mode == 1) {
        int K = cc * 32 + (lane >> 4) * 8 + jj;
        int g = K / 72, r2 = K % 72;
        int tap = r2 >> 3, c = r2 & 7;
        int ci = g * 8 + c;
        if (o < J.O && ci < J.I) wv = J.src[(o * J.I + ci) * 9 + tap];
    } else {  // mode 2: 1x1
        int ci = cc * 32 + (lane >> 4) * 8 + jj;
        if (o < J.O && ci < J.I) wv = J.src[o * J.I + ci];
    }
    ushort_t h, l;
    split16(wv, h, l);
    J.dst[idx] = h;
    J.dst[total + idx] = l;
}

// ---------------------------------------------------------------------------
// Transposing pack: planar fp32 frames -> interleaved [px][64ch] packed u32.
// ---------------------------------------------------------------------------
__global__ __launch_bounds__(256) void pack_tr_k(const float* __restrict__ src,
                                                 unsigned* __restrict__ dst) {
    const int t = blockIdx.y;
    const int px0 = blockIdx.x * 64;
    __shared__ unsigned tile[64 * 65];
    const float* s = src + (size_t)t * FRAME;
    unsigned* d = dst + (size_t)t * FRAME;
#pragma unroll
    for (int it = 0; it < 16; ++it) {
        int e = it * 256 + threadIdx.x;
        int p = e & 63, ch = e >> 6;
        tile[ch * 65 + p] = pk(s[(size_t)ch * HW96 + px0 + p]);
    }
    __syncthreads();
#pragma unroll
    for (int it = 0; it < 16; ++it) {
        int e = it * 256 + threadIdx.x;
        int ch = e & 63, p = e >> 6;
        d[(size_t)(px0 + p) * 64 + ch] = tile[ch * 65 + p];
    }
}

// ---------------------------------------------------------------------------
// MFMA implicit-GEMM 3x3 conv, 16x16x32 bf16.
// TERMS=3: AhBh + AlBh + AhBl (fp32-grade: bw2). TERMS=2: AhBh + AhBl.
// addsrc path (bw2): v += addsrc[off] + addsrc2[off] + abias[cout]  (pacc).
// outhi: optional bf16-hi interleaved shadow write (gather source frames).
// ---------------------------------------------------------------------------
template <int TERMS>
__global__ __launch_bounds__(128, 3) void convm_k(
    const unsigned* __restrict__ s0, const unsigned* __restrict__ s1,
    const unsigned* __restrict__ s2, int b0, int b1, int b2, int nsrc,
    const ushort_t* __restrict__ wfrag, int KCfull,
    const float* __restrict__ bias, const float* __restrict__ addsrc,
    const float* __restrict__ addsrc2, const float* __restrict__ abias,
    ushort_t* __restrict__ outhi, unsigned* __restrict__ outpk, int act) {
    const int tid = threadIdx.x;
    const int lane = tid & 63;
    const int w = tid >> 6;              // 0..1
    const int h = blockIdx.x & 1;       // cout half
    const int bseg = blockIdx.x >> 1;   // px segment
    const int ot = h * 2 + w;           // global out-tile 0..3
    const int xb = (bseg % 6) * 16;
    const int y = bseg / 6;
    const int n = lane & 15;
    const int quad = lane >> 4;

    __shared__ __align__(16) ushort_t ldsH[3 * 18 * 72];
    __shared__ __align__(16) ushort_t ldsL[3 * 18 * 72];

    // staging job decode (loop-invariant): 432 jobs = 54 (r,c) x 8 octets
    int jst[4], jok[4], joff[4], jbase[4];
#pragma unroll
    for (int i = 0; i < 4; ++i) {
        int e = tid + i * 128;
        int rc = e >> 3, cg = e & 7;
        int r = rc / 18, col = rc - r * 18;
        int gy = y - 1 + r, gx = xb - 1 + col;
        jst[i] = (e < 432);
        jok[i] = jst[i] && ((unsigned)gy < 96u) && ((unsigned)gx < 96u);
        joff[i] = (gy * 96 + gx) * 64 + cg * 8;
        jbase[i] = rc * 72 + cg * 8;
    }

    f32x4 acc0, acc1;
#pragma unroll
    for (int r = 0; r < 4; ++r) { acc0[r] = 0.f; acc1[r] = 0.f; }

    const size_t hlOff = (size_t)9 * KCfull * 4 * 512;

    for (int j = 0; j < nsrc; ++j) {
        const unsigned* sv = (j == 0) ? s0 : (j == 1 ? s1 : s2);
        const int base = (j == 0) ? b0 : (j == 1 ? b1 : b2);
        __syncthreads();
#pragma unroll
        for (int i = 0; i < 4; ++i) {
            if (jst[i]) {
                u32x4 a, b;
                if (jok[i]) {
                    a = *(const u32x4*)(sv + joff[i]);
                    b = *(const u32x4*)(sv + joff[i] + 4);
                } else {
#pragma unroll
                    for (int q = 0; q < 4; ++q) { a[q] = 0; b[q] = 0; }
                }
                u32x4 H, L;
#pragma unroll
                for (int q = 0; q < 2; ++q) {
                    H[q] = (a[2 * q] >> 16) | (a[2 * q + 1] & 0xFFFF0000u);
                    L[q] = (a[2 * q] & 0xFFFFu) | (a[2 * q + 1] << 16);
                    H[2 + q] = (b[2 * q] >> 16) | (b[2 * q + 1] & 0xFFFF0000u);
                    L[2 + q] = (b[2 * q] & 0xFFFFu) | (b[2 * q + 1] << 16);
                }
                *(u32x4*)(ldsH + jbase[i]) = H;
                *(u32x4*)(ldsL + jbase[i]) = L;
            }
        }
        __syncthreads();
        // depth-5 rolling pipeline over 18 steps (t = s>>1, cc2 = s&1)
        bf16x8 pAh[5], pAl[5], pBh[5], pBl[5];
#pragma unroll
        for (int s = 0; s < 23; ++s) {
            if (s >= 5) {  // consume BEFORE refilling the slot
                const int u = s - 5;
                const bf16x8 Ah = pAh[u % 5];
                const bf16x8 Bh = pBh[u % 5], Bl = pBl[u % 5];
                if (u & 1) {
                    acc1 = __builtin_amdgcn_mfma_f32_16x16x32_bf16(Ah, Bh, acc1, 0, 0, 0);
                    if (TERMS == 3)
                        acc1 = __builtin_amdgcn_mfma_f32_16x16x32_bf16(pAl[u % 5], Bh, acc1, 0, 0, 0);
                    acc1 = __builtin_amdgcn_mfma_f32_16x16x32_bf16(Ah, Bl, acc1, 0, 0, 0);
                } else {
                    acc0 = __builtin_amdgcn_mfma_f32_16x16x32_bf16(Ah, Bh, acc0, 0, 0, 0);
                    if (TERMS == 3)
                        acc0 = __builtin_amdgcn_mfma_f32_16x16x32_bf16(pAl[u % 5], Bh, acc0, 0, 0, 0);
                    acc0 = __builtin_amdgcn_mfma_f32_16x16x32_bf16(Ah, Bl, acc0, 0, 0, 0);
                }
            }
            if (s < 18) {
                const int t = s >> 1, cc2 = s & 1;
                const int ky = t / 3, kx = t % 3;
                const int ccor = base + cc2;
                const ushort_t* ab =
                    wfrag + (((size_t)(t * KCfull + ccor) * 4 + ot) * 64 + lane) * 8;
                pAh[s % 5] = *(const bf16x8*)ab;
                if (TERMS == 3) pAl[s % 5] = *(const bf16x8*)(ab + hlOff);
                const int lb = (ky * 18 + n + kx) * 72 + cc2 * 32 + quad * 8;
                pBh[s % 5] = *(const bf16x8*)(ldsH + lb);
                pBl[s % 5] = *(const bf16x8*)(ldsL + lb);
            }
        }
    }

    const int px = y * 96 + xb + n;
    u16x4 hi4;
#pragma unroll
    for (int r = 0; r < 4; ++r) {
        int cout = ot * 16 + quad * 4 + r;
        float v = acc0[r] + acc1[r] + bias[cout];
        if (act) v = (v >= 0.f) ? v : 0.1f * v;
        if (addsrc) {
            size_t off = (size_t)cout * HW96 + px;
            v += addsrc[off] + addsrc2[off] + abias[cout];
        }
        outpk[(size_t)px * 64 + cout] = pk(v);
        hi4[r] = bf16rnd(v);
    }
    if (outhi)
        *(u16x4*)(outhi + (size_t)px * 64 + ot * 16 + quad * 4) = hi4;
}

// ---------------------------------------------------------------------------
// Fused ow4 + modulated deformable conv, HALF-SPLIT: grid 1152 = 576 seg x 2.
// Gather now reads bf16-hi shadow feats (u16x8: ONE 16B load per corner,
// 4 requests/job instead of 8). Phase 3 dconv MFMA 2-term.
// ---------------------------------------------------------------------------
__global__ __launch_bounds__(256) void dconv_fused_k(
    const ushort_t* __restrict__ sAh, const ushort_t* __restrict__ sBh,
    const unsigned* __restrict__ hA, const ushort_t* __restrict__ w4,
    const float* __restrict__ ob4, const ushort_t* __restrict__ dwf,
    int ngr4, float* __restrict__ pacc) {
    const int tid = threadIdx.x;
    const int lane = tid & 63;
    const int w = tid >> 6;
    const int h = blockIdx.x & 1;
    const int seg = blockIdx.x >> 1;
    const int xb = (seg % 6) * 16;
    const int y = seg / 6;
    const int n = lane & 15;
    const int quad = lane >> 4;

    __shared__ __align__(16) char smem[15232 + 18944];
    float* rawS = (float*)smem;               // up to [224][17] fp32
    ushort_t* ldsAH = (ushort_t*)(smem + 15232);  // 3888 ushorts
    ushort_t* ldsAL = ldsAH + 3888;               // (15552 B <= 18944)
    ushort_t* colsH = (ushort_t*)(smem + 15232);  // union with ldsA
    ushort_t* colsL = colsH + 4736;

    // ---- out-tile ranges for this half (derived from ngr4) ----
    const int nrounds = ngr4 >> 1;   // 1 or 2
    const int ng = nrounds * 4;      // groups per half
    const int g0 = h * ng;
    const int otO_s = (g0 * 18) >> 4;
    const int otO_e = (g0 * 18 + ng * 18 - 1) >> 4;
    const int nO = otO_e - otO_s + 1;
    const int otM_s = (288 + g0 * 9) >> 4;
    const int otM_e = (288 + g0 * 9 + ng * 9 - 1) >> 4;
    const int nM = otM_e - otM_s + 1;
    const int nt = nO + nM;          // 14 (ngr4=4) or 8 (ngr4=2)
    const int rowOffO = otO_s * 16;
    const int rowOffM = otM_s * 16 - nO * 16;

    // ---- phase 1: stage hA window (interleaved source) ----
#pragma unroll
    for (int i = 0; i < 2; ++i) {
        int e = tid + i * 256;
        if (e < 432) {
            int rc = e >> 3, cg = e & 7;
            int r = rc / 18, col = rc - r * 18;
            int gy = y - 1 + r, gx = xb - 1 + col;
            bool ok = ((unsigned)gy < 96u) && ((unsigned)gx < 96u);
            u32x4 a, b;
            if (ok) {
                int off = (gy * 96 + gx) * 64 + cg * 8;
                a = *(const u32x4*)(hA + off);
                b = *(const u32x4*)(hA + off + 4);
            } else {
#pragma unroll
                for (int q = 0; q < 4; ++q) { a[q] = 0; b[q] = 0; }
            }
            u32x4 H, L;
#pragma unroll
            for (int q = 0; q < 2; ++q) {
                H[q] = (a[2 * q] >> 16) | (a[2 * q + 1] & 0xFFFF0000u);
                L[q] = (a[2 * q] & 0xFFFFu) | (a[2 * q + 1] << 16);
                H[2 + q] = (b[2 * q] >> 16) | (b[2 * q + 1] & 0xFFFF0000u);
                L[2 + q] = (b[2 * q] & 0xFFFFu) | (b[2 * q + 1] << 16);
            }
            *(u32x4*)(ldsAH + rc * 72 + cg * 8) = H;
            *(u32x4*)(ldsAL + rc * 72 + cg * 8) = L;
        }
    }
    __syncthreads();

    // ---- phase 2: needed ow4 out-tiles, 2-term, depth-5 pipeline ----
#pragma unroll 1
    for (int j = 0; j < 4; ++j) {
        const int idx = j * 4 + w;
        if (idx >= nt) break;
        const int ot = (idx < nO) ? (otO_s + idx) : (otM_s + (idx - nO));
        f32x4 a0, a1;
#pragma unroll
        for (int r = 0; r < 4; ++r) { a0[r] = 0.f; a1[r] = 0.f; }
        bf16x8 pAh[5], pBh[5], pBl[5];
#pragma unroll
        for (int s = 0; s < 23; ++s) {
            if (s >= 5) {  // consume BEFORE refilling the slot
                const int u = s - 5;
                const bf16x8 Ah = pAh[u % 5];
                const bf16x8 Bh = pBh[u % 5], Bl = pBl[u % 5];
                if (u & 1) {
                    a1 = __builtin_amdgcn_mfma_f32_16x16x32_bf16(Ah, Bh, a1, 0, 0, 0);
                    a1 = __builtin_amdgcn_mfma_f32_16x16x32_bf16(Ah, Bl, a1, 0, 0, 0);
                } else {
                    a0 = __builtin_amdgcn_mfma_f32_16x16x32_bf16(Ah, Bh, a0, 0, 0, 0);
                    a0 = __builtin_amdgcn_mfma_f32_16x16x32_bf16(Ah, Bl, a0, 0, 0, 0);
                }
            }
            if (s < 18) {
                const int t = s >> 1, cc2 = s & 1;
                const int ky = t / 3, kx = t % 3;
                const ushort_t* ab =
                    w4 + (((size_t)s * 28 + ot) * 64 + lane) * 8;
                pAh[s % 5] = *(const bf16x8*)ab;
                const int lb = (ky * 18 + n + kx) * 72 + cc2 * 32 + quad * 8;
                pBh[s % 5] = *(const bf16x8*)(ldsAH + lb);
                pBl[s % 5] = *(const bf16x8*)(ldsAL + lb);
            }
        }
#pragma unroll
        for (int r = 0; r < 4; ++r) {
            int cout = ot * 16 + quad * 4 + r;
            float v = a0[r] + a1[r] + (cout < 432 ? ob4[cout] : 0.f);
            rawS[(idx * 16 + quad * 4 + r) * 17 + n] = v;
        }
    }

    // ---- phase 3: gather (bf16-hi, 1 load/corner) + dconv MFMA (2-term) ----
    f32x4 acc0, acc1;
#pragma unroll
    for (int r = 0; r < 4; ++r) { acc0[r] = 0.f; acc1[r] = 0.f; }

    for (int gci = 0; gci < nrounds; ++gci) {
        const int gc = h * nrounds + gci;
        __syncthreads();  // rawS ready / cols (ldsA) reuse safe
#pragma unroll
        for (int i = 0; i < 3; ++i) {
            int e = tid + i * 256;
            if (e < 576) {
                int p = e & 15;
                int r = e >> 4;  // 0..35
                int gl = r / 9, k = r - gl * 9;
                int g = gc * 4 + gl;
                float ry = rawS[(g * 18 + k * 2 + 0 - rowOffO) * 17 + p];
                float rx = rawS[(g * 18 + k * 2 + 1 - rowOffO) * 17 + p];
                float rm = rawS[(288 + g * 9 + k - rowOffM) * 17 + p];
                float oy = 5.f * (1.f - 2.f / (1.f + __expf(2.f * ry)));
                float ox = 5.f * (1.f - 2.f / (1.f + __expf(2.f * rx)));
                float m = 1.f / (1.f + __expf(-rm));
                float sy = oy + (float)(y - 1 + k / 3);
                float sx = ox + (float)(xb + p - 1 + k % 3);
                float fy0 = floorf(sy), fx0 = floorf(sx);
                float fy = sy - fy0, fx = sx - fx0;
                int y0 = (int)fy0, x0 = (int)fx0;
                int y1 = y0 + 1, x1 = x0 + 1;
                bool vy0 = (unsigned)y0 < 96u, vy1 = (unsigned)y1 < 96u;
                bool vx0 = (unsigned)x0 < 96u, vx1 = (unsigned)x1 < 96u;
                int cy0 = min(max(y0, 0), 95), cy1 = min(max(y1, 0), 95);
                int cx0 = min(max(x0, 0), 95), cx1 = min(max(x1, 0), 95);
                float w00 = (1.f - fy) * (1.f - fx) * ((vy0 && vx0) ? 1.f : 0.f);
                float w01 = (1.f - fy) * fx * ((vy0 && vx1) ? 1.f : 0.f);
                float w10 = fy * (1.f - fx) * ((vy1 && vx0) ? 1.f : 0.f);
                float w11 = fy * fx * ((vy1 && vx1) ? 1.f : 0.f);
                const ushort_t* src = (g < 8) ? sAh : sBh;
                int cb = (g & 7) * 8;
                int kbase = p * 296 + gl * 72 + k * 8;
                ushort_t hh[8], ll[8];
                if (src) {
                    u16x8 c00 = *(const u16x8*)(src + (cy0 * 96 + cx0) * 64 + cb);
                    u16x8 c01 = *(const u16x8*)(src + (cy0 * 96 + cx1) * 64 + cb);
                    u16x8 c10 = *(const u16x8*)(src + (cy1 * 96 + cx0) * 64 + cb);
                    u16x8 c11 = *(const u16x8*)(src + (cy1 * 96 + cx1) * 64 + cb);
#pragma unroll
                    for (int c = 0; c < 8; ++c) {
                        float v = w00 * bfh(c00[c]) + w01 * bfh(c01[c]) +
                                  w10 * bfh(c10[c]) + w11 * bfh(c11[c]);
                        split16(v * m, hh[c], ll[c]);
                    }
                } else {
#pragma unroll
                    for (int c = 0; c < 8; ++c) { hh[c] = 0; ll[c] = 0; }
                }
                u32x4 H, L;
#pragma unroll
                for (int q = 0; q < 4; ++q) {
                    H[q] = (unsigned)hh[2 * q] | ((unsigned)hh[2 * q + 1] << 16);
                    L[q] = (unsigned)ll[2 * q] | ((unsigned)ll[2 * q + 1] << 16);
                }
                *(u32x4*)(colsH + kbase) = H;
                *(u32x4*)(colsL + kbase) = L;
            }
        }
        __syncthreads();
        bf16x8 qAh[4], qBh[4], qBl[4];
#pragma unroll
        for (int s = 0; s < 13; ++s) {
            if (s >= 4) {  // consume BEFORE refilling the slot
                const int u = s - 4;
                const bf16x8 Ah = qAh[u % 4];
                const bf16x8 Bh = qBh[u % 4], Bl = qBl[u % 4];
                if (u & 1) {
                    acc1 = __builtin_amdgcn_mfma_f32_16x16x32_bf16(Ah, Bh, acc1, 0, 0, 0);
                    acc1 = __builtin_amdgcn_mfma_f32_16x16x32_bf16(Ah, Bl, acc1, 0, 0, 0);
                } else {
                    acc0 = __builtin_amdgcn_mfma_f32_16x16x32_bf16(Ah, Bh, acc0, 0, 0, 0);
                    acc0 = __builtin_amdgcn_mfma_f32_16x16x32_bf16(Ah, Bl, acc0, 0, 0, 0);
                }
            }
            if (s < 9) {
                const int cc = gc * 9 + s;
                const ushort_t* ab = dwf + (((size_t)cc * 4 + w) * 64 + lane) * 8;
                qAh[s % 4] = *(const bf16x8*)ab;
                const int lb = n * 296 + s * 32 + quad * 8;
                qBh[s % 4] = *(const bf16x8*)(colsH + lb);
                qBl[s % 4] = *(const bf16x8*)(colsL + lb);
            }
        }
    }

    const int pidx = y * 96 + xb + n;
#pragma unroll
    for (int r = 0; r < 4; ++r) {
        int cout = w * 16 + quad * 4 + r;
        pacc[(size_t)h * FRAME + (size_t)cout * HW96 + pidx] =
            acc0[r] + acc1[r];
    }
}

// ---------------------------------------------------------------------------
// Combine dconv partials -> Dpk (interleaved packed) only; bw2 reads pacc
// directly as its addsrc (Dbuf retired). grid 144.
// ---------------------------------------------------------------------------
__global__ __launch_bounds__(256) void dcomb_k(const float* __restrict__ pacc,
                                               const float* __restrict__ dbias,
                                               unsigned* __restrict__ outpk) {
    const int px0 = blockIdx.x * 64;
    __shared__ unsigned tile[64 * 65];
#pragma unroll
    for (int it = 0; it < 16; ++it) {
        int e = it * 256 + threadIdx.x;
        int p = e & 63, ch = e >> 6;
        size_t off = (size_t)ch * HW96 + px0 + p;
        float v = pacc[off] + pacc[(size_t)FRAME + off] + dbias[ch];
        tile[ch * 65 + p] = pk(v);
    }
    __syncthreads();
#pragma unroll
    for (int it = 0; it < 16; ++it) {
        int e = it * 256 + threadIdx.x;
        int ch = e & 63, p = e >> 6;
        outpk[(size_t)(px0 + p) * 64 + ch] = tile[ch * 65 + p];
    }
}

// ---------------------------------------------------------------------------
// MFMA fusion: 1x1 conv over [featB[t], featF[t]] (K=128) + bias + x.
// ---------------------------------------------------------------------------
__global__ __launch_bounds__(128) void fusem_k(
    const unsigned* __restrict__ featB, const unsigned* __restrict__ featF,
    const float* __restrict__ x, const ushort_t* __restrict__ wfrag,
    const float* __restrict__ bias, float* __restrict__ out) {
    const int tid = threadIdx.x;
    const int lane = tid & 63;
    const int w = tid >> 6;
    const int h = blockIdx.x & 1;
    const int bseg = blockIdx.x >> 1;
    const int t = blockIdx.y;
    const int ot = h * 2 + w;
    const int xb = (bseg % 6) * 16;
    const int y = bseg / 6;
    const int n = lane & 15;
    const int quad = lane >> 4;

    __shared__ __align__(16) ushort_t ldsH[16 * 144];
    __shared__ __align__(16) ushort_t ldsL[16 * 144];

    const int p = tid >> 3, cg = tid & 7;
    const int off = ((y * 96 + xb + p) * 64 + cg * 8);
#pragma unroll
    for (int i = 0; i < 2; ++i) {  // i=0: featB (ch 0-63), i=1: featF (64-127)
        const unsigned* sv =
            (i == 0 ? featB : featF) + (size_t)t * FRAME;
        u32x4 a = *(const u32x4*)(sv + off);
        u32x4 b = *(const u32x4*)(sv + off + 4);
        u32x4 H, L;
#pragma unroll
        for (int q = 0; q < 2; ++q) {
            H[q] = (a[2 * q] >> 16) | (a[2 * q + 1] & 0xFFFF0000u);
            L[q] = (a[2 * q] & 0xFFFFu) | (a[2 * q + 1] << 16);
            H[2 + q] = (b[2 * q] >> 16) | (b[2 * q + 1] & 0xFFFF0000u);
            L[2 + q] = (b[2 * q] & 0xFFFFu) | (b[2 * q + 1] << 16);
        }
        *(u32x4*)(ldsH + p * 144 + i * 64 + cg * 8) = H;
        *(u32x4*)(ldsL + p * 144 + i * 64 + cg * 8) = L;
    }
    __syncthreads();

    f32x4 acc0, acc1;
#pragma unroll
    for (int r = 0; r < 4; ++r) { acc0[r] = 0.f; acc1[r] = 0.f; }
    const size_t hlOff = (size_t)4 * 4 * 512;
#pragma unroll
    for (int cc = 0; cc < 4; ++cc) {
        const ushort_t* ab = wfrag + (((size_t)cc * 4 + ot) * 64 + lane) * 8;
        bf16x8 Ah = *(const bf16x8*)ab;
        bf16x8 Al = *(const bf16x8*)(ab + hlOff);
        int lb = n * 144 + cc * 32 + quad * 8;
        bf16x8 Bh = *(const bf16x8*)(ldsH + lb);
        bf16x8 Bl = *(const bf16x8*)(ldsL + lb);
        if (cc & 1) {
            acc1 = __builtin_amdgcn_mfma_f32_16x16x32_bf16(Ah, Bh, acc1, 0, 0, 0);
            acc1 = __builtin_amdgcn_mfma_f32_16x16x32_bf16(Al, Bh, acc1, 0, 0, 0);
            acc1 = __builtin_amdgcn_mfma_f32_16x16x32_bf16(Ah, Bl, acc1, 0, 0, 0);
        } else {
            acc0 = __builtin_amdgcn_mfma_f32_16x16x32_bf16(Ah, Bh, acc0, 0, 0, 0);
            acc0 = __builtin_amdgcn_mfma_f32_16x16x32_bf16(Al, Bh, acc0, 0, 0, 0);
            acc0 = __builtin_amdgcn_mfma_f32_16x16x32_bf16(Ah, Bl, acc0, 0, 0, 0);
        }
    }

    const int pidx = y * 96 + xb + n;
    const float* xt = x + (size_t)t * FRAME;
    float* od = out + (size_t)t * FRAME;
#pragma unroll
    for (int r = 0; r < 4; ++r) {
        int cout = ot * 16 + quad * 4 + r;
        size_t o2 = (size_t)cout * HW96 + pidx;
        od[o2] = acc0[r] + acc1[r] + bias[cout] + xt[o2];
    }
}

// ---------------------------------------------------------------------------
extern "C" void kernel_launch(void* const* d_in, const int* in_sizes, int n_in,
                              void* d_out, int out_size, void* d_ws,
                              size_t ws_size, hipStream_t stream) {
    const float* x = (const float*)d_in[0];
    auto gp = [&](int i) { return (const float*)d_in[i]; };

    struct DirP {
        const float *dw, *db, *ow1, *ob1, *ow2, *ob2, *ow3, *ob3, *ow4, *ob4,
            *bw1, *bb1, *bw2, *bb2;
    };
    DirP Pb{gp(1), gp(2), gp(3), gp(4), gp(5), gp(6), gp(7),
            gp(8), gp(9), gp(10), gp(11), gp(12), gp(13), gp(14)};
    DirP Pf{gp(15), gp(16), gp(17), gp(18), gp(19), gp(20), gp(21),
            gp(22), gp(23), gp(24), gp(25), gp(26), gp(27), gp(28)};
    const float* fus_w = gp(29);
    const float* fus_b = gp(30);

    // ---- workspace carve-up (4-byte units); all feature bufs interleaved ----
    unsigned* featBpk = (unsigned*)d_ws;
    unsigned* featFpk = featBpk + (size_t)8 * FRAME;
    unsigned* xpk = featFpk + (size_t)8 * FRAME;
    unsigned* Dpk = xpk + (size_t)8 * FRAME;          // interleaved packed
    unsigned* hApk = Dpk + FRAME;
    unsigned* hBpk = hApk + FRAME;
    ushort_t* fragp = (ushort_t*)(hBpk + FRAME);

    auto falloc = [&](size_t nelem) {
        ushort_t* p = fragp;
        fragp += nelem;
        return p;
    };

    struct DirW { ushort_t *ow1, *ow2, *ow3, *ow4, *bw1, *bw2, *dw; int bw1KC; };
    FragJobs fj;
    int nf = 0;
    auto fjob = [&](const float* src, int O, int I, int OT, int KC) {
        ushort_t* dst = falloc((size_t)2 * 9 * KC * OT * 512);
        fj.j[nf++] = FragJob{src, dst, O, I, OT, KC, 0};
        return dst;
    };
    auto fjobd = [&](const float* src) {
        ushort_t* dst = falloc((size_t)2 * 36 * 4 * 512);
        fj.j[nf++] = FragJob{src, dst, 64, 128, 4, 36, 1};
        return dst;
    };
    DirW Wb, Wf;
    Wb.ow1 = fjob(Pb.ow1, 64, 192, 4, 6);
    Wb.ow2 = fjob(Pb.ow2, 64, 64, 4, 2);
    Wb.ow3 = fjob(Pb.ow3, 64, 64, 4, 2);
    Wb.ow4 = fjob(Pb.ow4, 432, 64, 28, 2);
    Wb.bw1 = fjob(Pb.bw1, 64, 128, 4, 4);
    Wb.bw1KC = 4;
    Wb.bw2 = fjob(Pb.bw2, 64, 64, 4, 2);
    Wb.dw = fjobd(Pb.dw);
    Wf.ow1 = fjob(Pf.ow1, 64, 192, 4, 6);
    Wf.ow2 = fjob(Pf.ow2, 64, 64, 4, 2);
    Wf.ow3 = fjob(Pf.ow3, 64, 64, 4, 2);
    Wf.ow4 = fjob(Pf.ow4, 432, 64, 28, 2);
    Wf.bw1 = fjob(Pf.bw1, 64, 192, 4, 6);
    Wf.bw1KC = 6;
    Wf.bw2 = fjob(Pf.bw2, 64, 64, 4, 2);
    Wf.dw = fjobd(Pf.dw);
    // fusion 1x1 weights (mode 2): O=64, I=128, OT=4, KC=4
    ushort_t* Wfus = falloc((size_t)2 * 4 * 4 * 512);
    fj.j[nf++] = FragJob{fus_w, Wfus, 64, 128, 4, 4, 2};
    frag_all_k<<<dim3(1008, 15), 256, 0, stream>>>(fj);

    // after frags: pacc (2 x FRAME f32), then bf16-hi feat shadows (16 frames)
    float* pacc = (float*)((((uintptr_t)fragp) + 15) & ~(uintptr_t)15);
    ushort_t* featBh = (ushort_t*)(pacc + (size_t)2 * FRAME);
    ushort_t* featFh = featBh + (size_t)8 * FRAME;

    pack_tr_k<<<dim3(144, 8), 256, 0, stream>>>(x, xpk);

    auto convm = [&](const unsigned* a, const unsigned* b, const unsigned* c2,
                     const ushort_t* frag, int KCfull, const float* bias,
                     const float* add, const float* add2, const float* abias,
                     ushort_t* outhi, unsigned* out, int act, int terms) {
        const unsigned* srcs[3] = {a, b, c2};
        const unsigned* S[3] = {nullptr, nullptr, nullptr};
        int B[3] = {0, 0, 0};
        int ns = 0;
        for (int j = 0; j < 3; ++j)
            if (srcs[j]) {
                S[ns] = srcs[j];
                B[ns] = j * 2;
                ++ns;
            }
        if (terms == 2)
            convm_k<2><<<1152, 128, 0, stream>>>(S[0], S[1], S[2], B[0], B[1],
                                                 B[2], ns, frag, KCfull, bias,
                                                 add, add2, abias, outhi, out,
                                                 act);
        else
            convm_k<3><<<1152, 128, 0, stream>>>(S[0], S[1], S[2], B[0], B[1],
                                                 B[2], ns, frag, KCfull, bias,
                                                 add, add2, abias, outhi, out,
                                                 act);
    };

    for (int dir = 0; dir < 2; ++dir) {  // 0 = backward, 1 = forward
        const DirP& P = dir ? Pf : Pb;
        const DirW& W = dir ? Wf : Wb;
        unsigned* feat = dir ? featFpk : featBpk;
        ushort_t* feath = dir ? featFh : featBh;
        const unsigned* prev1 = nullptr;
        const unsigned* prev2 = nullptr;
        const ushort_t* prev1h = nullptr;
        const ushort_t* prev2h = nullptr;
        for (int i = 0; i < 8; ++i) {
            int idx = dir ? i : 7 - i;
            const unsigned* cur = xpk + (size_t)idx * FRAME;
            bool hasD = false;
            if (i > 0) {
                // offset/mask path: 2-term (weight-lo dropped)
                convm(prev1, cur, prev2, W.ow1, 6, P.ob1, nullptr, nullptr,
                      nullptr, nullptr, hApk, 1, 2);
                convm(hApk, nullptr, nullptr, W.ow2, 2, P.ob2, nullptr,
                      nullptr, nullptr, nullptr, hBpk, 1, 2);
                convm(hBpk, nullptr, nullptr, W.ow3, 2, P.ob3, nullptr,
                      nullptr, nullptr, nullptr, hApk, 1, 2);
                int ngr4 = (prev2 != nullptr) ? 4 : 2;
                dconv_fused_k<<<1152, 256, 0, stream>>>(
                    prev1h, prev2h, hApk, W.ow4, P.ob4, W.dw, ngr4, pacc);
                dcomb_k<<<144, 256, 0, stream>>>(pacc, P.db, Dpk);
                hasD = true;
            }
            unsigned* dst = feat + (size_t)idx * FRAME;
            ushort_t* dsth = feath + (size_t)idx * FRAME;
            // bw1: 2-term; bw2: 3-term + pacc addsrc + hi shadow write
            if (dir == 0) {
                convm(cur, hasD ? Dpk : nullptr, nullptr, W.bw1, W.bw1KC,
                      P.bb1, nullptr, nullptr, nullptr, nullptr, hBpk, 1, 2);
            } else {
                convm(cur, featBpk + (size_t)idx * FRAME,
                      hasD ? Dpk : nullptr, W.bw1, W.bw1KC, P.bb1, nullptr,
                      nullptr, nullptr, nullptr, hBpk, 1, 2);
            }
            convm(hBpk, nullptr, nullptr, W.bw2, 2, P.bb2,
                  hasD ? pacc : nullptr, pacc + FRAME, P.db, dsth, dst, 0, 3);
            prev2 = prev1;
            prev1 = dst;
            prev2h = prev1h;
            prev1h = dsth;
        }
    }

    fusem_k<<<dim3(1152, 8), 128, 0, stream>>>(featBpk, featFpk, x, Wfus,
                                               fus_b, (float*)d_out);
}

// Round 11
// 1303.408 us; speedup vs baseline: 1.3785x; 1.0912x over previous
//
#include <hip/hip_runtime.h>
#include <cstddef>
#include <cstdint>

#define HW96 9216
#define FRAME (64 * 9216)

typedef unsigned short ushort_t;
typedef __attribute__((ext_vector_type(8))) short bf16x8;
typedef __attribute__((ext_vector_type(4))) float f32x4;
typedef __attribute__((ext_vector_type(4))) unsigned u32x4;
typedef __attribute__((ext_vector_type(8))) ushort_t u16x8;
typedef __attribute__((ext_vector_type(4))) ushort_t u16x4;

// packed u32 = (bf16 hi bits << 16) | bf16 lo bits; value = hi + lo exactly
__device__ __forceinline__ float unpk(unsigned p) {
    return __uint_as_float(p & 0xFFFF0000u) + __uint_as_float(p << 16);
}
__device__ __forceinline__ unsigned pk(float v) {
    unsigned u = __float_as_uint(v);
    unsigned hi = u & 0xFFFF0000u;
    float rem = v - __uint_as_float(hi);
    unsigned r = __float_as_uint(rem);
    unsigned lo = (r + 0x7FFFu + ((r >> 16) & 1u)) >> 16;
    return hi | (lo & 0xFFFFu);
}
__device__ __forceinline__ void split16(float v, ushort_t& h, ushort_t& l) {
    unsigned u = __float_as_uint(v);
    h = (ushort_t)(u >> 16);
    float rem = v - __uint_as_float(u & 0xFFFF0000u);
    unsigned r = __float_as_uint(rem);
    l = (ushort_t)((r + 0x7FFFu + ((r >> 16) & 1u)) >> 16);
}
__device__ __forceinline__ ushort_t bf16rnd(float v) {
    unsigned u = __float_as_uint(v);
    return (ushort_t)((u + 0x7FFFu + ((u >> 16) & 1u)) >> 16);
}
__device__ __forceinline__ float bfh(ushort_t h) {
    return __uint_as_float(((unsigned)h) << 16);
}

// ---------------------------------------------------------------------------
// MFMA A-fragment prepack (16x16x32) with bf16 hi/lo split.
// mode 0 (3x3 conv): layout [hl][t][cc][ot][lane][j]; K = cin chunks of 32.
// mode 1 (dconv):    layout [hl][cc][ot][lane][j]; K = g*72 + tap*8 + c.
// mode 2 (1x1 conv): layout [hl][cc][ot][lane][j]; K = cin chunks of 32.
// ---------------------------------------------------------------------------
struct FragJob { const float* src; ushort_t* dst; int O, I, OT, KC, mode; };
struct FragJobs { FragJob j[15]; };

__global__ __launch_bounds__(256) void frag_all_k(FragJobs jobs) {
    const FragJob& J = jobs.j[blockIdx.y];
    int idx = blockIdx.x * 256 + threadIdx.x;
    int total = ((J.mode == 0) ? 9 : 1) * J.KC * J.OT * 512;
    if (idx >= total) return;
    int jj = idx & 7;
    int lane = (idx >> 3) & 63;
    int rem = idx >> 9;
    int ot = rem % J.OT;
    rem /= J.OT;
    int cc = rem % J.KC;
    int t = rem / J.KC;
    int o = ot * 16 + (lane & 15);
    float wv = 0.f;
    if (J.mode == 0) {
        int ci = cc * 32 + (lane >> 4) * 8 + jj;
        if (o < J.O && ci < J.I) wv = J.src[(o * J.I + ci) * 9 + t];
    } else if (J.mode == 1) {
        int K = cc * 32 + (lane >> 4) * 8 + jj;
        int g = K / 72, r2 = K % 72;
        int tap = r2 >> 3, c = r2 & 7;
        int ci = g * 8 + c;
        if (o < J.O && ci < J.I) wv = J.src[(o * J.I + ci) * 9 + tap];
    } else {  // mode 2: 1x1
        int ci = cc * 32 + (lane >> 4) * 8 + jj;
        if (o < J.O && ci < J.I) wv = J.src[o * J.I + ci];
    }
    ushort_t h, l;
    split16(wv, h, l);
    J.dst[idx] = h;
    J.dst[total + idx] = l;
}

// ---------------------------------------------------------------------------
// Transposing pack: planar fp32 -> interleaved packed u32 + bf16-hi shadow.
// ---------------------------------------------------------------------------
__global__ __launch_bounds__(256) void pack_tr_k(const float* __restrict__ src,
                                                 unsigned* __restrict__ dst,
                                                 ushort_t* __restrict__ dsth) {
    const int t = blockIdx.y;
    const int px0 = blockIdx.x * 64;
    __shared__ unsigned tile[64 * 65];
    const float* s = src + (size_t)t * FRAME;
    unsigned* d = dst + (size_t)t * FRAME;
    ushort_t* dh = dsth + (size_t)t * FRAME;
#pragma unroll
    for (int it = 0; it < 16; ++it) {
        int e = it * 256 + threadIdx.x;
        int p = e & 63, ch = e >> 6;
        tile[ch * 65 + p] = pk(s[(size_t)ch * HW96 + px0 + p]);
    }
    __syncthreads();
#pragma unroll
    for (int it = 0; it < 16; ++it) {
        int e = it * 256 + threadIdx.x;
        int ch = e & 63, p = e >> 6;
        unsigned v = tile[ch * 65 + p];
        d[(size_t)(px0 + p) * 64 + ch] = v;
        dh[(size_t)(px0 + p) * 64 + ch] = (ushort_t)(v >> 16);
    }
}

// ---------------------------------------------------------------------------
// MFMA implicit-GEMM 3x3 conv, 16x16x32 bf16 (feature path).
// TERMS=3: AhBh + AlBh + AhBl (bw2). TERMS=2: AhBh + AhBl (bw1).
// addsrc path (bw2): v += addsrc[off] + addsrc2[off] + abias[cout]  (pacc).
// outhi: optional bf16-hi interleaved shadow write (gather source frames).
// ---------------------------------------------------------------------------
template <int TERMS>
__global__ __launch_bounds__(128, 3) void convm_k(
    const unsigned* __restrict__ s0, const unsigned* __restrict__ s1,
    const unsigned* __restrict__ s2, int b0, int b1, int b2, int nsrc,
    const ushort_t* __restrict__ wfrag, int KCfull,
    const float* __restrict__ bias, const float* __restrict__ addsrc,
    const float* __restrict__ addsrc2, const float* __restrict__ abias,
    ushort_t* __restrict__ outhi, unsigned* __restrict__ outpk, int act) {
    const int tid = threadIdx.x;
    const int lane = tid & 63;
    const int w = tid >> 6;              // 0..1
    const int h = blockIdx.x & 1;       // cout half
    const int bseg = blockIdx.x >> 1;   // px segment
    const int ot = h * 2 + w;           // global out-tile 0..3
    const int xb = (bseg % 6) * 16;
    const int y = bseg / 6;
    const int n = lane & 15;
    const int quad = lane >> 4;

    __shared__ __align__(16) ushort_t ldsH[3 * 18 * 72];
    __shared__ __align__(16) ushort_t ldsL[3 * 18 * 72];

    // staging job decode (loop-invariant): 432 jobs = 54 (r,c) x 8 octets
    int jst[4], jok[4], joff[4], jbase[4];
#pragma unroll
    for (int i = 0; i < 4; ++i) {
        int e = tid + i * 128;
        int rc = e >> 3, cg = e & 7;
        int r = rc / 18, col = rc - r * 18;
        int gy = y - 1 + r, gx = xb - 1 + col;
        jst[i] = (e < 432);
        jok[i] = jst[i] && ((unsigned)gy < 96u) && ((unsigned)gx < 96u);
        joff[i] = (gy * 96 + gx) * 64 + cg * 8;
        jbase[i] = rc * 72 + cg * 8;
    }

    f32x4 acc0, acc1;
#pragma unroll
    for (int r = 0; r < 4; ++r) { acc0[r] = 0.f; acc1[r] = 0.f; }

    const size_t hlOff = (size_t)9 * KCfull * 4 * 512;

    for (int j = 0; j < nsrc; ++j) {
        const unsigned* sv = (j == 0) ? s0 : (j == 1 ? s1 : s2);
        const int base = (j == 0) ? b0 : (j == 1 ? b1 : b2);
        __syncthreads();
#pragma unroll
        for (int i = 0; i < 4; ++i) {
            if (jst[i]) {
                u32x4 a, b;
                if (jok[i]) {
                    a = *(const u32x4*)(sv + joff[i]);
                    b = *(const u32x4*)(sv + joff[i] + 4);
                } else {
#pragma unroll
                    for (int q = 0; q < 4; ++q) { a[q] = 0; b[q] = 0; }
                }
                u32x4 H, L;
#pragma unroll
                for (int q = 0; q < 2; ++q) {
                    H[q] = (a[2 * q] >> 16) | (a[2 * q + 1] & 0xFFFF0000u);
                    L[q] = (a[2 * q] & 0xFFFFu) | (a[2 * q + 1] << 16);
                    H[2 + q] = (b[2 * q] >> 16) | (b[2 * q + 1] & 0xFFFF0000u);
                    L[2 + q] = (b[2 * q] & 0xFFFFu) | (b[2 * q + 1] << 16);
                }
                *(u32x4*)(ldsH + jbase[i]) = H;
                *(u32x4*)(ldsL + jbase[i]) = L;
            }
        }
        __syncthreads();
        // depth-5 rolling pipeline over 18 steps (t = s>>1, cc2 = s&1)
        bf16x8 pAh[5], pAl[5], pBh[5], pBl[5];
#pragma unroll
        for (int s = 0; s < 23; ++s) {
            if (s >= 5) {  // consume BEFORE refilling the slot
                const int u = s - 5;
                const bf16x8 Ah = pAh[u % 5];
                const bf16x8 Bh = pBh[u % 5], Bl = pBl[u % 5];
                if (u & 1) {
                    acc1 = __builtin_amdgcn_mfma_f32_16x16x32_bf16(Ah, Bh, acc1, 0, 0, 0);
                    if (TERMS == 3)
                        acc1 = __builtin_amdgcn_mfma_f32_16x16x32_bf16(pAl[u % 5], Bh, acc1, 0, 0, 0);
                    acc1 = __builtin_amdgcn_mfma_f32_16x16x32_bf16(Ah, Bl, acc1, 0, 0, 0);
                } else {
                    acc0 = __builtin_amdgcn_mfma_f32_16x16x32_bf16(Ah, Bh, acc0, 0, 0, 0);
                    if (TERMS == 3)
                        acc0 = __builtin_amdgcn_mfma_f32_16x16x32_bf16(pAl[u % 5], Bh, acc0, 0, 0, 0);
                    acc0 = __builtin_amdgcn_mfma_f32_16x16x32_bf16(Ah, Bl, acc0, 0, 0, 0);
                }
            }
            if (s < 18) {
                const int t = s >> 1, cc2 = s & 1;
                const int ky = t / 3, kx = t % 3;
                const int ccor = base + cc2;
                const ushort_t* ab =
                    wfrag + (((size_t)(t * KCfull + ccor) * 4 + ot) * 64 + lane) * 8;
                pAh[s % 5] = *(const bf16x8*)ab;
                if (TERMS == 3) pAl[s % 5] = *(const bf16x8*)(ab + hlOff);
                const int lb = (ky * 18 + n + kx) * 72 + cc2 * 32 + quad * 8;
                pBh[s % 5] = *(const bf16x8*)(ldsH + lb);
                pBl[s % 5] = *(const bf16x8*)(ldsL + lb);
            }
        }
    }

    const int px = y * 96 + xb + n;
    u16x4 hi4;
#pragma unroll
    for (int r = 0; r < 4; ++r) {
        int cout = ot * 16 + quad * 4 + r;
        float v = acc0[r] + acc1[r] + bias[cout];
        if (act) v = (v >= 0.f) ? v : 0.1f * v;
        if (addsrc) {
            size_t off = (size_t)cout * HW96 + px;
            v += addsrc[off] + addsrc2[off] + abias[cout];
        }
        outpk[(size_t)px * 64 + cout] = pk(v);
        hi4[r] = bf16rnd(v);
    }
    if (outhi)
        *(u16x4*)(outhi + (size_t)px * 64 + ot * 16 + quad * 4) = hi4;
}

// ---------------------------------------------------------------------------
// Hi-only bf16 MFMA 3x3 conv (offset/mask path: ow1/ow2/ow3).
// Sources are bf16-hi interleaved ushort[px][64]; staging = 1 u16x8 per job;
// LDS is H-only (7.8 KB); 1 MFMA per K-step (AhBh); bf16-hi ushort output.
// ---------------------------------------------------------------------------
__global__ __launch_bounds__(128, 3) void convh_k(
    const ushort_t* __restrict__ s0, const ushort_t* __restrict__ s1,
    const ushort_t* __restrict__ s2, int b0, int b1, int b2, int nsrc,
    const ushort_t* __restrict__ wfrag, int KCfull,
    const float* __restrict__ bias, ushort_t* __restrict__ outhi, int act) {
    const int tid = threadIdx.x;
    const int lane = tid & 63;
    const int w = tid >> 6;
    const int h = blockIdx.x & 1;
    const int bseg = blockIdx.x >> 1;
    const int ot = h * 2 + w;
    const int xb = (bseg % 6) * 16;
    const int y = bseg / 6;
    const int n = lane & 15;
    const int quad = lane >> 4;

    __shared__ __align__(16) ushort_t ldsH[3 * 18 * 72];

    int jst[4], jok[4], joff[4], jbase[4];
#pragma unroll
    for (int i = 0; i < 4; ++i) {
        int e = tid + i * 128;
        int rc = e >> 3, cg = e & 7;
        int r = rc / 18, col = rc - r * 18;
        int gy = y - 1 + r, gx = xb - 1 + col;
        jst[i] = (e < 432);
        jok[i] = jst[i] && ((unsigned)gy < 96u) && ((unsigned)gx < 96u);
        joff[i] = (gy * 96 + gx) * 64 + cg * 8;
        jbase[i] = rc * 72 + cg * 8;
    }

    f32x4 acc0, acc1;
#pragma unroll
    for (int r = 0; r < 4; ++r) { acc0[r] = 0.f; acc1[r] = 0.f; }

    for (int j = 0; j < nsrc; ++j) {
        const ushort_t* sv = (j == 0) ? s0 : (j == 1 ? s1 : s2);
        const int base = (j == 0) ? b0 : (j == 1 ? b1 : b2);
        __syncthreads();
#pragma unroll
        for (int i = 0; i < 4; ++i) {
            if (jst[i]) {
                u16x8 a;
                if (jok[i]) {
                    a = *(const u16x8*)(sv + joff[i]);
                } else {
#pragma unroll
                    for (int q = 0; q < 8; ++q) a[q] = 0;
                }
                *(u16x8*)(ldsH + jbase[i]) = a;
            }
        }
        __syncthreads();
        // depth-5 rolling pipeline over 18 steps, 1 MFMA each
        bf16x8 pAh[5], pBh[5];
#pragma unroll
        for (int s = 0; s < 23; ++s) {
            if (s >= 5) {  // consume BEFORE refilling the slot
                const int u = s - 5;
                const bf16x8 Ah = pAh[u % 5];
                const bf16x8 Bh = pBh[u % 5];
                if (u & 1)
                    acc1 = __builtin_amdgcn_mfma_f32_16x16x32_bf16(Ah, Bh, acc1, 0, 0, 0);
                else
                    acc0 = __builtin_amdgcn_mfma_f32_16x16x32_bf16(Ah, Bh, acc0, 0, 0, 0);
            }
            if (s < 18) {
                const int t = s >> 1, cc2 = s & 1;
                const int ky = t / 3, kx = t % 3;
                const int ccor = base + cc2;
                const ushort_t* ab =
                    wfrag + (((size_t)(t * KCfull + ccor) * 4 + ot) * 64 + lane) * 8;
                pAh[s % 5] = *(const bf16x8*)ab;
                const int lb = (ky * 18 + n + kx) * 72 + cc2 * 32 + quad * 8;
                pBh[s % 5] = *(const bf16x8*)(ldsH + lb);
            }
        }
    }

    const int px = y * 96 + xb + n;
    u16x4 hi4;
#pragma unroll
    for (int r = 0; r < 4; ++r) {
        int cout = ot * 16 + quad * 4 + r;
        float v = acc0[r] + acc1[r] + bias[cout];
        if (act) v = (v >= 0.f) ? v : 0.1f * v;
        hi4[r] = bf16rnd(v);
    }
    *(u16x4*)(outhi + (size_t)px * 64 + ot * 16 + quad * 4) = hi4;
}

// ---------------------------------------------------------------------------
// Fused ow4 + modulated deformable conv, HALF-SPLIT: grid 1152 = 576 seg x 2.
// hA input is bf16-hi (ushort): phase-1 staging = 1 u16x8/job, H-only LDS;
// phase-2 = 1 MFMA per K-step. Gather reads bf16-hi shadow feats.
// ---------------------------------------------------------------------------
__global__ __launch_bounds__(256) void dconv_fused_k(
    const ushort_t* __restrict__ sAh, const ushort_t* __restrict__ sBh,
    const ushort_t* __restrict__ hAh, const ushort_t* __restrict__ w4,
    const float* __restrict__ ob4, const ushort_t* __restrict__ dwf,
    int ngr4, float* __restrict__ pacc) {
    const int tid = threadIdx.x;
    const int lane = tid & 63;
    const int w = tid >> 6;
    const int h = blockIdx.x & 1;
    const int seg = blockIdx.x >> 1;
    const int xb = (seg % 6) * 16;
    const int y = seg / 6;
    const int n = lane & 15;
    const int quad = lane >> 4;

    __shared__ __align__(16) char smem[15232 + 18944];
    float* rawS = (float*)smem;               // up to [224][17] fp32
    ushort_t* ldsAH = (ushort_t*)(smem + 15232);  // 3888 ushorts (H-only)
    ushort_t* colsH = (ushort_t*)(smem + 15232);  // union with ldsA
    ushort_t* colsL = colsH + 4736;

    // ---- out-tile ranges for this half (derived from ngr4) ----
    const int nrounds = ngr4 >> 1;   // 1 or 2
    const int ng = nrounds * 4;      // groups per half
    const int g0 = h * ng;
    const int otO_s = (g0 * 18) >> 4;
    const int otO_e = (g0 * 18 + ng * 18 - 1) >> 4;
    const int nO = otO_e - otO_s + 1;
    const int otM_s = (288 + g0 * 9) >> 4;
    const int otM_e = (288 + g0 * 9 + ng * 9 - 1) >> 4;
    const int nM = otM_e - otM_s + 1;
    const int nt = nO + nM;          // 14 (ngr4=4) or 8 (ngr4=2)
    const int rowOffO = otO_s * 16;
    const int rowOffM = otM_s * 16 - nO * 16;

    // ---- phase 1: stage hA window (bf16-hi source, 1 load/job) ----
#pragma unroll
    for (int i = 0; i < 2; ++i) {
        int e = tid + i * 256;
        if (e < 432) {
            int rc = e >> 3, cg = e & 7;
            int r = rc / 18, col = rc - r * 18;
            int gy = y - 1 + r, gx = xb - 1 + col;
            bool ok = ((unsigned)gy < 96u) && ((unsigned)gx < 96u);
            u16x8 a;
            if (ok) {
                a = *(const u16x8*)(hAh + (gy * 96 + gx) * 64 + cg * 8);
            } else {
#pragma unroll
                for (int q = 0; q < 8; ++q) a[q] = 0;
            }
            *(u16x8*)(ldsAH + rc * 72 + cg * 8) = a;
        }
    }
    __syncthreads();

    // ---- phase 2: needed ow4 out-tiles, 1 MFMA/step, depth-5 pipeline ----
#pragma unroll 1
    for (int j = 0; j < 4; ++j) {
        const int idx = j * 4 + w;
        if (idx >= nt) break;
        const int ot = (idx < nO) ? (otO_s + idx) : (otM_s + (idx - nO));
        f32x4 a0, a1;
#pragma unroll
        for (int r = 0; r < 4; ++r) { a0[r] = 0.f; a1[r] = 0.f; }
        bf16x8 pAh[5], pBh[5];
#pragma unroll
        for (int s = 0; s < 23; ++s) {
            if (s >= 5) {  // consume BEFORE refilling the slot
                const int u = s - 5;
                const bf16x8 Ah = pAh[u % 5];
                const bf16x8 Bh = pBh[u % 5];
                if (u & 1)
                    a1 = __builtin_amdgcn_mfma_f32_16x16x32_bf16(Ah, Bh, a1, 0, 0, 0);
                else
                    a0 = __builtin_amdgcn_mfma_f32_16x16x32_bf16(Ah, Bh, a0, 0, 0, 0);
            }
            if (s < 18) {
                const int t = s >> 1, cc2 = s & 1;
                const int ky = t / 3, kx = t % 3;
                const ushort_t* ab =
                    w4 + (((size_t)s * 28 + ot) * 64 + lane) * 8;
                pAh[s % 5] = *(const bf16x8*)ab;
                const int lb = (ky * 18 + n + kx) * 72 + cc2 * 32 + quad * 8;
                pBh[s % 5] = *(const bf16x8*)(ldsAH + lb);
            }
        }
#pragma unroll
        for (int r = 0; r < 4; ++r) {
            int cout = ot * 16 + quad * 4 + r;
            float v = a0[r] + a1[r] + (cout < 432 ? ob4[cout] : 0.f);
            rawS[(idx * 16 + quad * 4 + r) * 17 + n] = v;
        }
    }

    // ---- phase 3: gather (bf16-hi, 1 load/corner) + dconv MFMA (2-term) ----
    f32x4 acc0, acc1;
#pragma unroll
    for (int r = 0; r < 4; ++r) { acc0[r] = 0.f; acc1[r] = 0.f; }

    for (int gci = 0; gci < nrounds; ++gci) {
        const int gc = h * nrounds + gci;
        __syncthreads();  // rawS ready / cols (ldsA) reuse safe
#pragma unroll
        for (int i = 0; i < 3; ++i) {
            int e = tid + i * 256;
            if (e < 576) {
                int p = e & 15;
                int r = e >> 4;  // 0..35
                int gl = r / 9, k = r - gl * 9;
                int g = gc * 4 + gl;
                float ry = rawS[(g * 18 + k * 2 + 0 - rowOffO) * 17 + p];
                float rx = rawS[(g * 18 + k * 2 + 1 - rowOffO) * 17 + p];
                float rm = rawS[(288 + g * 9 + k - rowOffM) * 17 + p];
                float oy = 5.f * (1.f - 2.f / (1.f + __expf(2.f * ry)));
                float ox = 5.f * (1.f - 2.f / (1.f + __expf(2.f * rx)));
                float m = 1.f / (1.f + __expf(-rm));
                float sy = oy + (float)(y - 1 + k / 3);
                float sx = ox + (float)(xb + p - 1 + k % 3);
                float fy0 = floorf(sy), fx0 = floorf(sx);
                float fy = sy - fy0, fx = sx - fx0;
                int y0 = (int)fy0, x0 = (int)fx0;
                int y1 = y0 + 1, x1 = x0 + 1;
                bool vy0 = (unsigned)y0 < 96u, vy1 = (unsigned)y1 < 96u;
                bool vx0 = (unsigned)x0 < 96u, vx1 = (unsigned)x1 < 96u;
                int cy0 = min(max(y0, 0), 95), cy1 = min(max(y1, 0), 95);
                int cx0 = min(max(x0, 0), 95), cx1 = min(max(x1, 0), 95);
                float w00 = (1.f - fy) * (1.f - fx) * ((vy0 && vx0) ? 1.f : 0.f);
                float w01 = (1.f - fy) * fx * ((vy0 && vx1) ? 1.f : 0.f);
                float w10 = fy * (1.f - fx) * ((vy1 && vx0) ? 1.f : 0.f);
                float w11 = fy * fx * ((vy1 && vx1) ? 1.f : 0.f);
                const ushort_t* src = (g < 8) ? sAh : sBh;
                int cb = (g & 7) * 8;
                int kbase = p * 296 + gl * 72 + k * 8;
                ushort_t hh[8], ll[8];
                if (src) {
                    u16x8 c00 = *(const u16x8*)(src + (cy0 * 96 + cx0) * 64 + cb);
                    u16x8 c01 = *(const u16x8*)(src + (cy0 * 96 + cx1) * 64 + cb);
                    u16x8 c10 = *(const u16x8*)(src + (cy1 * 96 + cx0) * 64 + cb);
                    u16x8 c11 = *(const u16x8*)(src + (cy1 * 96 + cx1) * 64 + cb);
#pragma unroll
                    for (int c = 0; c < 8; ++c) {
                        float v = w00 * bfh(c00[c]) + w01 * bfh(c01[c]) +
                                  w10 * bfh(c10[c]) + w11 * bfh(c11[c]);
                        split16(v * m, hh[c], ll[c]);
                    }
                } else {
#pragma unroll
                    for (int c = 0; c < 8; ++c) { hh[c] = 0; ll[c] = 0; }
                }
                u32x4 H, L;
#pragma unroll
                for (int q = 0; q < 4; ++q) {
                    H[q] = (unsigned)hh[2 * q] | ((unsigned)hh[2 * q + 1] << 16);
                    L[q] = (unsigned)ll[2 * q] | ((unsigned)ll[2 * q + 1] << 16);
                }
                *(u32x4*)(colsH + kbase) = H;
                *(u32x4*)(colsL + kbase) = L;
            }
        }
        __syncthreads();
        bf16x8 qAh[4], qBh[4], qBl[4];
#pragma unroll
        for (int s = 0; s < 13; ++s) {
            if (s >= 4) {  // consume BEFORE refilling the slot
                const int u = s - 4;
                const bf16x8 Ah = qAh[u % 4];
                const bf16x8 Bh = qBh[u % 4], Bl = qBl[u % 4];
                if (u & 1) {
                    acc1 = __builtin_amdgcn_mfma_f32_16x16x32_bf16(Ah, Bh, acc1, 0, 0, 0);
                    acc1 = __builtin_amdgcn_mfma_f32_16x16x32_bf16(Ah, Bl, acc1, 0, 0, 0);
                } else {
                    acc0 = __builtin_amdgcn_mfma_f32_16x16x32_bf16(Ah, Bh, acc0, 0, 0, 0);
                    acc0 = __builtin_amdgcn_mfma_f32_16x16x32_bf16(Ah, Bl, acc0, 0, 0, 0);
                }
            }
            if (s < 9) {
                const int cc = gc * 9 + s;
                const ushort_t* ab = dwf + (((size_t)cc * 4 + w) * 64 + lane) * 8;
                qAh[s % 4] = *(const bf16x8*)ab;
                const int lb = n * 296 + s * 32 + quad * 8;
                qBh[s % 4] = *(const bf16x8*)(colsH + lb);
                qBl[s % 4] = *(const bf16x8*)(colsL + lb);
            }
        }
    }

    const int pidx = y * 96 + xb + n;
#pragma unroll
    for (int r = 0; r < 4; ++r) {
        int cout = w * 16 + quad * 4 + r;
        pacc[(size_t)h * FRAME + (size_t)cout * HW96 + pidx] =
            acc0[r] + acc1[r];
    }
}

// ---------------------------------------------------------------------------
// Combine dconv partials -> Dpk (interleaved packed); bw2 reads pacc
// directly as its addsrc. grid 144.
// ---------------------------------------------------------------------------
__global__ __launch_bounds__(256) void dcomb_k(const float* __restrict__ pacc,
                                               const float* __restrict__ dbias,
                                               unsigned* __restrict__ outpk) {
    const int px0 = blockIdx.x * 64;
    __shared__ unsigned tile[64 * 65];
#pragma unroll
    for (int it = 0; it < 16; ++it) {
        int e = it * 256 + threadIdx.x;
        int p = e & 63, ch = e >> 6;
        size_t off = (size_t)ch * HW96 + px0 + p;
        float v = pacc[off] + pacc[(size_t)FRAME + off] + dbias[ch];
        tile[ch * 65 + p] = pk(v);
    }
    __syncthreads();
#pragma unroll
    for (int it = 0; it < 16; ++it) {
        int e = it * 256 + threadIdx.x;
        int ch = e & 63, p = e >> 6;
        outpk[(size_t)(px0 + p) * 64 + ch] = tile[ch * 65 + p];
    }
}

// ---------------------------------------------------------------------------
// MFMA fusion: 1x1 conv over [featB[t], featF[t]] (K=128) + bias + x.
// ---------------------------------------------------------------------------
__global__ __launch_bounds__(128) void fusem_k(
    const unsigned* __restrict__ featB, const unsigned* __restrict__ featF,
    const float* __restrict__ x, const ushort_t* __restrict__ wfrag,
    const float* __restrict__ bias, float* __restrict__ out) {
    const int tid = threadIdx.x;
    const int lane = tid & 63;
    const int w = tid >> 6;
    const int h = blockIdx.x & 1;
    const int bseg = blockIdx.x >> 1;
    const int t = blockIdx.y;
    const int ot = h * 2 + w;
    const int xb = (bseg % 6) * 16;
    const int y = bseg / 6;
    const int n = lane & 15;
    const int quad = lane >> 4;

    __shared__ __align__(16) ushort_t ldsH[16 * 144];
    __shared__ __align__(16) ushort_t ldsL[16 * 144];

    const int p = tid >> 3, cg = tid & 7;
    const int off = ((y * 96 + xb + p) * 64 + cg * 8);
#pragma unroll
    for (int i = 0; i < 2; ++i) {  // i=0: featB (ch 0-63), i=1: featF (64-127)
        const unsigned* sv =
            (i == 0 ? featB : featF) + (size_t)t * FRAME;
        u32x4 a = *(const u32x4*)(sv + off);
        u32x4 b = *(const u32x4*)(sv + off + 4);
        u32x4 H, L;
#pragma unroll
        for (int q = 0; q < 2; ++q) {
            H[q] = (a[2 * q] >> 16) | (a[2 * q + 1] & 0xFFFF0000u);
            L[q] = (a[2 * q] & 0xFFFFu) | (a[2 * q + 1] << 16);
            H[2 + q] = (b[2 * q] >> 16) | (b[2 * q + 1] & 0xFFFF0000u);
            L[2 + q] = (b[2 * q] & 0xFFFFu) | (b[2 * q + 1] << 16);
        }
        *(u32x4*)(ldsH + p * 144 + i * 64 + cg * 8) = H;
        *(u32x4*)(ldsL + p * 144 + i * 64 + cg * 8) = L;
    }
    __syncthreads();

    f32x4 acc0, acc1;
#pragma unroll
    for (int r = 0; r < 4; ++r) { acc0[r] = 0.f; acc1[r] = 0.f; }
    const size_t hlOff = (size_t)4 * 4 * 512;
#pragma unroll
    for (int cc = 0; cc < 4; ++cc) {
        const ushort_t* ab = wfrag + (((size_t)cc * 4 + ot) * 64 + lane) * 8;
        bf16x8 Ah = *(const bf16x8*)ab;
        bf16x8 Al = *(const bf16x8*)(ab + hlOff);
        int lb = n * 144 + cc * 32 + quad * 8;
        bf16x8 Bh = *(const bf16x8*)(ldsH + lb);
        bf16x8 Bl = *(const bf16x8*)(ldsL + lb);
        if (cc & 1) {
            acc1 = __builtin_amdgcn_mfma_f32_16x16x32_bf16(Ah, Bh, acc1, 0, 0, 0);
            acc1 = __builtin_amdgcn_mfma_f32_16x16x32_bf16(Al, Bh, acc1, 0, 0, 0);
            acc1 = __builtin_amdgcn_mfma_f32_16x16x32_bf16(Ah, Bl, acc1, 0, 0, 0);
        } else {
            acc0 = __builtin_amdgcn_mfma_f32_16x16x32_bf16(Ah, Bh, acc0, 0, 0, 0);
            acc0 = __builtin_amdgcn_mfma_f32_16x16x32_bf16(Al, Bh, acc0, 0, 0, 0);
            acc0 = __builtin_amdgcn_mfma_f32_16x16x32_bf16(Ah, Bl, acc0, 0, 0, 0);
        }
    }

    const int pidx = y * 96 + xb + n;
    const float* xt = x + (size_t)t * FRAME;
    float* od = out + (size_t)t * FRAME;
#pragma unroll
    for (int r = 0; r < 4; ++r) {
        int cout = ot * 16 + quad * 4 + r;
        size_t o2 = (size_t)cout * HW96 + pidx;
        od[o2] = acc0[r] + acc1[r] + bias[cout] + xt[o2];
    }
}

// ---------------------------------------------------------------------------
extern "C" void kernel_launch(void* const* d_in, const int* in_sizes, int n_in,
                              void* d_out, int out_size, void* d_ws,
                              size_t ws_size, hipStream_t stream) {
    const float* x = (const float*)d_in[0];
    auto gp = [&](int i) { return (const float*)d_in[i]; };

    struct DirP {
        const float *dw, *db, *ow1, *ob1, *ow2, *ob2, *ow3, *ob3, *ow4, *ob4,
            *bw1, *bb1, *bw2, *bb2;
    };
    DirP Pb{gp(1), gp(2), gp(3), gp(4), gp(5), gp(6), gp(7),
            gp(8), gp(9), gp(10), gp(11), gp(12), gp(13), gp(14)};
    DirP Pf{gp(15), gp(16), gp(17), gp(18), gp(19), gp(20), gp(21),
            gp(22), gp(23), gp(24), gp(25), gp(26), gp(27), gp(28)};
    const float* fus_w = gp(29);
    const float* fus_b = gp(30);

    // ---- workspace carve-up (4-byte units); all feature bufs interleaved ----
    unsigned* featBpk = (unsigned*)d_ws;
    unsigned* featFpk = featBpk + (size_t)8 * FRAME;
    unsigned* xpk = featFpk + (size_t)8 * FRAME;
    unsigned* Dpk = xpk + (size_t)8 * FRAME;          // interleaved packed
    unsigned* hApk = Dpk + FRAME;                     // ow chain (hi ushort)
    unsigned* hBpk = hApk + FRAME;
    ushort_t* fragp = (ushort_t*)(hBpk + FRAME);

    auto falloc = [&](size_t nelem) {
        ushort_t* p = fragp;
        fragp += nelem;
        return p;
    };

    struct DirW { ushort_t *ow1, *ow2, *ow3, *ow4, *bw1, *bw2, *dw; int bw1KC; };
    FragJobs fj;
    int nf = 0;
    auto fjob = [&](const float* src, int O, int I, int OT, int KC) {
        ushort_t* dst = falloc((size_t)2 * 9 * KC * OT * 512);
        fj.j[nf++] = FragJob{src, dst, O, I, OT, KC, 0};
        return dst;
    };
    auto fjobd = [&](const float* src) {
        ushort_t* dst = falloc((size_t)2 * 36 * 4 * 512);
        fj.j[nf++] = FragJob{src, dst, 64, 128, 4, 36, 1};
        return dst;
    };
    DirW Wb, Wf;
    Wb.ow1 = fjob(Pb.ow1, 64, 192, 4, 6);
    Wb.ow2 = fjob(Pb.ow2, 64, 64, 4, 2);
    Wb.ow3 = fjob(Pb.ow3, 64, 64, 4, 2);
    Wb.ow4 = fjob(Pb.ow4, 432, 64, 28, 2);
    Wb.bw1 = fjob(Pb.bw1, 64, 128, 4, 4);
    Wb.bw1KC = 4;
    Wb.bw2 = fjob(Pb.bw2, 64, 64, 4, 2);
    Wb.dw = fjobd(Pb.dw);
    Wf.ow1 = fjob(Pf.ow1, 64, 192, 4, 6);
    Wf.ow2 = fjob(Pf.ow2, 64, 64, 4, 2);
    Wf.ow3 = fjob(Pf.ow3, 64, 64, 4, 2);
    Wf.ow4 = fjob(Pf.ow4, 432, 64, 28, 2);
    Wf.bw1 = fjob(Pf.bw1, 64, 192, 4, 6);
    Wf.bw1KC = 6;
    Wf.bw2 = fjob(Pf.bw2, 64, 64, 4, 2);
    Wf.dw = fjobd(Pf.dw);
    // fusion 1x1 weights (mode 2): O=64, I=128, OT=4, KC=4
    ushort_t* Wfus = falloc((size_t)2 * 4 * 4 * 512);
    fj.j[nf++] = FragJob{fus_w, Wfus, 64, 128, 4, 4, 2};
    frag_all_k<<<dim3(1008, 15), 256, 0, stream>>>(fj);

    // after frags: pacc (2F f32), feat hi shadows (16 frames), x hi shadow (8)
    float* pacc = (float*)((((uintptr_t)fragp) + 15) & ~(uintptr_t)15);
    ushort_t* featBh = (ushort_t*)(pacc + (size_t)2 * FRAME);
    ushort_t* featFh = featBh + (size_t)8 * FRAME;
    ushort_t* xh = featFh + (size_t)8 * FRAME;
    ushort_t* hAh = (ushort_t*)hApk;
    ushort_t* hBh = (ushort_t*)hBpk;

    pack_tr_k<<<dim3(144, 8), 256, 0, stream>>>(x, xpk, xh);

    auto convm = [&](const unsigned* a, const unsigned* b, const unsigned* c2,
                     const ushort_t* frag, int KCfull, const float* bias,
                     const float* add, const float* add2, const float* abias,
                     ushort_t* outhi, unsigned* out, int act, int terms) {
        const unsigned* srcs[3] = {a, b, c2};
        const unsigned* S[3] = {nullptr, nullptr, nullptr};
        int B[3] = {0, 0, 0};
        int ns = 0;
        for (int j = 0; j < 3; ++j)
            if (srcs[j]) {
                S[ns] = srcs[j];
                B[ns] = j * 2;
                ++ns;
            }
        if (terms == 2)
            convm_k<2><<<1152, 128, 0, stream>>>(S[0], S[1], S[2], B[0], B[1],
                                                 B[2], ns, frag, KCfull, bias,
                                                 add, add2, abias, outhi, out,
                                                 act);
        else
            convm_k<3><<<1152, 128, 0, stream>>>(S[0], S[1], S[2], B[0], B[1],
                                                 B[2], ns, frag, KCfull, bias,
                                                 add, add2, abias, outhi, out,
                                                 act);
    };

    auto convh = [&](const ushort_t* a, const ushort_t* b, const ushort_t* c2,
                     const ushort_t* frag, int KCfull, const float* bias,
                     ushort_t* out, int act) {
        const ushort_t* srcs[3] = {a, b, c2};
        const ushort_t* S[3] = {nullptr, nullptr, nullptr};
        int B[3] = {0, 0, 0};
        int ns = 0;
        for (int j = 0; j < 3; ++j)
            if (srcs[j]) {
                S[ns] = srcs[j];
                B[ns] = j * 2;
                ++ns;
            }
        convh_k<<<1152, 128, 0, stream>>>(S[0], S[1], S[2], B[0], B[1], B[2],
                                          ns, frag, KCfull, bias, out, act);
    };

    for (int dir = 0; dir < 2; ++dir) {  // 0 = backward, 1 = forward
        const DirP& P = dir ? Pf : Pb;
        const DirW& W = dir ? Wf : Wb;
        unsigned* feat = dir ? featFpk : featBpk;
        ushort_t* feath = dir ? featFh : featBh;
        const unsigned* prev1 = nullptr;
        const unsigned* prev2 = nullptr;
        const ushort_t* prev1h = nullptr;
        const ushort_t* prev2h = nullptr;
        for (int i = 0; i < 8; ++i) {
            int idx = dir ? i : 7 - i;
            const unsigned* cur = xpk + (size_t)idx * FRAME;
            const ushort_t* curh = xh + (size_t)idx * FRAME;
            bool hasD = false;
            if (i > 0) {
                // offset/mask path: pure bf16-hi (convh)
                convh(prev1h, curh, prev2h, W.ow1, 6, P.ob1, hAh, 1);
                convh(hAh, nullptr, nullptr, W.ow2, 2, P.ob2, hBh, 1);
                convh(hBh, nullptr, nullptr, W.ow3, 2, P.ob3, hAh, 1);
                int ngr4 = (prev2 != nullptr) ? 4 : 2;
                dconv_fused_k<<<1152, 256, 0, stream>>>(
                    prev1h, prev2h, hAh, W.ow4, P.ob4, W.dw, ngr4, pacc);
                dcomb_k<<<144, 256, 0, stream>>>(pacc, P.db, Dpk);
                hasD = true;
            }
            unsigned* dst = feat + (size_t)idx * FRAME;
            ushort_t* dsth = feath + (size_t)idx * FRAME;
            // bw1: 2-term; bw2: 3-term + pacc addsrc + hi shadow write
            if (dir == 0) {
                convm(cur, hasD ? Dpk : nullptr, nullptr, W.bw1, W.bw1KC,
                      P.bb1, nullptr, nullptr, nullptr, nullptr, hBpk, 1, 2);
            } else {
                convm(cur, featBpk + (size_t)idx * FRAME,
                      hasD ? Dpk : nullptr, W.bw1, W.bw1KC, P.bb1, nullptr,
                      nullptr, nullptr, nullptr, hBpk, 1, 2);
            }
            convm(hBpk, nullptr, nullptr, W.bw2, 2, P.bb2,
                  hasD ? pacc : nullptr, pacc + FRAME, P.db, dsth, dst, 0, 3);
            prev2 = prev1;
            prev1 = dst;
            prev2h = prev1h;
            prev1h = dsth;
        }
    }

    fusem_k<<<dim3(1152, 8), 128, 0, stream>>>(featBpk, featFpk, x, Wfus,
                                               fus_b, (float*)d_out);
}

// Round 12
// 1240.460 us; speedup vs baseline: 1.4484x; 1.0507x over previous
//
#include <hip/hip_runtime.h>
#include <cstddef>
#include <cstdint>

#define HW96 9216
#define FRAME (64 * 9216)

typedef unsigned short ushort_t;
typedef __attribute__((ext_vector_type(8))) short bf16x8;
typedef __attribute__((ext_vector_type(4))) float f32x4;
typedef __attribute__((ext_vector_type(4))) unsigned u32x4;
typedef __attribute__((ext_vector_type(8))) ushort_t u16x8;
typedef __attribute__((ext_vector_type(4))) ushort_t u16x4;

// packed u32 = (bf16 hi bits << 16) | bf16 lo bits; value = hi + lo exactly
__device__ __forceinline__ float unpk(unsigned p) {
    return __uint_as_float(p & 0xFFFF0000u) + __uint_as_float(p << 16);
}
__device__ __forceinline__ unsigned pk(float v) {
    unsigned u = __float_as_uint(v);
    unsigned hi = u & 0xFFFF0000u;
    float rem = v - __uint_as_float(hi);
    unsigned r = __float_as_uint(rem);
    unsigned lo = (r + 0x7FFFu + ((r >> 16) & 1u)) >> 16;
    return hi | (lo & 0xFFFFu);
}
__device__ __forceinline__ void split16(float v, ushort_t& h, ushort_t& l) {
    unsigned u = __float_as_uint(v);
    h = (ushort_t)(u >> 16);
    float rem = v - __uint_as_float(u & 0xFFFF0000u);
    unsigned r = __float_as_uint(rem);
    l = (ushort_t)((r + 0x7FFFu + ((r >> 16) & 1u)) >> 16);
}
__device__ __forceinline__ ushort_t bf16rnd(float v) {
    unsigned u = __float_as_uint(v);
    return (ushort_t)((u + 0x7FFFu + ((u >> 16) & 1u)) >> 16);
}
__device__ __forceinline__ float bfh(ushort_t h) {
    return __uint_as_float(((unsigned)h) << 16);
}

// ---------------------------------------------------------------------------
// MFMA A-fragment prepack (16x16x32) with bf16 hi/lo split.
// mode 0 (3x3 conv): layout [hl][t][cc][ot][lane][j]; K = cin chunks of 32.
// mode 1 (dconv):    layout [hl][cc][ot][lane][j]; K = g*72 + tap*8 + c.
// mode 2 (1x1 conv): layout [hl][cc][ot][lane][j]; K = cin chunks of 32.
// ---------------------------------------------------------------------------
struct FragJob { const float* src; ushort_t* dst; int O, I, OT, KC, mode; };
struct FragJobs { FragJob j[15]; };

__global__ __launch_bounds__(256) void frag_all_k(FragJobs jobs) {
    const FragJob& J = jobs.j[blockIdx.y];
    int idx = blockIdx.x * 256 + threadIdx.x;
    int total = ((J.mode == 0) ? 9 : 1) * J.KC * J.OT * 512;
    if (idx >= total) return;
    int jj = idx & 7;
    int lane = (idx >> 3) & 63;
    int rem = idx >> 9;
    int ot = rem % J.OT;
    rem /= J.OT;
    int cc = rem % J.KC;
    int t = rem / J.KC;
    int o = ot * 16 + (lane & 15);
    float wv = 0.f;
    if (J.mode == 0) {
        int ci = cc * 32 + (lane >> 4) * 8 + jj;
        if (o < J.O && ci < J.I) wv = J.src[(o * J.I + ci) * 9 + t];
    } else if (J.mode == 1) {
        int K = cc * 32 + (lane >> 4) * 8 + jj;
        int g = K / 72, r2 = K % 72;
        int tap = r2 >> 3, c = r2 & 7;
        int ci = g * 8 + c;
        if (o < J.O && ci < J.I) wv = J.src[(o * J.I + ci) * 9 + tap];
    } else {  // mode 2: 1x1
        int ci = cc * 32 + (lane >> 4) * 8 + jj;
        if (o < J.O && ci < J.I) wv = J.src[o * J.I + ci];
    }
    ushort_t h, l;
    split16(wv, h, l);
    J.dst[idx] = h;
    J.dst[total + idx] = l;
}

// ---------------------------------------------------------------------------
// Transposing pack: planar fp32 -> interleaved packed u32 + bf16-hi shadow.
// ---------------------------------------------------------------------------
__global__ __launch_bounds__(256) void pack_tr_k(const float* __restrict__ src,
                                                 unsigned* __restrict__ dst,
                                                 ushort_t* __restrict__ dsth) {
    const int t = blockIdx.y;
    const int px0 = blockIdx.x * 64;
    __shared__ unsigned tile[64 * 65];
    const float* s = src + (size_t)t * FRAME;
    unsigned* d = dst + (size_t)t * FRAME;
    ushort_t* dh = dsth + (size_t)t * FRAME;
#pragma unroll
    for (int it = 0; it < 16; ++it) {
        int e = it * 256 + threadIdx.x;
        int p = e & 63, ch = e >> 6;
        tile[ch * 65 + p] = pk(s[(size_t)ch * HW96 + px0 + p]);
    }
    __syncthreads();
#pragma unroll
    for (int it = 0; it < 16; ++it) {
        int e = it * 256 + threadIdx.x;
        int ch = e & 63, p = e >> 6;
        unsigned v = tile[ch * 65 + p];
        d[(size_t)(px0 + p) * 64 + ch] = v;
        dh[(size_t)(px0 + p) * 64 + ch] = (ushort_t)(v >> 16);
    }
}

// ---------------------------------------------------------------------------
// MFMA implicit-GEMM 3x3 conv, 16x16x32 bf16 (feature path: bw1/bw2).
// TERMS=2: AhBh + AhBl (weight-lo dropped; now both bw1 and bw2).
// Sources are prefix-packed; base K-offset for source j is j*2.
// dslot >= 0: source at that slot is the dconv result, staged directly from
// INTERLEAVED pacc pair (pacc0+pacc1+dbias -> hi/lo split) — dcomb retired.
// bw2 addsrc: v += pacc0[px][c] + pacc1[px][c] + abias[c] (vector loads).
// outhi: optional bf16-hi interleaved shadow write (gather source frames).
// ---------------------------------------------------------------------------
template <int TERMS>
__global__ __launch_bounds__(128, 3) void convm_k(
    const unsigned* __restrict__ s0, const unsigned* __restrict__ s1,
    int nsrc, int dslot, const float* __restrict__ dpacc,
    const float* __restrict__ ddbias, const ushort_t* __restrict__ wfrag,
    int KCfull, const float* __restrict__ bias,
    const float* __restrict__ addsrc, const float* __restrict__ addsrc2,
    const float* __restrict__ abias, ushort_t* __restrict__ outhi,
    unsigned* __restrict__ outpk, int act) {
    const int tid = threadIdx.x;
    const int lane = tid & 63;
    const int w = tid >> 6;              // 0..1
    const int h = blockIdx.x & 1;       // cout half
    const int bseg = blockIdx.x >> 1;   // px segment
    const int ot = h * 2 + w;           // global out-tile 0..3
    const int xb = (bseg % 6) * 16;
    const int y = bseg / 6;
    const int n = lane & 15;
    const int quad = lane >> 4;

    __shared__ __align__(16) ushort_t ldsH[3 * 18 * 72];
    __shared__ __align__(16) ushort_t ldsL[3 * 18 * 72];

    // staging job decode (loop-invariant): 432 jobs = 54 (r,c) x 8 octets
    int jst[4], jok[4], joff[4], jbase[4];
#pragma unroll
    for (int i = 0; i < 4; ++i) {
        int e = tid + i * 128;
        int rc = e >> 3, cg = e & 7;
        int r = rc / 18, col = rc - r * 18;
        int gy = y - 1 + r, gx = xb - 1 + col;
        jst[i] = (e < 432);
        jok[i] = jst[i] && ((unsigned)gy < 96u) && ((unsigned)gx < 96u);
        joff[i] = (gy * 96 + gx) * 64 + cg * 8;
        jbase[i] = rc * 72 + cg * 8;
    }

    f32x4 acc0, acc1;
#pragma unroll
    for (int r = 0; r < 4; ++r) { acc0[r] = 0.f; acc1[r] = 0.f; }

    const size_t hlOff = (size_t)9 * KCfull * 4 * 512;

    for (int j = 0; j < nsrc; ++j) {
        const int base = j * 2;
        __syncthreads();
        if (j == dslot) {
            // stage D = pacc0 + pacc1 + dbias (interleaved f32 pair)
#pragma unroll
            for (int i = 0; i < 4; ++i) {
                if (jst[i]) {
                    ushort_t hh[8], ll[8];
                    if (jok[i]) {
                        const int cg8 = ((tid + i * 128) & 7) << 3;
                        f32x4 a0 = *(const f32x4*)(dpacc + joff[i]);
                        f32x4 a1 = *(const f32x4*)(dpacc + joff[i] + 4);
                        f32x4 b0 = *(const f32x4*)(dpacc + FRAME + joff[i]);
                        f32x4 b1 = *(const f32x4*)(dpacc + FRAME + joff[i] + 4);
                        f32x4 d0 = *(const f32x4*)(ddbias + cg8);
                        f32x4 d1 = *(const f32x4*)(ddbias + cg8 + 4);
#pragma unroll
                        for (int q = 0; q < 4; ++q) {
                            split16(a0[q] + b0[q] + d0[q], hh[q], ll[q]);
                            split16(a1[q] + b1[q] + d1[q], hh[4 + q], ll[4 + q]);
                        }
                    } else {
#pragma unroll
                        for (int q = 0; q < 8; ++q) { hh[q] = 0; ll[q] = 0; }
                    }
                    u32x4 H, L;
#pragma unroll
                    for (int q = 0; q < 4; ++q) {
                        H[q] = (unsigned)hh[2 * q] | ((unsigned)hh[2 * q + 1] << 16);
                        L[q] = (unsigned)ll[2 * q] | ((unsigned)ll[2 * q + 1] << 16);
                    }
                    *(u32x4*)(ldsH + jbase[i]) = H;
                    *(u32x4*)(ldsL + jbase[i]) = L;
                }
            }
        } else {
            const unsigned* sv = (j == 0) ? s0 : s1;
#pragma unroll
            for (int i = 0; i < 4; ++i) {
                if (jst[i]) {
                    u32x4 a, b;
                    if (jok[i]) {
                        a = *(const u32x4*)(sv + joff[i]);
                        b = *(const u32x4*)(sv + joff[i] + 4);
                    } else {
#pragma unroll
                        for (int q = 0; q < 4; ++q) { a[q] = 0; b[q] = 0; }
                    }
                    u32x4 H, L;
#pragma unroll
                    for (int q = 0; q < 2; ++q) {
                        H[q] = (a[2 * q] >> 16) | (a[2 * q + 1] & 0xFFFF0000u);
                        L[q] = (a[2 * q] & 0xFFFFu) | (a[2 * q + 1] << 16);
                        H[2 + q] = (b[2 * q] >> 16) | (b[2 * q + 1] & 0xFFFF0000u);
                        L[2 + q] = (b[2 * q] & 0xFFFFu) | (b[2 * q + 1] << 16);
                    }
                    *(u32x4*)(ldsH + jbase[i]) = H;
                    *(u32x4*)(ldsL + jbase[i]) = L;
                }
            }
        }
        __syncthreads();
        // depth-5 rolling pipeline over 18 steps (t = s>>1, cc2 = s&1)
        bf16x8 pAh[5], pAl[5], pBh[5], pBl[5];
#pragma unroll
        for (int s = 0; s < 23; ++s) {
            if (s >= 5) {  // consume BEFORE refilling the slot
                const int u = s - 5;
                const bf16x8 Ah = pAh[u % 5];
                const bf16x8 Bh = pBh[u % 5], Bl = pBl[u % 5];
                if (u & 1) {
                    acc1 = __builtin_amdgcn_mfma_f32_16x16x32_bf16(Ah, Bh, acc1, 0, 0, 0);
                    if (TERMS == 3)
                        acc1 = __builtin_amdgcn_mfma_f32_16x16x32_bf16(pAl[u % 5], Bh, acc1, 0, 0, 0);
                    acc1 = __builtin_amdgcn_mfma_f32_16x16x32_bf16(Ah, Bl, acc1, 0, 0, 0);
                } else {
                    acc0 = __builtin_amdgcn_mfma_f32_16x16x32_bf16(Ah, Bh, acc0, 0, 0, 0);
                    if (TERMS == 3)
                        acc0 = __builtin_amdgcn_mfma_f32_16x16x32_bf16(pAl[u % 5], Bh, acc0, 0, 0, 0);
                    acc0 = __builtin_amdgcn_mfma_f32_16x16x32_bf16(Ah, Bl, acc0, 0, 0, 0);
                }
            }
            if (s < 18) {
                const int t = s >> 1, cc2 = s & 1;
                const int ky = t / 3, kx = t % 3;
                const int ccor = base + cc2;
                const ushort_t* ab =
                    wfrag + (((size_t)(t * KCfull + ccor) * 4 + ot) * 64 + lane) * 8;
                pAh[s % 5] = *(const bf16x8*)ab;
                if (TERMS == 3) pAl[s % 5] = *(const bf16x8*)(ab + hlOff);
                const int lb = (ky * 18 + n + kx) * 72 + cc2 * 32 + quad * 8;
                pBh[s % 5] = *(const bf16x8*)(ldsH + lb);
                pBl[s % 5] = *(const bf16x8*)(ldsL + lb);
            }
        }
    }

    const int px = y * 96 + xb + n;
    f32x4 pa, pb;
#pragma unroll
    for (int r = 0; r < 4; ++r) { pa[r] = 0.f; pb[r] = 0.f; }
    if (addsrc) {
        pa = *(const f32x4*)(addsrc + (size_t)px * 64 + ot * 16 + quad * 4);
        pb = *(const f32x4*)(addsrc2 + (size_t)px * 64 + ot * 16 + quad * 4);
    }
    u16x4 hi4;
#pragma unroll
    for (int r = 0; r < 4; ++r) {
        int cout = ot * 16 + quad * 4 + r;
        float v = acc0[r] + acc1[r] + bias[cout];
        if (act) v = (v >= 0.f) ? v : 0.1f * v;
        if (addsrc) v += pa[r] + pb[r] + abias[cout];
        outpk[(size_t)px * 64 + cout] = pk(v);
        hi4[r] = bf16rnd(v);
    }
    if (outhi)
        *(u16x4*)(outhi + (size_t)px * 64 + ot * 16 + quad * 4) = hi4;
}

// ---------------------------------------------------------------------------
// Hi-only bf16 MFMA 3x3 conv (offset/mask path: ow1/ow2/ow3).
// Sources are bf16-hi interleaved ushort[px][64]; staging = 1 u16x8 per job;
// LDS is H-only (7.8 KB); 1 MFMA per K-step (AhBh); bf16-hi ushort output.
// ---------------------------------------------------------------------------
__global__ __launch_bounds__(128, 3) void convh_k(
    const ushort_t* __restrict__ s0, const ushort_t* __restrict__ s1,
    const ushort_t* __restrict__ s2, int b0, int b1, int b2, int nsrc,
    const ushort_t* __restrict__ wfrag, int KCfull,
    const float* __restrict__ bias, ushort_t* __restrict__ outhi, int act) {
    const int tid = threadIdx.x;
    const int lane = tid & 63;
    const int w = tid >> 6;
    const int h = blockIdx.x & 1;
    const int bseg = blockIdx.x >> 1;
    const int ot = h * 2 + w;
    const int xb = (bseg % 6) * 16;
    const int y = bseg / 6;
    const int n = lane & 15;
    const int quad = lane >> 4;

    __shared__ __align__(16) ushort_t ldsH[3 * 18 * 72];

    int jst[4], jok[4], joff[4], jbase[4];
#pragma unroll
    for (int i = 0; i < 4; ++i) {
        int e = tid + i * 128;
        int rc = e >> 3, cg = e & 7;
        int r = rc / 18, col = rc - r * 18;
        int gy = y - 1 + r, gx = xb - 1 + col;
        jst[i] = (e < 432);
        jok[i] = jst[i] && ((unsigned)gy < 96u) && ((unsigned)gx < 96u);
        joff[i] = (gy * 96 + gx) * 64 + cg * 8;
        jbase[i] = rc * 72 + cg * 8;
    }

    f32x4 acc0, acc1;
#pragma unroll
    for (int r = 0; r < 4; ++r) { acc0[r] = 0.f; acc1[r] = 0.f; }

    for (int j = 0; j < nsrc; ++j) {
        const ushort_t* sv = (j == 0) ? s0 : (j == 1 ? s1 : s2);
        const int base = (j == 0) ? b0 : (j == 1 ? b1 : b2);
        __syncthreads();
#pragma unroll
        for (int i = 0; i < 4; ++i) {
            if (jst[i]) {
                u16x8 a;
                if (jok[i]) {
                    a = *(const u16x8*)(sv + joff[i]);
                } else {
#pragma unroll
                    for (int q = 0; q < 8; ++q) a[q] = 0;
                }
                *(u16x8*)(ldsH + jbase[i]) = a;
            }
        }
        __syncthreads();
        // depth-5 rolling pipeline over 18 steps, 1 MFMA each
        bf16x8 pAh[5], pBh[5];
#pragma unroll
        for (int s = 0; s < 23; ++s) {
            if (s >= 5) {  // consume BEFORE refilling the slot
                const int u = s - 5;
                const bf16x8 Ah = pAh[u % 5];
                const bf16x8 Bh = pBh[u % 5];
                if (u & 1)
                    acc1 = __builtin_amdgcn_mfma_f32_16x16x32_bf16(Ah, Bh, acc1, 0, 0, 0);
                else
                    acc0 = __builtin_amdgcn_mfma_f32_16x16x32_bf16(Ah, Bh, acc0, 0, 0, 0);
            }
            if (s < 18) {
                const int t = s >> 1, cc2 = s & 1;
                const int ky = t / 3, kx = t % 3;
                const int ccor = base + cc2;
                const ushort_t* ab =
                    wfrag + (((size_t)(t * KCfull + ccor) * 4 + ot) * 64 + lane) * 8;
                pAh[s % 5] = *(const bf16x8*)ab;
                const int lb = (ky * 18 + n + kx) * 72 + cc2 * 32 + quad * 8;
                pBh[s % 5] = *(const bf16x8*)(ldsH + lb);
            }
        }
    }

    const int px = y * 96 + xb + n;
    u16x4 hi4;
#pragma unroll
    for (int r = 0; r < 4; ++r) {
        int cout = ot * 16 + quad * 4 + r;
        float v = acc0[r] + acc1[r] + bias[cout];
        if (act) v = (v >= 0.f) ? v : 0.1f * v;
        hi4[r] = bf16rnd(v);
    }
    *(u16x4*)(outhi + (size_t)px * 64 + ot * 16 + quad * 4) = hi4;
}

// ---------------------------------------------------------------------------
// Fused ow4 + modulated deformable conv, HALF-SPLIT: grid 1152 = 576 seg x 2.
// hA input is bf16-hi (ushort). Gather reads bf16-hi shadow feats.
// pacc output now INTERLEAVED [h][px][64] f32 (one f32x4 store per thread).
// ---------------------------------------------------------------------------
__global__ __launch_bounds__(256) void dconv_fused_k(
    const ushort_t* __restrict__ sAh, const ushort_t* __restrict__ sBh,
    const ushort_t* __restrict__ hAh, const ushort_t* __restrict__ w4,
    const float* __restrict__ ob4, const ushort_t* __restrict__ dwf,
    int ngr4, float* __restrict__ pacc) {
    const int tid = threadIdx.x;
    const int lane = tid & 63;
    const int w = tid >> 6;
    const int h = blockIdx.x & 1;
    const int seg = blockIdx.x >> 1;
    const int xb = (seg % 6) * 16;
    const int y = seg / 6;
    const int n = lane & 15;
    const int quad = lane >> 4;

    __shared__ __align__(16) char smem[15232 + 18944];
    float* rawS = (float*)smem;               // up to [224][17] fp32
    ushort_t* ldsAH = (ushort_t*)(smem + 15232);  // 3888 ushorts (H-only)
    ushort_t* colsH = (ushort_t*)(smem + 15232);  // union with ldsA
    ushort_t* colsL = colsH + 4736;

    // ---- out-tile ranges for this half (derived from ngr4) ----
    const int nrounds = ngr4 >> 1;   // 1 or 2
    const int ng = nrounds * 4;      // groups per half
    const int g0 = h * ng;
    const int otO_s = (g0 * 18) >> 4;
    const int otO_e = (g0 * 18 + ng * 18 - 1) >> 4;
    const int nO = otO_e - otO_s + 1;
    const int otM_s = (288 + g0 * 9) >> 4;
    const int otM_e = (288 + g0 * 9 + ng * 9 - 1) >> 4;
    const int nM = otM_e - otM_s + 1;
    const int nt = nO + nM;          // 14 (ngr4=4) or 8 (ngr4=2)
    const int rowOffO = otO_s * 16;
    const int rowOffM = otM_s * 16 - nO * 16;

    // ---- phase 1: stage hA window (bf16-hi source, 1 load/job) ----
#pragma unroll
    for (int i = 0; i < 2; ++i) {
        int e = tid + i * 256;
        if (e < 432) {
            int rc = e >> 3, cg = e & 7;
            int r = rc / 18, col = rc - r * 18;
            int gy = y - 1 + r, gx = xb - 1 + col;
            bool ok = ((unsigned)gy < 96u) && ((unsigned)gx < 96u);
            u16x8 a;
            if (ok) {
                a = *(const u16x8*)(hAh + (gy * 96 + gx) * 64 + cg * 8);
            } else {
#pragma unroll
                for (int q = 0; q < 8; ++q) a[q] = 0;
            }
            *(u16x8*)(ldsAH + rc * 72 + cg * 8) = a;
        }
    }
    __syncthreads();

    // ---- phase 2: needed ow4 out-tiles, 1 MFMA/step, depth-5 pipeline ----
#pragma unroll 1
    for (int j = 0; j < 4; ++j) {
        const int idx = j * 4 + w;
        if (idx >= nt) break;
        const int ot = (idx < nO) ? (otO_s + idx) : (otM_s + (idx - nO));
        f32x4 a0, a1;
#pragma unroll
        for (int r = 0; r < 4; ++r) { a0[r] = 0.f; a1[r] = 0.f; }
        bf16x8 pAh[5], pBh[5];
#pragma unroll
        for (int s = 0; s < 23; ++s) {
            if (s >= 5) {  // consume BEFORE refilling the slot
                const int u = s - 5;
                const bf16x8 Ah = pAh[u % 5];
                const bf16x8 Bh = pBh[u % 5];
                if (u & 1)
                    a1 = __builtin_amdgcn_mfma_f32_16x16x32_bf16(Ah, Bh, a1, 0, 0, 0);
                else
                    a0 = __builtin_amdgcn_mfma_f32_16x16x32_bf16(Ah, Bh, a0, 0, 0, 0);
            }
            if (s < 18) {
                const int t = s >> 1, cc2 = s & 1;
                const int ky = t / 3, kx = t % 3;
                const ushort_t* ab =
                    w4 + (((size_t)s * 28 + ot) * 64 + lane) * 8;
                pAh[s % 5] = *(const bf16x8*)ab;
                const int lb = (ky * 18 + n + kx) * 72 + cc2 * 32 + quad * 8;
                pBh[s % 5] = *(const bf16x8*)(ldsAH + lb);
            }
        }
#pragma unroll
        for (int r = 0; r < 4; ++r) {
            int cout = ot * 16 + quad * 4 + r;
            float v = a0[r] + a1[r] + (cout < 432 ? ob4[cout] : 0.f);
            rawS[(idx * 16 + quad * 4 + r) * 17 + n] = v;
        }
    }

    // ---- phase 3: gather (bf16-hi, 1 load/corner) + dconv MFMA (2-term) ----
    f32x4 acc0, acc1;
#pragma unroll
    for (int r = 0; r < 4; ++r) { acc0[r] = 0.f; acc1[r] = 0.f; }

    for (int gci = 0; gci < nrounds; ++gci) {
        const int gc = h * nrounds + gci;
        __syncthreads();  // rawS ready / cols (ldsA) reuse safe
#pragma unroll
        for (int i = 0; i < 3; ++i) {
            int e = tid + i * 256;
            if (e < 576) {
                int p = e & 15;
                int r = e >> 4;  // 0..35
                int gl = r / 9, k = r - gl * 9;
                int g = gc * 4 + gl;
                float ry = rawS[(g * 18 + k * 2 + 0 - rowOffO) * 17 + p];
                float rx = rawS[(g * 18 + k * 2 + 1 - rowOffO) * 17 + p];
                float rm = rawS[(288 + g * 9 + k - rowOffM) * 17 + p];
                float oy = 5.f * (1.f - 2.f / (1.f + __expf(2.f * ry)));
                float ox = 5.f * (1.f - 2.f / (1.f + __expf(2.f * rx)));
                float m = 1.f / (1.f + __expf(-rm));
                float sy = oy + (float)(y - 1 + k / 3);
                float sx = ox + (float)(xb + p - 1 + k % 3);
                float fy0 = floorf(sy), fx0 = floorf(sx);
                float fy = sy - fy0, fx = sx - fx0;
                int y0 = (int)fy0, x0 = (int)fx0;
                int y1 = y0 + 1, x1 = x0 + 1;
                bool vy0 = (unsigned)y0 < 96u, vy1 = (unsigned)y1 < 96u;
                bool vx0 = (unsigned)x0 < 96u, vx1 = (unsigned)x1 < 96u;
                int cy0 = min(max(y0, 0), 95), cy1 = min(max(y1, 0), 95);
                int cx0 = min(max(x0, 0), 95), cx1 = min(max(x1, 0), 95);
                float w00 = (1.f - fy) * (1.f - fx) * ((vy0 && vx0) ? 1.f : 0.f);
                float w01 = (1.f - fy) * fx * ((vy0 && vx1) ? 1.f : 0.f);
                float w10 = fy * (1.f - fx) * ((vy1 && vx0) ? 1.f : 0.f);
                float w11 = fy * fx * ((vy1 && vx1) ? 1.f : 0.f);
                const ushort_t* src = (g < 8) ? sAh : sBh;
                int cb = (g & 7) * 8;
                int kbase = p * 296 + gl * 72 + k * 8;
                ushort_t hh[8], ll[8];
                if (src) {
                    u16x8 c00 = *(const u16x8*)(src + (cy0 * 96 + cx0) * 64 + cb);
                    u16x8 c01 = *(const u16x8*)(src + (cy0 * 96 + cx1) * 64 + cb);
                    u16x8 c10 = *(const u16x8*)(src + (cy1 * 96 + cx0) * 64 + cb);
                    u16x8 c11 = *(const u16x8*)(src + (cy1 * 96 + cx1) * 64 + cb);
#pragma unroll
                    for (int c = 0; c < 8; ++c) {
                        float v = w00 * bfh(c00[c]) + w01 * bfh(c01[c]) +
                                  w10 * bfh(c10[c]) + w11 * bfh(c11[c]);
                        split16(v * m, hh[c], ll[c]);
                    }
                } else {
#pragma unroll
                    for (int c = 0; c < 8; ++c) { hh[c] = 0; ll[c] = 0; }
                }
                u32x4 H, L;
#pragma unroll
                for (int q = 0; q < 4; ++q) {
                    H[q] = (unsigned)hh[2 * q] | ((unsigned)hh[2 * q + 1] << 16);
                    L[q] = (unsigned)ll[2 * q] | ((unsigned)ll[2 * q + 1] << 16);
                }
                *(u32x4*)(colsH + kbase) = H;
                *(u32x4*)(colsL + kbase) = L;
            }
        }
        __syncthreads();
        bf16x8 qAh[4], qBh[4], qBl[4];
#pragma unroll
        for (int s = 0; s < 13; ++s) {
            if (s >= 4) {  // consume BEFORE refilling the slot
                const int u = s - 4;
                const bf16x8 Ah = qAh[u % 4];
                const bf16x8 Bh = qBh[u % 4], Bl = qBl[u % 4];
                if (u & 1) {
                    acc1 = __builtin_amdgcn_mfma_f32_16x16x32_bf16(Ah, Bh, acc1, 0, 0, 0);
                    acc1 = __builtin_amdgcn_mfma_f32_16x16x32_bf16(Ah, Bl, acc1, 0, 0, 0);
                } else {
                    acc0 = __builtin_amdgcn_mfma_f32_16x16x32_bf16(Ah, Bh, acc0, 0, 0, 0);
                    acc0 = __builtin_amdgcn_mfma_f32_16x16x32_bf16(Ah, Bl, acc0, 0, 0, 0);
                }
            }
            if (s < 9) {
                const int cc = gc * 9 + s;
                const ushort_t* ab = dwf + (((size_t)cc * 4 + w) * 64 + lane) * 8;
                qAh[s % 4] = *(const bf16x8*)ab;
                const int lb = n * 296 + s * 32 + quad * 8;
                qBh[s % 4] = *(const bf16x8*)(colsH + lb);
                qBl[s % 4] = *(const bf16x8*)(colsL + lb);
            }
        }
    }

    const int pidx = y * 96 + xb + n;
    f32x4 sv;
#pragma unroll
    for (int r = 0; r < 4; ++r) sv[r] = acc0[r] + acc1[r];
    *(f32x4*)(pacc + (size_t)h * FRAME + (size_t)pidx * 64 + w * 16 +
              quad * 4) = sv;
}

// ---------------------------------------------------------------------------
// MFMA fusion: 1x1 conv over [featB[t], featF[t]] (K=128) + bias + x.
// ---------------------------------------------------------------------------
__global__ __launch_bounds__(128) void fusem_k(
    const unsigned* __restrict__ featB, const unsigned* __restrict__ featF,
    const float* __restrict__ x, const ushort_t* __restrict__ wfrag,
    const float* __restrict__ bias, float* __restrict__ out) {
    const int tid = threadIdx.x;
    const int lane = tid & 63;
    const int w = tid >> 6;
    const int h = blockIdx.x & 1;
    const int bseg = blockIdx.x >> 1;
    const int t = blockIdx.y;
    const int ot = h * 2 + w;
    const int xb = (bseg % 6) * 16;
    const int y = bseg / 6;
    const int n = lane & 15;
    const int quad = lane >> 4;

    __shared__ __align__(16) ushort_t ldsH[16 * 144];
    __shared__ __align__(16) ushort_t ldsL[16 * 144];

    const int p = tid >> 3, cg = tid & 7;
    const int off = ((y * 96 + xb + p) * 64 + cg * 8);
#pragma unroll
    for (int i = 0; i < 2; ++i) {  // i=0: featB (ch 0-63), i=1: featF (64-127)
        const unsigned* sv =
            (i == 0 ? featB : featF) + (size_t)t * FRAME;
        u32x4 a = *(const u32x4*)(sv + off);
        u32x4 b = *(const u32x4*)(sv + off + 4);
        u32x4 H, L;
#pragma unroll
        for (int q = 0; q < 2; ++q) {
            H[q] = (a[2 * q] >> 16) | (a[2 * q + 1] & 0xFFFF0000u);
            L[q] = (a[2 * q] & 0xFFFFu) | (a[2 * q + 1] << 16);
            H[2 + q] = (b[2 * q] >> 16) | (b[2 * q + 1] & 0xFFFF0000u);
            L[2 + q] = (b[2 * q] & 0xFFFFu) | (b[2 * q + 1] << 16);
        }
        *(u32x4*)(ldsH + p * 144 + i * 64 + cg * 8) = H;
        *(u32x4*)(ldsL + p * 144 + i * 64 + cg * 8) = L;
    }
    __syncthreads();

    f32x4 acc0, acc1;
#pragma unroll
    for (int r = 0; r < 4; ++r) { acc0[r] = 0.f; acc1[r] = 0.f; }
    const size_t hlOff = (size_t)4 * 4 * 512;
#pragma unroll
    for (int cc = 0; cc < 4; ++cc) {
        const ushort_t* ab = wfrag + (((size_t)cc * 4 + ot) * 64 + lane) * 8;
        bf16x8 Ah = *(const bf16x8*)ab;
        bf16x8 Al = *(const bf16x8*)(ab + hlOff);
        int lb = n * 144 + cc * 32 + quad * 8;
        bf16x8 Bh = *(const bf16x8*)(ldsH + lb);
        bf16x8 Bl = *(const bf16x8*)(ldsL + lb);
        if (cc & 1) {
            acc1 = __builtin_amdgcn_mfma_f32_16x16x32_bf16(Ah, Bh, acc1, 0, 0, 0);
            acc1 = __builtin_amdgcn_mfma_f32_16x16x32_bf16(Al, Bh, acc1, 0, 0, 0);
            acc1 = __builtin_amdgcn_mfma_f32_16x16x32_bf16(Ah, Bl, acc1, 0, 0, 0);
        } else {
            acc0 = __builtin_amdgcn_mfma_f32_16x16x32_bf16(Ah, Bh, acc0, 0, 0, 0);
            acc0 = __builtin_amdgcn_mfma_f32_16x16x32_bf16(Al, Bh, acc0, 0, 0, 0);
            acc0 = __builtin_amdgcn_mfma_f32_16x16x32_bf16(Ah, Bl, acc0, 0, 0, 0);
        }
    }

    const int pidx = y * 96 + xb + n;
    const float* xt = x + (size_t)t * FRAME;
    float* od = out + (size_t)t * FRAME;
#pragma unroll
    for (int r = 0; r < 4; ++r) {
        int cout = ot * 16 + quad * 4 + r;
        size_t o2 = (size_t)cout * HW96 + pidx;
        od[o2] = acc0[r] + acc1[r] + bias[cout] + xt[o2];
    }
}

// ---------------------------------------------------------------------------
extern "C" void kernel_launch(void* const* d_in, const int* in_sizes, int n_in,
                              void* d_out, int out_size, void* d_ws,
                              size_t ws_size, hipStream_t stream) {
    const float* x = (const float*)d_in[0];
    auto gp = [&](int i) { return (const float*)d_in[i]; };

    struct DirP {
        const float *dw, *db, *ow1, *ob1, *ow2, *ob2, *ow3, *ob3, *ow4, *ob4,
            *bw1, *bb1, *bw2, *bb2;
    };
    DirP Pb{gp(1), gp(2), gp(3), gp(4), gp(5), gp(6), gp(7),
            gp(8), gp(9), gp(10), gp(11), gp(12), gp(13), gp(14)};
    DirP Pf{gp(15), gp(16), gp(17), gp(18), gp(19), gp(20), gp(21),
            gp(22), gp(23), gp(24), gp(25), gp(26), gp(27), gp(28)};
    const float* fus_w = gp(29);
    const float* fus_b = gp(30);

    // ---- workspace carve-up (4-byte units); all feature bufs interleaved ----
    unsigned* featBpk = (unsigned*)d_ws;
    unsigned* featFpk = featBpk + (size_t)8 * FRAME;
    unsigned* xpk = featFpk + (size_t)8 * FRAME;
    unsigned* hApk = xpk + (size_t)8 * FRAME;         // ow chain (hi ushort)
    unsigned* hBpk = hApk + FRAME;
    ushort_t* fragp = (ushort_t*)(hBpk + FRAME);

    auto falloc = [&](size_t nelem) {
        ushort_t* p = fragp;
        fragp += nelem;
        return p;
    };

    struct DirW { ushort_t *ow1, *ow2, *ow3, *ow4, *bw1, *bw2, *dw; int bw1KC; };
    FragJobs fj;
    int nf = 0;
    auto fjob = [&](const float* src, int O, int I, int OT, int KC) {
        ushort_t* dst = falloc((size_t)2 * 9 * KC * OT * 512);
        fj.j[nf++] = FragJob{src, dst, O, I, OT, KC, 0};
        return dst;
    };
    auto fjobd = [&](const float* src) {
        ushort_t* dst = falloc((size_t)2 * 36 * 4 * 512);
        fj.j[nf++] = FragJob{src, dst, 64, 128, 4, 36, 1};
        return dst;
    };
    DirW Wb, Wf;
    Wb.ow1 = fjob(Pb.ow1, 64, 192, 4, 6);
    Wb.ow2 = fjob(Pb.ow2, 64, 64, 4, 2);
    Wb.ow3 = fjob(Pb.ow3, 64, 64, 4, 2);
    Wb.ow4 = fjob(Pb.ow4, 432, 64, 28, 2);
    Wb.bw1 = fjob(Pb.bw1, 64, 128, 4, 4);
    Wb.bw1KC = 4;
    Wb.bw2 = fjob(Pb.bw2, 64, 64, 4, 2);
    Wb.dw = fjobd(Pb.dw);
    Wf.ow1 = fjob(Pf.ow1, 64, 192, 4, 6);
    Wf.ow2 = fjob(Pf.ow2, 64, 64, 4, 2);
    Wf.ow3 = fjob(Pf.ow3, 64, 64, 4, 2);
    Wf.ow4 = fjob(Pf.ow4, 432, 64, 28, 2);
    Wf.bw1 = fjob(Pf.bw1, 64, 192, 4, 6);
    Wf.bw1KC = 6;
    Wf.bw2 = fjob(Pf.bw2, 64, 64, 4, 2);
    Wf.dw = fjobd(Pf.dw);
    // fusion 1x1 weights (mode 2): O=64, I=128, OT=4, KC=4
    ushort_t* Wfus = falloc((size_t)2 * 4 * 4 * 512);
    fj.j[nf++] = FragJob{fus_w, Wfus, 64, 128, 4, 4, 2};
    frag_all_k<<<dim3(1008, 15), 256, 0, stream>>>(fj);

    // after frags: pacc (2F f32 interleaved), feat hi shadows, x hi shadow
    float* pacc = (float*)((((uintptr_t)fragp) + 15) & ~(uintptr_t)15);
    ushort_t* featBh = (ushort_t*)(pacc + (size_t)2 * FRAME);
    ushort_t* featFh = featBh + (size_t)8 * FRAME;
    ushort_t* xh = featFh + (size_t)8 * FRAME;
    ushort_t* hAh = (ushort_t*)hApk;
    ushort_t* hBh = (ushort_t*)hBpk;

    pack_tr_k<<<dim3(144, 8), 256, 0, stream>>>(x, xpk, xh);

    auto convm = [&](const unsigned* a, const unsigned* b, int withD,
                     const float* ddbias, const ushort_t* frag, int KCfull,
                     const float* bias, const float* add, const float* add2,
                     const float* abias, ushort_t* outhi, unsigned* out,
                     int act, int terms) {
        const unsigned* S[2] = {nullptr, nullptr};
        int ns = 0;
        if (a) S[ns++] = a;
        if (b) S[ns++] = b;
        int dslot = -1;
        if (withD) { dslot = ns; ++ns; }
        if (terms == 2)
            convm_k<2><<<1152, 128, 0, stream>>>(
                S[0], S[1], ns, dslot, pacc, ddbias, frag, KCfull, bias, add,
                add2, abias, outhi, out, act);
        else
            convm_k<3><<<1152, 128, 0, stream>>>(
                S[0], S[1], ns, dslot, pacc, ddbias, frag, KCfull, bias, add,
                add2, abias, outhi, out, act);
    };

    auto convh = [&](const ushort_t* a, const ushort_t* b, const ushort_t* c2,
                     const ushort_t* frag, int KCfull, const float* bias,
                     ushort_t* out, int act) {
        const ushort_t* srcs[3] = {a, b, c2};
        const ushort_t* S[3] = {nullptr, nullptr, nullptr};
        int B[3] = {0, 0, 0};
        int ns = 0;
        for (int j = 0; j < 3; ++j)
            if (srcs[j]) {
                S[ns] = srcs[j];
                B[ns] = j * 2;
                ++ns;
            }
        convh_k<<<1152, 128, 0, stream>>>(S[0], S[1], S[2], B[0], B[1], B[2],
                                          ns, frag, KCfull, bias, out, act);
    };

    for (int dir = 0; dir < 2; ++dir) {  // 0 = backward, 1 = forward
        const DirP& P = dir ? Pf : Pb;
        const DirW& W = dir ? Wf : Wb;
        unsigned* feat = dir ? featFpk : featBpk;
        ushort_t* feath = dir ? featFh : featBh;
        const unsigned* prev1 = nullptr;
        const ushort_t* prev1h = nullptr;
        const ushort_t* prev2h = nullptr;
        for (int i = 0; i < 8; ++i) {
            int idx = dir ? i : 7 - i;
            const unsigned* cur = xpk + (size_t)idx * FRAME;
            const ushort_t* curh = xh + (size_t)idx * FRAME;
            bool hasD = false;
            if (i > 0) {
                // offset/mask path: pure bf16-hi (convh)
                convh(prev1h, curh, prev2h, W.ow1, 6, P.ob1, hAh, 1);
                convh(hAh, nullptr, nullptr, W.ow2, 2, P.ob2, hBh, 1);
                convh(hBh, nullptr, nullptr, W.ow3, 2, P.ob3, hAh, 1);
                int ngr4 = (prev2h != nullptr) ? 4 : 2;
                dconv_fused_k<<<1152, 256, 0, stream>>>(
                    prev1h, prev2h, hAh, W.ow4, P.ob4, W.dw, ngr4, pacc);
                hasD = true;
            }
            unsigned* dst = feat + (size_t)idx * FRAME;
            ushort_t* dsth = feath + (size_t)idx * FRAME;
            // bw1: 2-term, D staged from interleaved pacc (dcomb retired)
            if (dir == 0) {
                convm(cur, nullptr, hasD ? 1 : 0, P.db, W.bw1, W.bw1KC, P.bb1,
                      nullptr, nullptr, nullptr, nullptr, hBpk, 1, 2);
            } else {
                convm(cur, featBpk + (size_t)idx * FRAME, hasD ? 1 : 0, P.db,
                      W.bw1, W.bw1KC, P.bb1, nullptr, nullptr, nullptr,
                      nullptr, hBpk, 1, 2);
            }
            // bw2: 2-term + interleaved pacc addsrc + hi shadow write
            convm(hBpk, nullptr, 0, nullptr, W.bw2, 2, P.bb2,
                  hasD ? pacc : nullptr, pacc + FRAME, P.db, dsth, dst, 0, 2);
            prev1 = dst;
            prev2h = prev1h;
            prev1h = dsth;
        }
        (void)prev1;
    }

    fusem_k<<<dim3(1152, 8), 128, 0, stream>>>(featBpk, featFpk, x, Wfus,
                                               fus_b, (float*)d_out);
}

// Round 13
// 1152.655 us; speedup vs baseline: 1.5587x; 1.0762x over previous
//
#include <hip/hip_runtime.h>
#include <cstddef>
#include <cstdint>

#define HW96 9216
#define FRAME (64 * 9216)

typedef unsigned short ushort_t;
typedef __attribute__((ext_vector_type(8))) short bf16x8;
typedef __attribute__((ext_vector_type(4))) float f32x4;
typedef __attribute__((ext_vector_type(4))) unsigned u32x4;
typedef __attribute__((ext_vector_type(8))) ushort_t u16x8;
typedef __attribute__((ext_vector_type(4))) ushort_t u16x4;

// packed u32 = (bf16 hi bits << 16) | bf16 lo bits; value = hi + lo exactly
__device__ __forceinline__ float unpk(unsigned p) {
    return __uint_as_float(p & 0xFFFF0000u) + __uint_as_float(p << 16);
}
__device__ __forceinline__ unsigned pk(float v) {
    unsigned u = __float_as_uint(v);
    unsigned hi = u & 0xFFFF0000u;
    float rem = v - __uint_as_float(hi);
    unsigned r = __float_as_uint(rem);
    unsigned lo = (r + 0x7FFFu + ((r >> 16) & 1u)) >> 16;
    return hi | (lo & 0xFFFFu);
}
__device__ __forceinline__ void split16(float v, ushort_t& h, ushort_t& l) {
    unsigned u = __float_as_uint(v);
    h = (ushort_t)(u >> 16);
    float rem = v - __uint_as_float(u & 0xFFFF0000u);
    unsigned r = __float_as_uint(rem);
    l = (ushort_t)((r + 0x7FFFu + ((r >> 16) & 1u)) >> 16);
}
__device__ __forceinline__ ushort_t bf16rnd(float v) {
    unsigned u = __float_as_uint(v);
    return (ushort_t)((u + 0x7FFFu + ((u >> 16) & 1u)) >> 16);
}
__device__ __forceinline__ float bfh(ushort_t h) {
    return __uint_as_float(((unsigned)h) << 16);
}

// ---------------------------------------------------------------------------
// MFMA A-fragment prepack (16x16x32) with bf16 hi/lo split.
// mode 0 (3x3 conv): layout [hl][t][cc][ot][lane][j]; K = cin chunks of 32.
// mode 1 (dconv):    layout [hl][cc][ot][lane][j]; K = g*72 + tap*8 + c.
// mode 2 (1x1 conv): layout [hl][cc][ot][lane][j]; K = cin chunks of 32.
// ---------------------------------------------------------------------------
struct FragJob { const float* src; ushort_t* dst; int O, I, OT, KC, mode; };
struct FragJobs { FragJob j[15]; };

__global__ __launch_bounds__(256) void frag_all_k(FragJobs jobs) {
    const FragJob& J = jobs.j[blockIdx.y];
    int idx = blockIdx.x * 256 + threadIdx.x;
    int total = ((J.mode == 0) ? 9 : 1) * J.KC * J.OT * 512;
    if (idx >= total) return;
    int jj = idx & 7;
    int lane = (idx >> 3) & 63;
    int rem = idx >> 9;
    int ot = rem % J.OT;
    rem /= J.OT;
    int cc = rem % J.KC;
    int t = rem / J.KC;
    int o = ot * 16 + (lane & 15);
    float wv = 0.f;
    if (J.mode == 0) {
        int ci = cc * 32 + (lane >> 4) * 8 + jj;
        if (o < J.O && ci < J.I) wv = J.src[(o * J.I + ci) * 9 + t];
    } else if (J.mode == 1) {
        int K = cc * 32 + (lane >> 4) * 8 + jj;
        int g = K / 72, r2 = K % 72;
        int tap = r2 >> 3, c = r2 & 7;
        int ci = g * 8 + c;
        if (o < J.O && ci < J.I) wv = J.src[(o * J.I + ci) * 9 + tap];
    } else {  // mode 2: 1x1
        int ci = cc * 32 + (lane >> 4) * 8 + jj;
        if (o < J.O && ci < J.I) wv = J.src[o * J.I + ci];
    }
    ushort_t h, l;
    split16(wv, h, l);
    J.dst[idx] = h;
    J.dst[total + idx] = l;
}

// ---------------------------------------------------------------------------
// Transposing pack: planar fp32 -> interleaved packed u32 + bf16-hi shadow.
// ---------------------------------------------------------------------------
__global__ __launch_bounds__(256) void pack_tr_k(const float* __restrict__ src,
                                                 unsigned* __restrict__ dst,
                                                 ushort_t* __restrict__ dsth) {
    const int t = blockIdx.y;
    const int px0 = blockIdx.x * 64;
    __shared__ unsigned tile[64 * 65];
    const float* s = src + (size_t)t * FRAME;
    unsigned* d = dst + (size_t)t * FRAME;
    ushort_t* dh = dsth + (size_t)t * FRAME;
#pragma unroll
    for (int it = 0; it < 16; ++it) {
        int e = it * 256 + threadIdx.x;
        int p = e & 63, ch = e >> 6;
        tile[ch * 65 + p] = pk(s[(size_t)ch * HW96 + px0 + p]);
    }
    __syncthreads();
#pragma unroll
    for (int it = 0; it < 16; ++it) {
        int e = it * 256 + threadIdx.x;
        int ch = e & 63, p = e >> 6;
        unsigned v = tile[ch * 65 + p];
        d[(size_t)(px0 + p) * 64 + ch] = v;
        dh[(size_t)(px0 + p) * 64 + ch] = (ushort_t)(v >> 16);
    }
}

// ---------------------------------------------------------------------------
// MFMA implicit-GEMM 3x3 conv, 16x16x32 bf16 (feature path: bw1/bw2).
// TERMS=2: AhBh + AhBl (weight-lo dropped; both bw1 and bw2).
// Sources are prefix-packed; base K-offset for source j is j*2.
// dslot >= 0: source at that slot is the dconv result, staged directly from
// INTERLEAVED pacc pair (pacc0+pacc1+dbias -> hi/lo split).
// bw2 addsrc: v += pacc0[px][c] + pacc1[px][c] + abias[c] (vector loads).
// outhi: optional bf16-hi interleaved shadow write (gather source frames).
// ---------------------------------------------------------------------------
template <int TERMS>
__global__ __launch_bounds__(128, 3) void convm_k(
    const unsigned* __restrict__ s0, const unsigned* __restrict__ s1,
    int nsrc, int dslot, const float* __restrict__ dpacc,
    const float* __restrict__ ddbias, const ushort_t* __restrict__ wfrag,
    int KCfull, const float* __restrict__ bias,
    const float* __restrict__ addsrc, const float* __restrict__ addsrc2,
    const float* __restrict__ abias, ushort_t* __restrict__ outhi,
    unsigned* __restrict__ outpk, int act) {
    const int tid = threadIdx.x;
    const int lane = tid & 63;
    const int w = tid >> 6;              // 0..1
    const int h = blockIdx.x & 1;       // cout half
    const int bseg = blockIdx.x >> 1;   // px segment
    const int ot = h * 2 + w;           // global out-tile 0..3
    const int xb = (bseg % 6) * 16;
    const int y = bseg / 6;
    const int n = lane & 15;
    const int quad = lane >> 4;

    __shared__ __align__(16) ushort_t ldsH[3 * 18 * 72];
    __shared__ __align__(16) ushort_t ldsL[3 * 18 * 72];

    // staging job decode (loop-invariant): 432 jobs = 54 (r,c) x 8 octets
    int jst[4], jok[4], joff[4], jbase[4];
#pragma unroll
    for (int i = 0; i < 4; ++i) {
        int e = tid + i * 128;
        int rc = e >> 3, cg = e & 7;
        int r = rc / 18, col = rc - r * 18;
        int gy = y - 1 + r, gx = xb - 1 + col;
        jst[i] = (e < 432);
        jok[i] = jst[i] && ((unsigned)gy < 96u) && ((unsigned)gx < 96u);
        joff[i] = (gy * 96 + gx) * 64 + cg * 8;
        jbase[i] = rc * 72 + cg * 8;
    }

    f32x4 acc0, acc1;
#pragma unroll
    for (int r = 0; r < 4; ++r) { acc0[r] = 0.f; acc1[r] = 0.f; }

    const size_t hlOff = (size_t)9 * KCfull * 4 * 512;

    for (int j = 0; j < nsrc; ++j) {
        const int base = j * 2;
        __syncthreads();
        if (j == dslot) {
            // stage D = pacc0 + pacc1 + dbias (interleaved f32 pair)
#pragma unroll
            for (int i = 0; i < 4; ++i) {
                if (jst[i]) {
                    ushort_t hh[8], ll[8];
                    if (jok[i]) {
                        const int cg8 = ((tid + i * 128) & 7) << 3;
                        f32x4 a0 = *(const f32x4*)(dpacc + joff[i]);
                        f32x4 a1 = *(const f32x4*)(dpacc + joff[i] + 4);
                        f32x4 b0 = *(const f32x4*)(dpacc + FRAME + joff[i]);
                        f32x4 b1 = *(const f32x4*)(dpacc + FRAME + joff[i] + 4);
                        f32x4 d0 = *(const f32x4*)(ddbias + cg8);
                        f32x4 d1 = *(const f32x4*)(ddbias + cg8 + 4);
#pragma unroll
                        for (int q = 0; q < 4; ++q) {
                            split16(a0[q] + b0[q] + d0[q], hh[q], ll[q]);
                            split16(a1[q] + b1[q] + d1[q], hh[4 + q], ll[4 + q]);
                        }
                    } else {
#pragma unroll
                        for (int q = 0; q < 8; ++q) { hh[q] = 0; ll[q] = 0; }
                    }
                    u32x4 H, L;
#pragma unroll
                    for (int q = 0; q < 4; ++q) {
                        H[q] = (unsigned)hh[2 * q] | ((unsigned)hh[2 * q + 1] << 16);
                        L[q] = (unsigned)ll[2 * q] | ((unsigned)ll[2 * q + 1] << 16);
                    }
                    *(u32x4*)(ldsH + jbase[i]) = H;
                    *(u32x4*)(ldsL + jbase[i]) = L;
                }
            }
        } else {
            const unsigned* sv = (j == 0) ? s0 : s1;
#pragma unroll
            for (int i = 0; i < 4; ++i) {
                if (jst[i]) {
                    u32x4 a, b;
                    if (jok[i]) {
                        a = *(const u32x4*)(sv + joff[i]);
                        b = *(const u32x4*)(sv + joff[i] + 4);
                    } else {
#pragma unroll
                        for (int q = 0; q < 4; ++q) { a[q] = 0; b[q] = 0; }
                    }
                    u32x4 H, L;
#pragma unroll
                    for (int q = 0; q < 2; ++q) {
                        H[q] = (a[2 * q] >> 16) | (a[2 * q + 1] & 0xFFFF0000u);
                        L[q] = (a[2 * q] & 0xFFFFu) | (a[2 * q + 1] << 16);
                        H[2 + q] = (b[2 * q] >> 16) | (b[2 * q + 1] & 0xFFFF0000u);
                        L[2 + q] = (b[2 * q] & 0xFFFFu) | (b[2 * q + 1] << 16);
                    }
                    *(u32x4*)(ldsH + jbase[i]) = H;
                    *(u32x4*)(ldsL + jbase[i]) = L;
                }
            }
        }
        __syncthreads();
        // depth-5 rolling pipeline over 18 steps (t = s>>1, cc2 = s&1)
        bf16x8 pAh[5], pAl[5], pBh[5], pBl[5];
#pragma unroll
        for (int s = 0; s < 23; ++s) {
            if (s >= 5) {  // consume BEFORE refilling the slot
                const int u = s - 5;
                const bf16x8 Ah = pAh[u % 5];
                const bf16x8 Bh = pBh[u % 5], Bl = pBl[u % 5];
                if (u & 1) {
                    acc1 = __builtin_amdgcn_mfma_f32_16x16x32_bf16(Ah, Bh, acc1, 0, 0, 0);
                    if (TERMS == 3)
                        acc1 = __builtin_amdgcn_mfma_f32_16x16x32_bf16(pAl[u % 5], Bh, acc1, 0, 0, 0);
                    acc1 = __builtin_amdgcn_mfma_f32_16x16x32_bf16(Ah, Bl, acc1, 0, 0, 0);
                } else {
                    acc0 = __builtin_amdgcn_mfma_f32_16x16x32_bf16(Ah, Bh, acc0, 0, 0, 0);
                    if (TERMS == 3)
                        acc0 = __builtin_amdgcn_mfma_f32_16x16x32_bf16(pAl[u % 5], Bh, acc0, 0, 0, 0);
                    acc0 = __builtin_amdgcn_mfma_f32_16x16x32_bf16(Ah, Bl, acc0, 0, 0, 0);
                }
            }
            if (s < 18) {
                const int t = s >> 1, cc2 = s & 1;
                const int ky = t / 3, kx = t % 3;
                const int ccor = base + cc2;
                const ushort_t* ab =
                    wfrag + (((size_t)(t * KCfull + ccor) * 4 + ot) * 64 + lane) * 8;
                pAh[s % 5] = *(const bf16x8*)ab;
                if (TERMS == 3) pAl[s % 5] = *(const bf16x8*)(ab + hlOff);
                const int lb = (ky * 18 + n + kx) * 72 + cc2 * 32 + quad * 8;
                pBh[s % 5] = *(const bf16x8*)(ldsH + lb);
                pBl[s % 5] = *(const bf16x8*)(ldsL + lb);
            }
        }
    }

    const int px = y * 96 + xb + n;
    f32x4 pa, pb;
#pragma unroll
    for (int r = 0; r < 4; ++r) { pa[r] = 0.f; pb[r] = 0.f; }
    if (addsrc) {
        pa = *(const f32x4*)(addsrc + (size_t)px * 64 + ot * 16 + quad * 4);
        pb = *(const f32x4*)(addsrc2 + (size_t)px * 64 + ot * 16 + quad * 4);
    }
    u16x4 hi4;
#pragma unroll
    for (int r = 0; r < 4; ++r) {
        int cout = ot * 16 + quad * 4 + r;
        float v = acc0[r] + acc1[r] + bias[cout];
        if (act) v = (v >= 0.f) ? v : 0.1f * v;
        if (addsrc) v += pa[r] + pb[r] + abias[cout];
        outpk[(size_t)px * 64 + cout] = pk(v);
        hi4[r] = bf16rnd(v);
    }
    if (outhi)
        *(u16x4*)(outhi + (size_t)px * 64 + ot * 16 + quad * 4) = hi4;
}

// ---------------------------------------------------------------------------
// Hi-only bf16 MFMA 3x3 conv (offset/mask path: ow1/ow2/ow3).
// Sources are bf16-hi interleaved ushort[px][64]; staging = 1 u16x8 per job;
// LDS is H-only (7.8 KB); 1 MFMA per K-step (AhBh); bf16-hi ushort output.
// ---------------------------------------------------------------------------
__global__ __launch_bounds__(128, 3) void convh_k(
    const ushort_t* __restrict__ s0, const ushort_t* __restrict__ s1,
    const ushort_t* __restrict__ s2, int b0, int b1, int b2, int nsrc,
    const ushort_t* __restrict__ wfrag, int KCfull,
    const float* __restrict__ bias, ushort_t* __restrict__ outhi, int act) {
    const int tid = threadIdx.x;
    const int lane = tid & 63;
    const int w = tid >> 6;
    const int h = blockIdx.x & 1;
    const int bseg = blockIdx.x >> 1;
    const int ot = h * 2 + w;
    const int xb = (bseg % 6) * 16;
    const int y = bseg / 6;
    const int n = lane & 15;
    const int quad = lane >> 4;

    __shared__ __align__(16) ushort_t ldsH[3 * 18 * 72];

    int jst[4], jok[4], joff[4], jbase[4];
#pragma unroll
    for (int i = 0; i < 4; ++i) {
        int e = tid + i * 128;
        int rc = e >> 3, cg = e & 7;
        int r = rc / 18, col = rc - r * 18;
        int gy = y - 1 + r, gx = xb - 1 + col;
        jst[i] = (e < 432);
        jok[i] = jst[i] && ((unsigned)gy < 96u) && ((unsigned)gx < 96u);
        joff[i] = (gy * 96 + gx) * 64 + cg * 8;
        jbase[i] = rc * 72 + cg * 8;
    }

    f32x4 acc0, acc1;
#pragma unroll
    for (int r = 0; r < 4; ++r) { acc0[r] = 0.f; acc1[r] = 0.f; }

    for (int j = 0; j < nsrc; ++j) {
        const ushort_t* sv = (j == 0) ? s0 : (j == 1 ? s1 : s2);
        const int base = (j == 0) ? b0 : (j == 1 ? b1 : b2);
        __syncthreads();
#pragma unroll
        for (int i = 0; i < 4; ++i) {
            if (jst[i]) {
                u16x8 a;
                if (jok[i]) {
                    a = *(const u16x8*)(sv + joff[i]);
                } else {
#pragma unroll
                    for (int q = 0; q < 8; ++q) a[q] = 0;
                }
                *(u16x8*)(ldsH + jbase[i]) = a;
            }
        }
        __syncthreads();
        // depth-5 rolling pipeline over 18 steps, 1 MFMA each
        bf16x8 pAh[5], pBh[5];
#pragma unroll
        for (int s = 0; s < 23; ++s) {
            if (s >= 5) {  // consume BEFORE refilling the slot
                const int u = s - 5;
                const bf16x8 Ah = pAh[u % 5];
                const bf16x8 Bh = pBh[u % 5];
                if (u & 1)
                    acc1 = __builtin_amdgcn_mfma_f32_16x16x32_bf16(Ah, Bh, acc1, 0, 0, 0);
                else
                    acc0 = __builtin_amdgcn_mfma_f32_16x16x32_bf16(Ah, Bh, acc0, 0, 0, 0);
            }
            if (s < 18) {
                const int t = s >> 1, cc2 = s & 1;
                const int ky = t / 3, kx = t % 3;
                const int ccor = base + cc2;
                const ushort_t* ab =
                    wfrag + (((size_t)(t * KCfull + ccor) * 4 + ot) * 64 + lane) * 8;
                pAh[s % 5] = *(const bf16x8*)ab;
                const int lb = (ky * 18 + n + kx) * 72 + cc2 * 32 + quad * 8;
                pBh[s % 5] = *(const bf16x8*)(ldsH + lb);
            }
        }
    }

    const int px = y * 96 + xb + n;
    u16x4 hi4;
#pragma unroll
    for (int r = 0; r < 4; ++r) {
        int cout = ot * 16 + quad * 4 + r;
        float v = acc0[r] + acc1[r] + bias[cout];
        if (act) v = (v >= 0.f) ? v : 0.1f * v;
        hi4[r] = bf16rnd(v);
    }
    *(u16x4*)(outhi + (size_t)px * 64 + ot * 16 + quad * 4) = hi4;
}

// ---------------------------------------------------------------------------
// Fused ow4 + modulated deformable conv, HALF-SPLIT: grid 1152 = 576 seg x 2.
// hA input bf16-hi. Gather reads bf16-hi shadow feats; cols now SINGLE bf16
// (cols-lo dropped): 1 MFMA per K-step in phase 3, H-only cols LDS (24.7 KB
// total). pacc INTERLEAVED [h][px][64] f32.
// ---------------------------------------------------------------------------
__global__ __launch_bounds__(256) void dconv_fused_k(
    const ushort_t* __restrict__ sAh, const ushort_t* __restrict__ sBh,
    const ushort_t* __restrict__ hAh, const ushort_t* __restrict__ w4,
    const float* __restrict__ ob4, const ushort_t* __restrict__ dwf,
    int ngr4, float* __restrict__ pacc) {
    const int tid = threadIdx.x;
    const int lane = tid & 63;
    const int w = tid >> 6;
    const int h = blockIdx.x & 1;
    const int seg = blockIdx.x >> 1;
    const int xb = (seg % 6) * 16;
    const int y = seg / 6;
    const int n = lane & 15;
    const int quad = lane >> 4;

    __shared__ __align__(16) char smem[15232 + 9472];
    float* rawS = (float*)smem;               // up to [224][17] fp32
    ushort_t* ldsAH = (ushort_t*)(smem + 15232);  // 3888 ushorts (H-only)
    ushort_t* colsH = (ushort_t*)(smem + 15232);  // union with ldsA (4736 us)

    // ---- out-tile ranges for this half (derived from ngr4) ----
    const int nrounds = ngr4 >> 1;   // 1 or 2
    const int ng = nrounds * 4;      // groups per half
    const int g0 = h * ng;
    const int otO_s = (g0 * 18) >> 4;
    const int otO_e = (g0 * 18 + ng * 18 - 1) >> 4;
    const int nO = otO_e - otO_s + 1;
    const int otM_s = (288 + g0 * 9) >> 4;
    const int otM_e = (288 + g0 * 9 + ng * 9 - 1) >> 4;
    const int nM = otM_e - otM_s + 1;
    const int nt = nO + nM;          // 14 (ngr4=4) or 8 (ngr4=2)
    const int rowOffO = otO_s * 16;
    const int rowOffM = otM_s * 16 - nO * 16;

    // ---- phase 1: stage hA window (bf16-hi source, 1 load/job) ----
#pragma unroll
    for (int i = 0; i < 2; ++i) {
        int e = tid + i * 256;
        if (e < 432) {
            int rc = e >> 3, cg = e & 7;
            int r = rc / 18, col = rc - r * 18;
            int gy = y - 1 + r, gx = xb - 1 + col;
            bool ok = ((unsigned)gy < 96u) && ((unsigned)gx < 96u);
            u16x8 a;
            if (ok) {
                a = *(const u16x8*)(hAh + (gy * 96 + gx) * 64 + cg * 8);
            } else {
#pragma unroll
                for (int q = 0; q < 8; ++q) a[q] = 0;
            }
            *(u16x8*)(ldsAH + rc * 72 + cg * 8) = a;
        }
    }
    __syncthreads();

    // ---- phase 2: needed ow4 out-tiles, 1 MFMA/step, depth-5 pipeline ----
#pragma unroll 1
    for (int j = 0; j < 4; ++j) {
        const int idx = j * 4 + w;
        if (idx >= nt) break;
        const int ot = (idx < nO) ? (otO_s + idx) : (otM_s + (idx - nO));
        f32x4 a0, a1;
#pragma unroll
        for (int r = 0; r < 4; ++r) { a0[r] = 0.f; a1[r] = 0.f; }
        bf16x8 pAh[5], pBh[5];
#pragma unroll
        for (int s = 0; s < 23; ++s) {
            if (s >= 5) {  // consume BEFORE refilling the slot
                const int u = s - 5;
                const bf16x8 Ah = pAh[u % 5];
                const bf16x8 Bh = pBh[u % 5];
                if (u & 1)
                    a1 = __builtin_amdgcn_mfma_f32_16x16x32_bf16(Ah, Bh, a1, 0, 0, 0);
                else
                    a0 = __builtin_amdgcn_mfma_f32_16x16x32_bf16(Ah, Bh, a0, 0, 0, 0);
            }
            if (s < 18) {
                const int t = s >> 1, cc2 = s & 1;
                const int ky = t / 3, kx = t % 3;
                const ushort_t* ab =
                    w4 + (((size_t)s * 28 + ot) * 64 + lane) * 8;
                pAh[s % 5] = *(const bf16x8*)ab;
                const int lb = (ky * 18 + n + kx) * 72 + cc2 * 32 + quad * 8;
                pBh[s % 5] = *(const bf16x8*)(ldsAH + lb);
            }
        }
#pragma unroll
        for (int r = 0; r < 4; ++r) {
            int cout = ot * 16 + quad * 4 + r;
            float v = a0[r] + a1[r] + (cout < 432 ? ob4[cout] : 0.f);
            rawS[(idx * 16 + quad * 4 + r) * 17 + n] = v;
        }
    }

    // ---- phase 3: gather (bf16-hi) -> bf16 cols -> dconv MFMA (1-term) ----
    f32x4 acc0, acc1;
#pragma unroll
    for (int r = 0; r < 4; ++r) { acc0[r] = 0.f; acc1[r] = 0.f; }

    for (int gci = 0; gci < nrounds; ++gci) {
        const int gc = h * nrounds + gci;
        __syncthreads();  // rawS ready / cols (ldsA) reuse safe
#pragma unroll
        for (int i = 0; i < 3; ++i) {
            int e = tid + i * 256;
            if (e < 576) {
                int p = e & 15;
                int r = e >> 4;  // 0..35
                int gl = r / 9, k = r - gl * 9;
                int g = gc * 4 + gl;
                float ry = rawS[(g * 18 + k * 2 + 0 - rowOffO) * 17 + p];
                float rx = rawS[(g * 18 + k * 2 + 1 - rowOffO) * 17 + p];
                float rm = rawS[(288 + g * 9 + k - rowOffM) * 17 + p];
                float oy = 5.f * (1.f - 2.f / (1.f + __expf(2.f * ry)));
                float ox = 5.f * (1.f - 2.f / (1.f + __expf(2.f * rx)));
                float m = 1.f / (1.f + __expf(-rm));
                float sy = oy + (float)(y - 1 + k / 3);
                float sx = ox + (float)(xb + p - 1 + k % 3);
                float fy0 = floorf(sy), fx0 = floorf(sx);
                float fy = sy - fy0, fx = sx - fx0;
                int y0 = (int)fy0, x0 = (int)fx0;
                int y1 = y0 + 1, x1 = x0 + 1;
                bool vy0 = (unsigned)y0 < 96u, vy1 = (unsigned)y1 < 96u;
                bool vx0 = (unsigned)x0 < 96u, vx1 = (unsigned)x1 < 96u;
                int cy0 = min(max(y0, 0), 95), cy1 = min(max(y1, 0), 95);
                int cx0 = min(max(x0, 0), 95), cx1 = min(max(x1, 0), 95);
                float w00 = (1.f - fy) * (1.f - fx) * ((vy0 && vx0) ? 1.f : 0.f);
                float w01 = (1.f - fy) * fx * ((vy0 && vx1) ? 1.f : 0.f);
                float w10 = fy * (1.f - fx) * ((vy1 && vx0) ? 1.f : 0.f);
                float w11 = fy * fx * ((vy1 && vx1) ? 1.f : 0.f);
                const ushort_t* src = (g < 8) ? sAh : sBh;
                int cb = (g & 7) * 8;
                int kbase = p * 296 + gl * 72 + k * 8;
                ushort_t hh[8];
                if (src) {
                    u16x8 c00 = *(const u16x8*)(src + (cy0 * 96 + cx0) * 64 + cb);
                    u16x8 c01 = *(const u16x8*)(src + (cy0 * 96 + cx1) * 64 + cb);
                    u16x8 c10 = *(const u16x8*)(src + (cy1 * 96 + cx0) * 64 + cb);
                    u16x8 c11 = *(const u16x8*)(src + (cy1 * 96 + cx1) * 64 + cb);
#pragma unroll
                    for (int c = 0; c < 8; ++c) {
                        float v = w00 * bfh(c00[c]) + w01 * bfh(c01[c]) +
                                  w10 * bfh(c10[c]) + w11 * bfh(c11[c]);
                        hh[c] = bf16rnd(v * m);
                    }
                } else {
#pragma unroll
                    for (int c = 0; c < 8; ++c) hh[c] = 0;
                }
                u32x4 H;
#pragma unroll
                for (int q = 0; q < 4; ++q)
                    H[q] = (unsigned)hh[2 * q] | ((unsigned)hh[2 * q + 1] << 16);
                *(u32x4*)(colsH + kbase) = H;
            }
        }
        __syncthreads();
        bf16x8 qAh[4], qBh[4];
#pragma unroll
        for (int s = 0; s < 13; ++s) {
            if (s >= 4) {  // consume BEFORE refilling the slot
                const int u = s - 4;
                const bf16x8 Ah = qAh[u % 4];
                const bf16x8 Bh = qBh[u % 4];
                if (u & 1)
                    acc1 = __builtin_amdgcn_mfma_f32_16x16x32_bf16(Ah, Bh, acc1, 0, 0, 0);
                else
                    acc0 = __builtin_amdgcn_mfma_f32_16x16x32_bf16(Ah, Bh, acc0, 0, 0, 0);
            }
            if (s < 9) {
                const int cc = gc * 9 + s;
                const ushort_t* ab = dwf + (((size_t)cc * 4 + w) * 64 + lane) * 8;
                qAh[s % 4] = *(const bf16x8*)ab;
                const int lb = n * 296 + s * 32 + quad * 8;
                qBh[s % 4] = *(const bf16x8*)(colsH + lb);
            }
        }
    }

    const int pidx = y * 96 + xb + n;
    f32x4 sv;
#pragma unroll
    for (int r = 0; r < 4; ++r) sv[r] = acc0[r] + acc1[r];
    *(f32x4*)(pacc + (size_t)h * FRAME + (size_t)pidx * 64 + w * 16 +
              quad * 4) = sv;
}

// ---------------------------------------------------------------------------
// MFMA fusion: 1x1 conv over [featB[t], featF[t]] (K=128) + bias + x.
// ---------------------------------------------------------------------------
__global__ __launch_bounds__(128) void fusem_k(
    const unsigned* __restrict__ featB, const unsigned* __restrict__ featF,
    const float* __restrict__ x, const ushort_t* __restrict__ wfrag,
    const float* __restrict__ bias, float* __restrict__ out) {
    const int tid = threadIdx.x;
    const int lane = tid & 63;
    const int w = tid >> 6;
    const int h = blockIdx.x & 1;
    const int bseg = blockIdx.x >> 1;
    const int t = blockIdx.y;
    const int ot = h * 2 + w;
    const int xb = (bseg % 6) * 16;
    const int y = bseg / 6;
    const int n = lane & 15;
    const int quad = lane >> 4;

    __shared__ __align__(16) ushort_t ldsH[16 * 144];
    __shared__ __align__(16) ushort_t ldsL[16 * 144];

    const int p = tid >> 3, cg = tid & 7;
    const int off = ((y * 96 + xb + p) * 64 + cg * 8);
#pragma unroll
    for (int i = 0; i < 2; ++i) {  // i=0: featB (ch 0-63), i=1: featF (64-127)
        const unsigned* sv =
            (i == 0 ? featB : featF) + (size_t)t * FRAME;
        u32x4 a = *(const u32x4*)(sv + off);
        u32x4 b = *(const u32x4*)(sv + off + 4);
        u32x4 H, L;
#pragma unroll
        for (int q = 0; q < 2; ++q) {
            H[q] = (a[2 * q] >> 16) | (a[2 * q + 1] & 0xFFFF0000u);
            L[q] = (a[2 * q] & 0xFFFFu) | (a[2 * q + 1] << 16);
            H[2 + q] = (b[2 * q] >> 16) | (b[2 * q + 1] & 0xFFFF0000u);
            L[2 + q] = (b[2 * q] & 0xFFFFu) | (b[2 * q + 1] << 16);
        }
        *(u32x4*)(ldsH + p * 144 + i * 64 + cg * 8) = H;
        *(u32x4*)(ldsL + p * 144 + i * 64 + cg * 8) = L;
    }
    __syncthreads();

    f32x4 acc0, acc1;
#pragma unroll
    for (int r = 0; r < 4; ++r) { acc0[r] = 0.f; acc1[r] = 0.f; }
    const size_t hlOff = (size_t)4 * 4 * 512;
#pragma unroll
    for (int cc = 0; cc < 4; ++cc) {
        const ushort_t* ab = wfrag + (((size_t)cc * 4 + ot) * 64 + lane) * 8;
        bf16x8 Ah = *(const bf16x8*)ab;
        bf16x8 Al = *(const bf16x8*)(ab + hlOff);
        int lb = n * 144 + cc * 32 + quad * 8;
        bf16x8 Bh = *(const bf16x8*)(ldsH + lb);
        bf16x8 Bl = *(const bf16x8*)(ldsL + lb);
        if (cc & 1) {
            acc1 = __builtin_amdgcn_mfma_f32_16x16x32_bf16(Ah, Bh, acc1, 0, 0, 0);
            acc1 = __builtin_amdgcn_mfma_f32_16x16x32_bf16(Al, Bh, acc1, 0, 0, 0);
            acc1 = __builtin_amdgcn_mfma_f32_16x16x32_bf16(Ah, Bl, acc1, 0, 0, 0);
        } else {
            acc0 = __builtin_amdgcn_mfma_f32_16x16x32_bf16(Ah, Bh, acc0, 0, 0, 0);
            acc0 = __builtin_amdgcn_mfma_f32_16x16x32_bf16(Al, Bh, acc0, 0, 0, 0);
            acc0 = __builtin_amdgcn_mfma_f32_16x16x32_bf16(Ah, Bl, acc0, 0, 0, 0);
        }
    }

    const int pidx = y * 96 + xb + n;
    const float* xt = x + (size_t)t * FRAME;
    float* od = out + (size_t)t * FRAME;
#pragma unroll
    for (int r = 0; r < 4; ++r) {
        int cout = ot * 16 + quad * 4 + r;
        size_t o2 = (size_t)cout * HW96 + pidx;
        od[o2] = acc0[r] + acc1[r] + bias[cout] + xt[o2];
    }
}

// ---------------------------------------------------------------------------
extern "C" void kernel_launch(void* const* d_in, const int* in_sizes, int n_in,
                              void* d_out, int out_size, void* d_ws,
                              size_t ws_size, hipStream_t stream) {
    const float* x = (const float*)d_in[0];
    auto gp = [&](int i) { return (const float*)d_in[i]; };

    struct DirP {
        const float *dw, *db, *ow1, *ob1, *ow2, *ob2, *ow3, *ob3, *ow4, *ob4,
            *bw1, *bb1, *bw2, *bb2;
    };
    DirP Pb{gp(1), gp(2), gp(3), gp(4), gp(5), gp(6), gp(7),
            gp(8), gp(9), gp(10), gp(11), gp(12), gp(13), gp(14)};
    DirP Pf{gp(15), gp(16), gp(17), gp(18), gp(19), gp(20), gp(21),
            gp(22), gp(23), gp(24), gp(25), gp(26), gp(27), gp(28)};
    const float* fus_w = gp(29);
    const float* fus_b = gp(30);

    // ---- workspace carve-up (4-byte units); all feature bufs interleaved ----
    unsigned* featBpk = (unsigned*)d_ws;
    unsigned* featFpk = featBpk + (size_t)8 * FRAME;
    unsigned* xpk = featFpk + (size_t)8 * FRAME;
    unsigned* hApk = xpk + (size_t)8 * FRAME;         // ow chain (hi ushort)
    unsigned* hBpk = hApk + FRAME;
    ushort_t* fragp = (ushort_t*)(hBpk + FRAME);

    auto falloc = [&](size_t nelem) {
        ushort_t* p = fragp;
        fragp += nelem;
        return p;
    };

    struct DirW { ushort_t *ow1, *ow2, *ow3, *ow4, *bw1, *bw2, *dw; int bw1KC; };
    FragJobs fj;
    int nf = 0;
    auto fjob = [&](const float* src, int O, int I, int OT, int KC) {
        ushort_t* dst = falloc((size_t)2 * 9 * KC * OT * 512);
        fj.j[nf++] = FragJob{src, dst, O, I, OT, KC, 0};
        return dst;
    };
    auto fjobd = [&](const float* src) {
        ushort_t* dst = falloc((size_t)2 * 36 * 4 * 512);
        fj.j[nf++] = FragJob{src, dst, 64, 128, 4, 36, 1};
        return dst;
    };
    DirW Wb, Wf;
    Wb.ow1 = fjob(Pb.ow1, 64, 192, 4, 6);
    Wb.ow2 = fjob(Pb.ow2, 64, 64, 4, 2);
    Wb.ow3 = fjob(Pb.ow3, 64, 64, 4, 2);
    Wb.ow4 = fjob(Pb.ow4, 432, 64, 28, 2);
    Wb.bw1 = fjob(Pb.bw1, 64, 128, 4, 4);
    Wb.bw1KC = 4;
    Wb.bw2 = fjob(Pb.bw2, 64, 64, 4, 2);
    Wb.dw = fjobd(Pb.dw);
    Wf.ow1 = fjob(Pf.ow1, 64, 192, 4, 6);
    Wf.ow2 = fjob(Pf.ow2, 64, 64, 4, 2);
    Wf.ow3 = fjob(Pf.ow3, 64, 64, 4, 2);
    Wf.ow4 = fjob(Pf.ow4, 432, 64, 28, 2);
    Wf.bw1 = fjob(Pf.bw1, 64, 192, 4, 6);
    Wf.bw1KC = 6;
    Wf.bw2 = fjob(Pf.bw2, 64, 64, 4, 2);
    Wf.dw = fjobd(Pf.dw);
    // fusion 1x1 weights (mode 2): O=64, I=128, OT=4, KC=4
    ushort_t* Wfus = falloc((size_t)2 * 4 * 4 * 512);
    fj.j[nf++] = FragJob{fus_w, Wfus, 64, 128, 4, 4, 2};
    frag_all_k<<<dim3(1008, 15), 256, 0, stream>>>(fj);

    // after frags: pacc (2F f32 interleaved), feat hi shadows, x hi shadow
    float* pacc = (float*)((((uintptr_t)fragp) + 15) & ~(uintptr_t)15);
    ushort_t* featBh = (ushort_t*)(pacc + (size_t)2 * FRAME);
    ushort_t* featFh = featBh + (size_t)8 * FRAME;
    ushort_t* xh = featFh + (size_t)8 * FRAME;
    ushort_t* hAh = (ushort_t*)hApk;
    ushort_t* hBh = (ushort_t*)hBpk;

    pack_tr_k<<<dim3(144, 8), 256, 0, stream>>>(x, xpk, xh);

    auto convm = [&](const unsigned* a, const unsigned* b, int withD,
                     const float* ddbias, const ushort_t* frag, int KCfull,
                     const float* bias, const float* add, const float* add2,
                     const float* abias, ushort_t* outhi, unsigned* out,
                     int act, int terms) {
        const unsigned* S[2] = {nullptr, nullptr};
        int ns = 0;
        if (a) S[ns++] = a;
        if (b) S[ns++] = b;
        int dslot = -1;
        if (withD) { dslot = ns; ++ns; }
        if (terms == 2)
            convm_k<2><<<1152, 128, 0, stream>>>(
                S[0], S[1], ns, dslot, pacc, ddbias, frag, KCfull, bias, add,
                add2, abias, outhi, out, act);
        else
            convm_k<3><<<1152, 128, 0, stream>>>(
                S[0], S[1], ns, dslot, pacc, ddbias, frag, KCfull, bias, add,
                add2, abias, outhi, out, act);
    };

    auto convh = [&](const ushort_t* a, const ushort_t* b, const ushort_t* c2,
                     const ushort_t* frag, int KCfull, const float* bias,
                     ushort_t* out, int act) {
        const ushort_t* srcs[3] = {a, b, c2};
        const ushort_t* S[3] = {nullptr, nullptr, nullptr};
        int B[3] = {0, 0, 0};
        int ns = 0;
        for (int j = 0; j < 3; ++j)
            if (srcs[j]) {
                S[ns] = srcs[j];
                B[ns] = j * 2;
                ++ns;
            }
        convh_k<<<1152, 128, 0, stream>>>(S[0], S[1], S[2], B[0], B[1], B[2],
                                          ns, frag, KCfull, bias, out, act);
    };

    for (int dir = 0; dir < 2; ++dir) {  // 0 = backward, 1 = forward
        const DirP& P = dir ? Pf : Pb;
        const DirW& W = dir ? Wf : Wb;
        unsigned* feat = dir ? featFpk : featBpk;
        ushort_t* feath = dir ? featFh : featBh;
        const ushort_t* prev1h = nullptr;
        const ushort_t* prev2h = nullptr;
        for (int i = 0; i < 8; ++i) {
            int idx = dir ? i : 7 - i;
            const unsigned* cur = xpk + (size_t)idx * FRAME;
            const ushort_t* curh = xh + (size_t)idx * FRAME;
            bool hasD = false;
            if (i > 0) {
                // offset/mask path: pure bf16-hi (convh)
                convh(prev1h, curh, prev2h, W.ow1, 6, P.ob1, hAh, 1);
                convh(hAh, nullptr, nullptr, W.ow2, 2, P.ob2, hBh, 1);
                convh(hBh, nullptr, nullptr, W.ow3, 2, P.ob3, hAh, 1);
                int ngr4 = (prev2h != nullptr) ? 4 : 2;
                dconv_fused_k<<<1152, 256, 0, stream>>>(
                    prev1h, prev2h, hAh, W.ow4, P.ob4, W.dw, ngr4, pacc);
                hasD = true;
            }
            unsigned* dst = feat + (size_t)idx * FRAME;
            ushort_t* dsth = feath + (size_t)idx * FRAME;
            // bw1: 2-term, D staged from interleaved pacc
            if (dir == 0) {
                convm(cur, nullptr, hasD ? 1 : 0, P.db, W.bw1, W.bw1KC, P.bb1,
                      nullptr, nullptr, nullptr, nullptr, hBpk, 1, 2);
            } else {
                convm(cur, featBpk + (size_t)idx * FRAME, hasD ? 1 : 0, P.db,
                      W.bw1, W.bw1KC, P.bb1, nullptr, nullptr, nullptr,
                      nullptr, hBpk, 1, 2);
            }
            // bw2: 2-term + interleaved pacc addsrc + hi shadow write
            convm(hBpk, nullptr, 0, nullptr, W.bw2, 2, P.bb2,
                  hasD ? pacc : nullptr, pacc + FRAME, P.db, dsth, dst, 0, 2);
            prev2h = prev1h;
            prev1h = dsth;
        }
    }

    fusem_k<<<dim3(1152, 8), 128, 0, stream>>>(featBpk, featFpk, x, Wfus,
                                               fus_b, (float*)d_out);
}

// Round 14
// 1062.914 us; speedup vs baseline: 1.6903x; 1.0844x over previous
//
#include <hip/hip_runtime.h>
#include <cstddef>
#include <cstdint>

#define HW96 9216
#define FRAME (64 * 9216)

typedef unsigned short ushort_t;
typedef __attribute__((ext_vector_type(8))) short bf16x8;
typedef __attribute__((ext_vector_type(4))) float f32x4;
typedef __attribute__((ext_vector_type(4))) unsigned u32x4;
typedef __attribute__((ext_vector_type(8))) ushort_t u16x8;
typedef __attribute__((ext_vector_type(4))) ushort_t u16x4;

__device__ __forceinline__ void split16(float v, ushort_t& h, ushort_t& l) {
    unsigned u = __float_as_uint(v);
    h = (ushort_t)(u >> 16);
    float rem = v - __uint_as_float(u & 0xFFFF0000u);
    unsigned r = __float_as_uint(rem);
    l = (ushort_t)((r + 0x7FFFu + ((r >> 16) & 1u)) >> 16);
}
__device__ __forceinline__ ushort_t bf16rnd(float v) {
    unsigned u = __float_as_uint(v);
    return (ushort_t)((u + 0x7FFFu + ((u >> 16) & 1u)) >> 16);
}
__device__ __forceinline__ float bfh(ushort_t h) {
    return __uint_as_float(((unsigned)h) << 16);
}

// ---------------------------------------------------------------------------
// MFMA A-fragment prepack (16x16x32) with bf16 hi/lo split.
// mode 0 (3x3 conv): layout [hl][t][cc][ot][lane][j]; K = cin chunks of 32.
// mode 1 (dconv):    layout [hl][cc][ot][lane][j]; K = g*72 + tap*8 + c.
// mode 2 (1x1 conv): layout [hl][cc][ot][lane][j]; K = cin chunks of 32.
// ---------------------------------------------------------------------------
struct FragJob { const float* src; ushort_t* dst; int O, I, OT, KC, mode; };
struct FragJobs { FragJob j[15]; };

__global__ __launch_bounds__(256) void frag_all_k(FragJobs jobs) {
    const FragJob& J = jobs.j[blockIdx.y];
    int idx = blockIdx.x * 256 + threadIdx.x;
    int total = ((J.mode == 0) ? 9 : 1) * J.KC * J.OT * 512;
    if (idx >= total) return;
    int jj = idx & 7;
    int lane = (idx >> 3) & 63;
    int rem = idx >> 9;
    int ot = rem % J.OT;
    rem /= J.OT;
    int cc = rem % J.KC;
    int t = rem / J.KC;
    int o = ot * 16 + (lane & 15);
    float wv = 0.f;
    if (J.mode == 0) {
        int ci = cc * 32 + (lane >> 4) * 8 + jj;
        if (o < J.O && ci < J.I) wv = J.src[(o * J.I + ci) * 9 + t];
    } else if (J.mode == 1) {
        int K = cc * 32 + (lane >> 4) * 8 + jj;
        int g = K / 72, r2 = K % 72;
        int tap = r2 >> 3, c = r2 & 7;
        int ci = g * 8 + c;
        if (o < J.O && ci < J.I) wv = J.src[(o * J.I + ci) * 9 + tap];
    } else {  // mode 2: 1x1
        int ci = cc * 32 + (lane >> 4) * 8 + jj;
        if (o < J.O && ci < J.I) wv = J.src[o * J.I + ci];
    }
    ushort_t h, l;
    split16(wv, h, l);
    J.dst[idx] = h;
    J.dst[total + idx] = l;
}

// ---------------------------------------------------------------------------
// Transposing pack: planar fp32 -> interleaved bf16-hi shadow only.
// ---------------------------------------------------------------------------
__global__ __launch_bounds__(256) void pack_tr_k(const float* __restrict__ src,
                                                 ushort_t* __restrict__ dsth) {
    const int t = blockIdx.y;
    const int px0 = blockIdx.x * 64;
    __shared__ ushort_t tile[64 * 65];
    const float* s = src + (size_t)t * FRAME;
    ushort_t* dh = dsth + (size_t)t * FRAME;
#pragma unroll
    for (int it = 0; it < 16; ++it) {
        int e = it * 256 + threadIdx.x;
        int p = e & 63, ch = e >> 6;
        tile[ch * 65 + p] = bf16rnd(s[(size_t)ch * HW96 + px0 + p]);
    }
    __syncthreads();
#pragma unroll
    for (int it = 0; it < 16; ++it) {
        int e = it * 256 + threadIdx.x;
        int ch = e & 63, p = e >> 6;
        dh[(size_t)(px0 + p) * 64 + ch] = tile[ch * 65 + p];
    }
}

// ---------------------------------------------------------------------------
// Hi-only bf16 MFMA 3x3 conv (offset/mask path: ow1/ow2/ow3).
// Sources bf16-hi interleaved; 1 u16x8/job staging; H-only LDS; 1 MFMA/step.
// ---------------------------------------------------------------------------
__global__ __launch_bounds__(128, 3) void convh_k(
    const ushort_t* __restrict__ s0, const ushort_t* __restrict__ s1,
    const ushort_t* __restrict__ s2, int b0, int b1, int b2, int nsrc,
    const ushort_t* __restrict__ wfrag, int KCfull,
    const float* __restrict__ bias, ushort_t* __restrict__ outhi, int act) {
    const int tid = threadIdx.x;
    const int lane = tid & 63;
    const int w = tid >> 6;
    const int h = blockIdx.x & 1;
    const int bseg = blockIdx.x >> 1;
    const int ot = h * 2 + w;
    const int xb = (bseg % 6) * 16;
    const int y = bseg / 6;
    const int n = lane & 15;
    const int quad = lane >> 4;

    __shared__ __align__(16) ushort_t ldsH[3 * 18 * 72];

    int jst[4], jok[4], joff[4], jbase[4];
#pragma unroll
    for (int i = 0; i < 4; ++i) {
        int e = tid + i * 128;
        int rc = e >> 3, cg = e & 7;
        int r = rc / 18, col = rc - r * 18;
        int gy = y - 1 + r, gx = xb - 1 + col;
        jst[i] = (e < 432);
        jok[i] = jst[i] && ((unsigned)gy < 96u) && ((unsigned)gx < 96u);
        joff[i] = (gy * 96 + gx) * 64 + cg * 8;
        jbase[i] = rc * 72 + cg * 8;
    }

    f32x4 acc0, acc1;
#pragma unroll
    for (int r = 0; r < 4; ++r) { acc0[r] = 0.f; acc1[r] = 0.f; }

    for (int j = 0; j < nsrc; ++j) {
        const ushort_t* sv = (j == 0) ? s0 : (j == 1 ? s1 : s2);
        const int base = (j == 0) ? b0 : (j == 1 ? b1 : b2);
        __syncthreads();
#pragma unroll
        for (int i = 0; i < 4; ++i) {
            if (jst[i]) {
                u16x8 a;
                if (jok[i]) {
                    a = *(const u16x8*)(sv + joff[i]);
                } else {
#pragma unroll
                    for (int q = 0; q < 8; ++q) a[q] = 0;
                }
                *(u16x8*)(ldsH + jbase[i]) = a;
            }
        }
        __syncthreads();
        bf16x8 pAh[5], pBh[5];
#pragma unroll
        for (int s = 0; s < 23; ++s) {
            if (s >= 5) {  // consume BEFORE refilling the slot
                const int u = s - 5;
                const bf16x8 Ah = pAh[u % 5];
                const bf16x8 Bh = pBh[u % 5];
                if (u & 1)
                    acc1 = __builtin_amdgcn_mfma_f32_16x16x32_bf16(Ah, Bh, acc1, 0, 0, 0);
                else
                    acc0 = __builtin_amdgcn_mfma_f32_16x16x32_bf16(Ah, Bh, acc0, 0, 0, 0);
            }
            if (s < 18) {
                const int t = s >> 1, cc2 = s & 1;
                const int ky = t / 3, kx = t % 3;
                const int ccor = base + cc2;
                const ushort_t* ab =
                    wfrag + (((size_t)(t * KCfull + ccor) * 4 + ot) * 64 + lane) * 8;
                pAh[s % 5] = *(const bf16x8*)ab;
                const int lb = (ky * 18 + n + kx) * 72 + cc2 * 32 + quad * 8;
                pBh[s % 5] = *(const bf16x8*)(ldsH + lb);
            }
        }
    }

    const int px = y * 96 + xb + n;
    u16x4 hi4;
#pragma unroll
    for (int r = 0; r < 4; ++r) {
        int cout = ot * 16 + quad * 4 + r;
        float v = acc0[r] + acc1[r] + bias[cout];
        if (act) v = (v >= 0.f) ? v : 0.1f * v;
        hi4[r] = bf16rnd(v);
    }
    *(u16x4*)(outhi + (size_t)px * 64 + ot * 16 + quad * 4) = hi4;
}

// ---------------------------------------------------------------------------
// Feature-path hi-only bf16 MFMA 3x3 conv (bw1/bw2).
// Like convh, plus: dslot stages D = bf16(pacc0+pacc1+dbias) from the
// interleaved pacc pair; bw2 epilogue adds pacc pair + abias (fp32 vector
// loads) before writing the bf16-hi feature shadow. 1 MFMA/K-step.
// ---------------------------------------------------------------------------
__global__ __launch_bounds__(128, 3) void convb_k(
    const ushort_t* __restrict__ s0, const ushort_t* __restrict__ s1,
    int nsrc, int dslot, const float* __restrict__ dpacc,
    const float* __restrict__ ddbias, const ushort_t* __restrict__ wfrag,
    int KCfull, const float* __restrict__ bias,
    const float* __restrict__ addsrc, const float* __restrict__ addsrc2,
    const float* __restrict__ abias, ushort_t* __restrict__ outhi, int act) {
    const int tid = threadIdx.x;
    const int lane = tid & 63;
    const int w = tid >> 6;
    const int h = blockIdx.x & 1;
    const int bseg = blockIdx.x >> 1;
    const int ot = h * 2 + w;
    const int xb = (bseg % 6) * 16;
    const int y = bseg / 6;
    const int n = lane & 15;
    const int quad = lane >> 4;

    __shared__ __align__(16) ushort_t ldsH[3 * 18 * 72];

    int jst[4], jok[4], joff[4], jbase[4];
#pragma unroll
    for (int i = 0; i < 4; ++i) {
        int e = tid + i * 128;
        int rc = e >> 3, cg = e & 7;
        int r = rc / 18, col = rc - r * 18;
        int gy = y - 1 + r, gx = xb - 1 + col;
        jst[i] = (e < 432);
        jok[i] = jst[i] && ((unsigned)gy < 96u) && ((unsigned)gx < 96u);
        joff[i] = (gy * 96 + gx) * 64 + cg * 8;
        jbase[i] = rc * 72 + cg * 8;
    }

    f32x4 acc0, acc1;
#pragma unroll
    for (int r = 0; r < 4; ++r) { acc0[r] = 0.f; acc1[r] = 0.f; }

    for (int j = 0; j < nsrc; ++j) {
        const int base = j * 2;
        __syncthreads();
        if (j == dslot) {
            // stage D = bf16(pacc0 + pacc1 + dbias) (interleaved f32 pair)
#pragma unroll
            for (int i = 0; i < 4; ++i) {
                if (jst[i]) {
                    u16x8 a;
                    if (jok[i]) {
                        const int cg8 = ((tid + i * 128) & 7) << 3;
                        f32x4 a0 = *(const f32x4*)(dpacc + joff[i]);
                        f32x4 a1 = *(const f32x4*)(dpacc + joff[i] + 4);
                        f32x4 b0 = *(const f32x4*)(dpacc + FRAME + joff[i]);
                        f32x4 b1 = *(const f32x4*)(dpacc + FRAME + joff[i] + 4);
                        f32x4 d0 = *(const f32x4*)(ddbias + cg8);
                        f32x4 d1 = *(const f32x4*)(ddbias + cg8 + 4);
#pragma unroll
                        for (int q = 0; q < 4; ++q) {
                            a[q] = bf16rnd(a0[q] + b0[q] + d0[q]);
                            a[4 + q] = bf16rnd(a1[q] + b1[q] + d1[q]);
                        }
                    } else {
#pragma unroll
                        for (int q = 0; q < 8; ++q) a[q] = 0;
                    }
                    *(u16x8*)(ldsH + jbase[i]) = a;
                }
            }
        } else {
            const ushort_t* sv = (j == 0) ? s0 : s1;
#pragma unroll
            for (int i = 0; i < 4; ++i) {
                if (jst[i]) {
                    u16x8 a;
                    if (jok[i]) {
                        a = *(const u16x8*)(sv + joff[i]);
                    } else {
#pragma unroll
                        for (int q = 0; q < 8; ++q) a[q] = 0;
                    }
                    *(u16x8*)(ldsH + jbase[i]) = a;
                }
            }
        }
        __syncthreads();
        bf16x8 pAh[5], pBh[5];
#pragma unroll
        for (int s = 0; s < 23; ++s) {
            if (s >= 5) {  // consume BEFORE refilling the slot
                const int u = s - 5;
                const bf16x8 Ah = pAh[u % 5];
                const bf16x8 Bh = pBh[u % 5];
                if (u & 1)
                    acc1 = __builtin_amdgcn_mfma_f32_16x16x32_bf16(Ah, Bh, acc1, 0, 0, 0);
                else
                    acc0 = __builtin_amdgcn_mfma_f32_16x16x32_bf16(Ah, Bh, acc0, 0, 0, 0);
            }
            if (s < 18) {
                const int t = s >> 1, cc2 = s & 1;
                const int ky = t / 3, kx = t % 3;
                const int ccor = j * 2 + cc2;
                (void)ccor;
                const int cco = base + cc2;
                const ushort_t* ab =
                    wfrag + (((size_t)(t * KCfull + cco) * 4 + ot) * 64 + lane) * 8;
                pAh[s % 5] = *(const bf16x8*)ab;
                const int lb = (ky * 18 + n + kx) * 72 + cc2 * 32 + quad * 8;
                pBh[s % 5] = *(const bf16x8*)(ldsH + lb);
            }
        }
    }

    const int px = y * 96 + xb + n;
    f32x4 pa, pb;
#pragma unroll
    for (int r = 0; r < 4; ++r) { pa[r] = 0.f; pb[r] = 0.f; }
    if (addsrc) {
        pa = *(const f32x4*)(addsrc + (size_t)px * 64 + ot * 16 + quad * 4);
        pb = *(const f32x4*)(addsrc2 + (size_t)px * 64 + ot * 16 + quad * 4);
    }
    u16x4 hi4;
#pragma unroll
    for (int r = 0; r < 4; ++r) {
        int cout = ot * 16 + quad * 4 + r;
        float v = acc0[r] + acc1[r] + bias[cout];
        if (act) v = (v >= 0.f) ? v : 0.1f * v;
        if (addsrc) v += pa[r] + pb[r] + abias[cout];
        hi4[r] = bf16rnd(v);
    }
    *(u16x4*)(outhi + (size_t)px * 64 + ot * 16 + quad * 4) = hi4;
}

// ---------------------------------------------------------------------------
// Fused ow4 + modulated deformable conv, HALF-SPLIT: grid 1152 = 576 seg x 2.
// hA bf16-hi; gather reads bf16-hi shadows; cols single bf16; 1-term MFMA.
// pacc INTERLEAVED [h][px][64] f32.
// ---------------------------------------------------------------------------
__global__ __launch_bounds__(256) void dconv_fused_k(
    const ushort_t* __restrict__ sAh, const ushort_t* __restrict__ sBh,
    const ushort_t* __restrict__ hAh, const ushort_t* __restrict__ w4,
    const float* __restrict__ ob4, const ushort_t* __restrict__ dwf,
    int ngr4, float* __restrict__ pacc) {
    const int tid = threadIdx.x;
    const int lane = tid & 63;
    const int w = tid >> 6;
    const int h = blockIdx.x & 1;
    const int seg = blockIdx.x >> 1;
    const int xb = (seg % 6) * 16;
    const int y = seg / 6;
    const int n = lane & 15;
    const int quad = lane >> 4;

    __shared__ __align__(16) char smem[15232 + 9472];
    float* rawS = (float*)smem;               // up to [224][17] fp32
    ushort_t* ldsAH = (ushort_t*)(smem + 15232);  // 3888 ushorts (H-only)
    ushort_t* colsH = (ushort_t*)(smem + 15232);  // union with ldsA (4736 us)

    const int nrounds = ngr4 >> 1;   // 1 or 2
    const int ng = nrounds * 4;      // groups per half
    const int g0 = h * ng;
    const int otO_s = (g0 * 18) >> 4;
    const int otO_e = (g0 * 18 + ng * 18 - 1) >> 4;
    const int nO = otO_e - otO_s + 1;
    const int otM_s = (288 + g0 * 9) >> 4;
    const int otM_e = (288 + g0 * 9 + ng * 9 - 1) >> 4;
    const int nM = otM_e - otM_s + 1;
    const int nt = nO + nM;          // 14 (ngr4=4) or 8 (ngr4=2)
    const int rowOffO = otO_s * 16;
    const int rowOffM = otM_s * 16 - nO * 16;

    // ---- phase 1: stage hA window (bf16-hi source, 1 load/job) ----
#pragma unroll
    for (int i = 0; i < 2; ++i) {
        int e = tid + i * 256;
        if (e < 432) {
            int rc = e >> 3, cg = e & 7;
            int r = rc / 18, col = rc - r * 18;
            int gy = y - 1 + r, gx = xb - 1 + col;
            bool ok = ((unsigned)gy < 96u) && ((unsigned)gx < 96u);
            u16x8 a;
            if (ok) {
                a = *(const u16x8*)(hAh + (gy * 96 + gx) * 64 + cg * 8);
            } else {
#pragma unroll
                for (int q = 0; q < 8; ++q) a[q] = 0;
            }
            *(u16x8*)(ldsAH + rc * 72 + cg * 8) = a;
        }
    }
    __syncthreads();

    // ---- phase 2: needed ow4 out-tiles, 1 MFMA/step, depth-5 pipeline ----
#pragma unroll 1
    for (int j = 0; j < 4; ++j) {
        const int idx = j * 4 + w;
        if (idx >= nt) break;
        const int ot = (idx < nO) ? (otO_s + idx) : (otM_s + (idx - nO));
        f32x4 a0, a1;
#pragma unroll
        for (int r = 0; r < 4; ++r) { a0[r] = 0.f; a1[r] = 0.f; }
        bf16x8 pAh[5], pBh[5];
#pragma unroll
        for (int s = 0; s < 23; ++s) {
            if (s >= 5) {  // consume BEFORE refilling the slot
                const int u = s - 5;
                const bf16x8 Ah = pAh[u % 5];
                const bf16x8 Bh = pBh[u % 5];
                if (u & 1)
                    a1 = __builtin_amdgcn_mfma_f32_16x16x32_bf16(Ah, Bh, a1, 0, 0, 0);
                else
                    a0 = __builtin_amdgcn_mfma_f32_16x16x32_bf16(Ah, Bh, a0, 0, 0, 0);
            }
            if (s < 18) {
                const int t = s >> 1, cc2 = s & 1;
                const int ky = t / 3, kx = t % 3;
                const ushort_t* ab =
                    w4 + (((size_t)s * 28 + ot) * 64 + lane) * 8;
                pAh[s % 5] = *(const bf16x8*)ab;
                const int lb = (ky * 18 + n + kx) * 72 + cc2 * 32 + quad * 8;
                pBh[s % 5] = *(const bf16x8*)(ldsAH + lb);
            }
        }
#pragma unroll
        for (int r = 0; r < 4; ++r) {
            int cout = ot * 16 + quad * 4 + r;
            float v = a0[r] + a1[r] + (cout < 432 ? ob4[cout] : 0.f);
            rawS[(idx * 16 + quad * 4 + r) * 17 + n] = v;
        }
    }

    // ---- phase 3: gather (bf16-hi) -> bf16 cols -> dconv MFMA (1-term) ----
    f32x4 acc0, acc1;
#pragma unroll
    for (int r = 0; r < 4; ++r) { acc0[r] = 0.f; acc1[r] = 0.f; }

    for (int gci = 0; gci < nrounds; ++gci) {
        const int gc = h * nrounds + gci;
        __syncthreads();  // rawS ready / cols (ldsA) reuse safe
#pragma unroll
        for (int i = 0; i < 3; ++i) {
            int e = tid + i * 256;
            if (e < 576) {
                int p = e & 15;
                int r = e >> 4;  // 0..35
                int gl = r / 9, k = r - gl * 9;
                int g = gc * 4 + gl;
                float ry = rawS[(g * 18 + k * 2 + 0 - rowOffO) * 17 + p];
                float rx = rawS[(g * 18 + k * 2 + 1 - rowOffO) * 17 + p];
                float rm = rawS[(288 + g * 9 + k - rowOffM) * 17 + p];
                float oy = 5.f * (1.f - 2.f / (1.f + __expf(2.f * ry)));
                float ox = 5.f * (1.f - 2.f / (1.f + __expf(2.f * rx)));
                float m = 1.f / (1.f + __expf(-rm));
                float sy = oy + (float)(y - 1 + k / 3);
                float sx = ox + (float)(xb + p - 1 + k % 3);
                float fy0 = floorf(sy), fx0 = floorf(sx);
                float fy = sy - fy0, fx = sx - fx0;
                int y0 = (int)fy0, x0 = (int)fx0;
                int y1 = y0 + 1, x1 = x0 + 1;
                bool vy0 = (unsigned)y0 < 96u, vy1 = (unsigned)y1 < 96u;
                bool vx0 = (unsigned)x0 < 96u, vx1 = (unsigned)x1 < 96u;
                int cy0 = min(max(y0, 0), 95), cy1 = min(max(y1, 0), 95);
                int cx0 = min(max(x0, 0), 95), cx1 = min(max(x1, 0), 95);
                float w00 = (1.f - fy) * (1.f - fx) * ((vy0 && vx0) ? 1.f : 0.f);
                float w01 = (1.f - fy) * fx * ((vy0 && vx1) ? 1.f : 0.f);
                float w10 = fy * (1.f - fx) * ((vy1 && vx0) ? 1.f : 0.f);
                float w11 = fy * fx * ((vy1 && vx1) ? 1.f : 0.f);
                const ushort_t* src = (g < 8) ? sAh : sBh;
                int cb = (g & 7) * 8;
                int kbase = p * 296 + gl * 72 + k * 8;
                ushort_t hh[8];
                if (src) {
                    u16x8 c00 = *(const u16x8*)(src + (cy0 * 96 + cx0) * 64 + cb);
                    u16x8 c01 = *(const u16x8*)(src + (cy0 * 96 + cx1) * 64 + cb);
                    u16x8 c10 = *(const u16x8*)(src + (cy1 * 96 + cx0) * 64 + cb);
                    u16x8 c11 = *(const u16x8*)(src + (cy1 * 96 + cx1) * 64 + cb);
#pragma unroll
                    for (int c = 0; c < 8; ++c) {
                        float v = w00 * bfh(c00[c]) + w01 * bfh(c01[c]) +
                                  w10 * bfh(c10[c]) + w11 * bfh(c11[c]);
                        hh[c] = bf16rnd(v * m);
                    }
                } else {
#pragma unroll
                    for (int c = 0; c < 8; ++c) hh[c] = 0;
                }
                u32x4 H;
#pragma unroll
                for (int q = 0; q < 4; ++q)
                    H[q] = (unsigned)hh[2 * q] | ((unsigned)hh[2 * q + 1] << 16);
                *(u32x4*)(colsH + kbase) = H;
            }
        }
        __syncthreads();
        bf16x8 qAh[4], qBh[4];
#pragma unroll
        for (int s = 0; s < 13; ++s) {
            if (s >= 4) {  // consume BEFORE refilling the slot
                const int u = s - 4;
                const bf16x8 Ah = qAh[u % 4];
                const bf16x8 Bh = qBh[u % 4];
                if (u & 1)
                    acc1 = __builtin_amdgcn_mfma_f32_16x16x32_bf16(Ah, Bh, acc1, 0, 0, 0);
                else
                    acc0 = __builtin_amdgcn_mfma_f32_16x16x32_bf16(Ah, Bh, acc0, 0, 0, 0);
            }
            if (s < 9) {
                const int cc = gc * 9 + s;
                const ushort_t* ab = dwf + (((size_t)cc * 4 + w) * 64 + lane) * 8;
                qAh[s % 4] = *(const bf16x8*)ab;
                const int lb = n * 296 + s * 32 + quad * 8;
                qBh[s % 4] = *(const bf16x8*)(colsH + lb);
            }
        }
    }

    const int pidx = y * 96 + xb + n;
    f32x4 sv;
#pragma unroll
    for (int r = 0; r < 4; ++r) sv[r] = acc0[r] + acc1[r];
    *(f32x4*)(pacc + (size_t)h * FRAME + (size_t)pidx * 64 + w * 16 +
              quad * 4) = sv;
}

// ---------------------------------------------------------------------------
// MFMA fusion: 1x1 conv over bf16-hi [featBh[t], featFh[t]] (K=128) + bias
// + x. Weight hi/lo kept (AhBh + AlBh): final-output precision.
// ---------------------------------------------------------------------------
__global__ __launch_bounds__(128) void fusem_k(
    const ushort_t* __restrict__ featBh, const ushort_t* __restrict__ featFh,
    const float* __restrict__ x, const ushort_t* __restrict__ wfrag,
    const float* __restrict__ bias, float* __restrict__ out) {
    const int tid = threadIdx.x;
    const int lane = tid & 63;
    const int w = tid >> 6;
    const int h = blockIdx.x & 1;
    const int bseg = blockIdx.x >> 1;
    const int t = blockIdx.y;
    const int ot = h * 2 + w;
    const int xb = (bseg % 6) * 16;
    const int y = bseg / 6;
    const int n = lane & 15;
    const int quad = lane >> 4;

    __shared__ __align__(16) ushort_t ldsH[16 * 144];

    const int p = tid >> 3, cg = tid & 7;
    const int off = ((y * 96 + xb + p) * 64 + cg * 8);
#pragma unroll
    for (int i = 0; i < 2; ++i) {  // i=0: featB (ch 0-63), i=1: featF (64-127)
        const ushort_t* sv =
            (i == 0 ? featBh : featFh) + (size_t)t * FRAME;
        u16x8 a = *(const u16x8*)(sv + off);
        *(u16x8*)(ldsH + p * 144 + i * 64 + cg * 8) = a;
    }
    __syncthreads();

    f32x4 acc0, acc1;
#pragma unroll
    for (int r = 0; r < 4; ++r) { acc0[r] = 0.f; acc1[r] = 0.f; }
    const size_t hlOff = (size_t)4 * 4 * 512;
#pragma unroll
    for (int cc = 0; cc < 4; ++cc) {
        const ushort_t* ab = wfrag + (((size_t)cc * 4 + ot) * 64 + lane) * 8;
        bf16x8 Ah = *(const bf16x8*)ab;
        bf16x8 Al = *(const bf16x8*)(ab + hlOff);
        int lb = n * 144 + cc * 32 + quad * 8;
        bf16x8 Bh = *(const bf16x8*)(ldsH + lb);
        if (cc & 1) {
            acc1 = __builtin_amdgcn_mfma_f32_16x16x32_bf16(Ah, Bh, acc1, 0, 0, 0);
            acc1 = __builtin_amdgcn_mfma_f32_16x16x32_bf16(Al, Bh, acc1, 0, 0, 0);
        } else {
            acc0 = __builtin_amdgcn_mfma_f32_16x16x32_bf16(Ah, Bh, acc0, 0, 0, 0);
            acc0 = __builtin_amdgcn_mfma_f32_16x16x32_bf16(Al, Bh, acc0, 0, 0, 0);
        }
    }

    const int pidx = y * 96 + xb + n;
    const float* xt = x + (size_t)t * FRAME;
    float* od = out + (size_t)t * FRAME;
#pragma unroll
    for (int r = 0; r < 4; ++r) {
        int cout = ot * 16 + quad * 4 + r;
        size_t o2 = (size_t)cout * HW96 + pidx;
        od[o2] = acc0[r] + acc1[r] + bias[cout] + xt[o2];
    }
}

// ---------------------------------------------------------------------------
extern "C" void kernel_launch(void* const* d_in, const int* in_sizes, int n_in,
                              void* d_out, int out_size, void* d_ws,
                              size_t ws_size, hipStream_t stream) {
    const float* x = (const float*)d_in[0];
    auto gp = [&](int i) { return (const float*)d_in[i]; };

    struct DirP {
        const float *dw, *db, *ow1, *ob1, *ow2, *ob2, *ow3, *ob3, *ow4, *ob4,
            *bw1, *bb1, *bw2, *bb2;
    };
    DirP Pb{gp(1), gp(2), gp(3), gp(4), gp(5), gp(6), gp(7),
            gp(8), gp(9), gp(10), gp(11), gp(12), gp(13), gp(14)};
    DirP Pf{gp(15), gp(16), gp(17), gp(18), gp(19), gp(20), gp(21),
            gp(22), gp(23), gp(24), gp(25), gp(26), gp(27), gp(28)};
    const float* fus_w = gp(29);
    const float* fus_b = gp(30);

    // ---- workspace carve-up: all feature/intermediate bufs bf16-hi ushort --
    ushort_t* xh = (ushort_t*)d_ws;                       // 8 frames
    ushort_t* featBh = xh + (size_t)8 * FRAME;            // 8 frames
    ushort_t* featFh = featBh + (size_t)8 * FRAME;        // 8 frames
    ushort_t* hAh = featFh + (size_t)8 * FRAME;           // 1 frame
    ushort_t* hBh = hAh + FRAME;                          // 1 frame
    float* pacc = (float*)((((uintptr_t)(hBh + FRAME)) + 15) & ~(uintptr_t)15);
    ushort_t* fragp = (ushort_t*)(pacc + (size_t)2 * FRAME);

    auto falloc = [&](size_t nelem) {
        ushort_t* p = fragp;
        fragp += nelem;
        return p;
    };

    struct DirW { ushort_t *ow1, *ow2, *ow3, *ow4, *bw1, *bw2, *dw; int bw1KC; };
    FragJobs fj;
    int nf = 0;
    auto fjob = [&](const float* src, int O, int I, int OT, int KC) {
        ushort_t* dst = falloc((size_t)2 * 9 * KC * OT * 512);
        fj.j[nf++] = FragJob{src, dst, O, I, OT, KC, 0};
        return dst;
    };
    auto fjobd = [&](const float* src) {
        ushort_t* dst = falloc((size_t)2 * 36 * 4 * 512);
        fj.j[nf++] = FragJob{src, dst, 64, 128, 4, 36, 1};
        return dst;
    };
    DirW Wb, Wf;
    Wb.ow1 = fjob(Pb.ow1, 64, 192, 4, 6);
    Wb.ow2 = fjob(Pb.ow2, 64, 64, 4, 2);
    Wb.ow3 = fjob(Pb.ow3, 64, 64, 4, 2);
    Wb.ow4 = fjob(Pb.ow4, 432, 64, 28, 2);
    Wb.bw1 = fjob(Pb.bw1, 64, 128, 4, 4);
    Wb.bw1KC = 4;
    Wb.bw2 = fjob(Pb.bw2, 64, 64, 4, 2);
    Wb.dw = fjobd(Pb.dw);
    Wf.ow1 = fjob(Pf.ow1, 64, 192, 4, 6);
    Wf.ow2 = fjob(Pf.ow2, 64, 64, 4, 2);
    Wf.ow3 = fjob(Pf.ow3, 64, 64, 4, 2);
    Wf.ow4 = fjob(Pf.ow4, 432, 64, 28, 2);
    Wf.bw1 = fjob(Pf.bw1, 64, 192, 4, 6);
    Wf.bw1KC = 6;
    Wf.bw2 = fjob(Pf.bw2, 64, 64, 4, 2);
    Wf.dw = fjobd(Pf.dw);
    // fusion 1x1 weights (mode 2): O=64, I=128, OT=4, KC=4
    ushort_t* Wfus = falloc((size_t)2 * 4 * 4 * 512);
    fj.j[nf++] = FragJob{fus_w, Wfus, 64, 128, 4, 4, 2};
    frag_all_k<<<dim3(1008, 15), 256, 0, stream>>>(fj);

    pack_tr_k<<<dim3(144, 8), 256, 0, stream>>>(x, xh);

    auto convh = [&](const ushort_t* a, const ushort_t* b, const ushort_t* c2,
                     const ushort_t* frag, int KCfull, const float* bias,
                     ushort_t* out, int act) {
        const ushort_t* srcs[3] = {a, b, c2};
        const ushort_t* S[3] = {nullptr, nullptr, nullptr};
        int B[3] = {0, 0, 0};
        int ns = 0;
        for (int j = 0; j < 3; ++j)
            if (srcs[j]) {
                S[ns] = srcs[j];
                B[ns] = j * 2;
                ++ns;
            }
        convh_k<<<1152, 128, 0, stream>>>(S[0], S[1], S[2], B[0], B[1], B[2],
                                          ns, frag, KCfull, bias, out, act);
    };

    auto convb = [&](const ushort_t* a, const ushort_t* b, int withD,
                     const float* ddbias, const ushort_t* frag, int KCfull,
                     const float* bias, const float* add, const float* add2,
                     const float* abias, ushort_t* out, int act) {
        const ushort_t* S[2] = {nullptr, nullptr};
        int ns = 0;
        if (a) S[ns++] = a;
        if (b) S[ns++] = b;
        int dslot = -1;
        if (withD) { dslot = ns; ++ns; }
        convb_k<<<1152, 128, 0, stream>>>(S[0], S[1], ns, dslot, pacc, ddbias,
                                          frag, KCfull, bias, add, add2,
                                          abias, out, act);
    };

    for (int dir = 0; dir < 2; ++dir) {  // 0 = backward, 1 = forward
        const DirP& P = dir ? Pf : Pb;
        const DirW& W = dir ? Wf : Wb;
        ushort_t* feath = dir ? featFh : featBh;
        const ushort_t* prev1h = nullptr;
        const ushort_t* prev2h = nullptr;
        for (int i = 0; i < 8; ++i) {
            int idx = dir ? i : 7 - i;
            const ushort_t* curh = xh + (size_t)idx * FRAME;
            bool hasD = false;
            if (i > 0) {
                // offset/mask path: pure bf16-hi (convh)
                convh(prev1h, curh, prev2h, W.ow1, 6, P.ob1, hAh, 1);
                convh(hAh, nullptr, nullptr, W.ow2, 2, P.ob2, hBh, 1);
                convh(hBh, nullptr, nullptr, W.ow3, 2, P.ob3, hAh, 1);
                int ngr4 = (prev2h != nullptr) ? 4 : 2;
                dconv_fused_k<<<1152, 256, 0, stream>>>(
                    prev1h, prev2h, hAh, W.ow4, P.ob4, W.dw, ngr4, pacc);
                hasD = true;
            }
            ushort_t* dsth = feath + (size_t)idx * FRAME;
            // bw1: hi-only, D staged from interleaved pacc
            if (dir == 0) {
                convb(curh, nullptr, hasD ? 1 : 0, P.db, W.bw1, W.bw1KC,
                      P.bb1, nullptr, nullptr, nullptr, hBh, 1);
            } else {
                convb(curh, featBh + (size_t)idx * FRAME, hasD ? 1 : 0, P.db,
                      W.bw1, W.bw1KC, P.bb1, nullptr, nullptr, nullptr, hBh,
                      1);
            }
            // bw2: hi-only + interleaved pacc addsrc, writes feature hi shadow
            convb(hBh, nullptr, 0, nullptr, W.bw2, 2, P.bb2,
                  hasD ? pacc : nullptr, pacc + FRAME, P.db, dsth, 0);
            prev2h = prev1h;
            prev1h = dsth;
        }
    }

    fusem_k<<<dim3(1152, 8), 128, 0, stream>>>(featBh, featFh, x, Wfus,
                                               fus_b, (float*)d_out);
}